// Round 4
// baseline (595.994 us; speedup 1.0000x reference)
//
#include <hip/hip_runtime.h>
#include <hip/hip_bf16.h>
#include <math.h>

#define LRELU_NEG 0.2f
#define BN_EPS 1e-5f

__device__ __forceinline__ float lrelu(float x) { return x > 0.f ? x : LRELU_NEG * x; }
__device__ __forceinline__ float b2f(__hip_bfloat16 v) { return __bfloat162float(v); }

// ---------------- dtype detection: are float inputs bf16 or f32? ----------------
// Reads W1's buffer as 16-bit halves, sampling EVEN indices (little-endian).
// bf16 data: even ushorts are genuine weights (0.1*N(0,1)) -> bf16 exponent in
// [90,131] -> ~0% bad. f32 data: even ushorts are LOW mantissa halves ->
// exponent field uniform -> ~84% bad.
__global__ __launch_bounds__(256) void k_detect(const unsigned short* __restrict__ w, int n,
                                                int* __restrict__ flag) {
  __shared__ int bad_s;
  if (threadIdx.x == 0) bad_s = 0;
  __syncthreads();
  int bad = 0;
  for (int i = 2 * threadIdx.x; i < n; i += 512) {
    unsigned short u = w[i];
    if ((u & 0x7FFF) == 0) continue;
    int ex = (u >> 7) & 0xFF;
    if (ex > 131 || ex < 90) bad++;
  }
  atomicAdd(&bad_s, bad);
  __syncthreads();
  if (threadIdx.x == 0) *flag = (bad_s < 2048) ? 1 : 0;   // 1 = inputs are bf16
}

// ---------------- unified input conversion -> f32 in ws ----------------
struct CvtArgs {
  const void* src[30];
  float* dst[30];
  int n[30];
};

__global__ __launch_bounds__(256) void k_cvt_all(CvtArgs a, const int* __restrict__ flag) {
  int ai = blockIdx.y;
  int n = a.n[ai];
  int i = blockIdx.x * 256 + threadIdx.x;
  if (i >= n) return;
  if (*flag) {
    a.dst[ai][i] = b2f(((const __hip_bfloat16*)a.src[ai])[i]);
  } else {
    a.dst[ai][i] = ((const float*)a.src[ai])[i];
  }
}

// ---------------- CSR build ----------------
__global__ void k_count(const int* __restrict__ ei, int* __restrict__ deg, int E, int N) {
  int e = blockIdx.x * 256 + threadIdx.x;
  if (e >= E + N) return;
  int dst = (e < E) ? ei[E + e] : (e - E);   // self-loops appended
  atomicAdd(&deg[dst], 1);
}

__global__ __launch_bounds__(1024) void k_scan(const int* __restrict__ deg, int* __restrict__ rs,
                                               int* __restrict__ cur, int N) {
  __shared__ int lds[1024];
  int tid = threadIdx.x;
  int running = 0;
  for (int base = 0; base <= N; base += 1024) {
    int idx = base + tid;
    int v = (idx < N) ? deg[idx] : 0;
    int x = v;
    lds[tid] = x;
    __syncthreads();
    for (int off = 1; off < 1024; off <<= 1) {
      int y = (tid >= off) ? lds[tid - off] : 0;
      __syncthreads();
      x += y;
      lds[tid] = x;
      __syncthreads();
    }
    int excl = running + x - v;
    if (idx <= N) rs[idx] = excl;
    if (idx < N) cur[idx] = excl;
    running += lds[1023];
    __syncthreads();
  }
}

__global__ void k_scatter(const int* __restrict__ ei, int* __restrict__ cur,
                          int* __restrict__ col, int E, int N) {
  int e = blockIdx.x * 256 + threadIdx.x;
  if (e >= E + N) return;
  int src, dst;
  if (e < E) { src = ei[e]; dst = ei[E + e]; }
  else       { src = e - E; dst = e - E; }
  int pos = atomicAdd(&cur[dst], 1);
  col[pos] = src;
}

// ---------------- layer-0 GEMM (din=4, dout=128) + attention logits ----------------
__global__ __launch_bounds__(256) void k_gemm0(const float* __restrict__ x, const float* __restrict__ W,
    const float* __restrict__ a_s, const float* __restrict__ a_d,
    float* __restrict__ h, float* __restrict__ als, float* __restrict__ ald, int N) {
  int t = blockIdx.x * 256 + threadIdx.x;
  int nrow = t >> 7, c = t & 127;
  if (nrow >= N) return;
  float x0 = x[nrow * 4 + 0];
  float x1 = x[nrow * 4 + 1];
  float x2 = x[nrow * 4 + 2];
  float x3 = x[nrow * 4 + 3];
  float acc = fmaf(x0, W[c], fmaf(x1, W[128 + c], fmaf(x2, W[256 + c], x3 * W[384 + c])));
  h[(size_t)nrow * 128 + c] = acc;
  int hh = c >> 5, cc = c & 31;
  float ps = acc * a_s[hh * 32 + cc];
  float pd = acc * a_d[hh * 32 + cc];
  #pragma unroll
  for (int off = 16; off; off >>= 1) { ps += __shfl_xor(ps, off, 32); pd += __shfl_xor(pd, off, 32); }
  if (cc == 0) { als[nrow * 4 + hh] = ps; ald[nrow * 4 + hh] = pd; }
}

// ---------------- generic GEMM (din=128) + attention logits ----------------
template <int DOUT, int HEADS>
__global__ __launch_bounds__(256) void k_gemm(const float* __restrict__ x, const float* __restrict__ W,
    const float* __restrict__ a_s, const float* __restrict__ a_d,
    float* __restrict__ h, float* __restrict__ als, float* __restrict__ ald, int N) {
  constexpr int RPB = 256 / DOUT;
  __shared__ float xs[RPB][128];
  int tid = threadIdx.x;
  int r = tid / DOUT, c = tid % DOUT;
  int row0 = blockIdx.x * RPB;
  for (int i = tid; i < RPB * 128; i += 256) {
    int rr = i >> 7, k = i & 127;
    int gr = row0 + rr;
    xs[rr][k] = (gr < N) ? x[(size_t)gr * 128 + k] : 0.f;
  }
  __syncthreads();
  int nrow = row0 + r;
  if (nrow >= N) return;
  float acc = 0.f;
  #pragma unroll 8
  for (int k = 0; k < 128; k++) acc = fmaf(xs[r][k], W[k * DOUT + c], acc);
  h[(size_t)nrow * DOUT + c] = acc;
  int hh = c >> 5, cc = c & 31;
  float ps = acc * a_s[hh * 32 + cc];
  float pd = acc * a_d[hh * 32 + cc];
  #pragma unroll
  for (int off = 16; off; off >>= 1) { ps += __shfl_xor(ps, off, 32); pd += __shfl_xor(pd, off, 32); }
  if (cc == 0) { als[(size_t)nrow * HEADS + hh] = ps; ald[(size_t)nrow * HEADS + hh] = pd; }
}

// ---------------- aggregation, H=4 C=32 (width 128), wave per dst node ----------------
__global__ __launch_bounds__(256) void k_agg4(const float* __restrict__ h, const float* __restrict__ als,
    const float* __restrict__ ald, const int* __restrict__ rs, const int* __restrict__ col,
    const float* __restrict__ bias, const float* __restrict__ bng,
    const float* __restrict__ bnb, const float* __restrict__ bnm,
    const float* __restrict__ bnv, float* __restrict__ out, int N) {
  int lane = threadIdx.x & 63;
  int n = blockIdx.x * 4 + (threadIdx.x >> 6);
  if (n >= N) return;
  int row = rs[n], deg = rs[n + 1] - row;
  float4 ad4 = *(const float4*)(ald + (size_t)n * 4);
  float m0 = -1e30f, m1 = -1e30f, m2 = -1e30f, m3 = -1e30f;
  for (int k = lane; k < deg; k += 64) {
    int s = col[row + k];
    float4 a4 = *(const float4*)(als + (size_t)s * 4);
    m0 = fmaxf(m0, lrelu(a4.x + ad4.x));
    m1 = fmaxf(m1, lrelu(a4.y + ad4.y));
    m2 = fmaxf(m2, lrelu(a4.z + ad4.z));
    m3 = fmaxf(m3, lrelu(a4.w + ad4.w));
  }
  #pragma unroll
  for (int off = 32; off; off >>= 1) {
    m0 = fmaxf(m0, __shfl_xor(m0, off));
    m1 = fmaxf(m1, __shfl_xor(m1, off));
    m2 = fmaxf(m2, __shfl_xor(m2, off));
    m3 = fmaxf(m3, __shfl_xor(m3, off));
  }
  float s0 = 0.f, s1 = 0.f, s2 = 0.f, s3 = 0.f;
  for (int k = lane; k < deg; k += 64) {
    int s = col[row + k];
    float4 a4 = *(const float4*)(als + (size_t)s * 4);
    s0 += __expf(lrelu(a4.x + ad4.x) - m0);
    s1 += __expf(lrelu(a4.y + ad4.y) - m1);
    s2 += __expf(lrelu(a4.z + ad4.z) - m2);
    s3 += __expf(lrelu(a4.w + ad4.w) - m3);
  }
  #pragma unroll
  for (int off = 32; off; off >>= 1) {
    s0 += __shfl_xor(s0, off); s1 += __shfl_xor(s1, off);
    s2 += __shfl_xor(s2, off); s3 += __shfl_xor(s3, off);
  }
  float i0 = 1.f / (s0 + 1e-16f), i1 = 1.f / (s1 + 1e-16f);
  float i2 = 1.f / (s2 + 1e-16f), i3 = 1.f / (s3 + 1e-16f);
  int hh = lane >> 4;       // channel pair c0=2*lane -> head = c0/32
  float acc0 = 0.f, acc1 = 0.f;
  for (int base = 0; base < deg; base += 64) {
    int k = base + lane;
    int sv = 0; float al0 = 0.f, al1 = 0.f, al2 = 0.f, al3 = 0.f;
    if (k < deg) {
      sv = col[row + k];
      float4 a4 = *(const float4*)(als + (size_t)sv * 4);
      al0 = __expf(lrelu(a4.x + ad4.x) - m0) * i0;
      al1 = __expf(lrelu(a4.y + ad4.y) - m1) * i1;
      al2 = __expf(lrelu(a4.z + ad4.z) - m2) * i2;
      al3 = __expf(lrelu(a4.w + ad4.w) - m3) * i3;
    }
    int cnt = min(64, deg - base);
    for (int k2 = 0; k2 < cnt; k2++) {
      int s2v = __shfl(sv, k2);
      float b0v = __shfl(al0, k2), b1v = __shfl(al1, k2);
      float b2v = __shfl(al2, k2), b3v = __shfl(al3, k2);
      float alpha = hh == 0 ? b0v : hh == 1 ? b1v : hh == 2 ? b2v : b3v;
      float2 hv = *(const float2*)(h + (size_t)s2v * 128 + 2 * lane);
      acc0 = fmaf(alpha, hv.x, acc0);
      acc1 = fmaf(alpha, hv.y, acc1);
    }
  }
  int c0 = 2 * lane;
  float v0 = acc0 + bias[c0];
  float v1 = acc1 + bias[c0 + 1];
  v0 = (v0 - bnm[c0]) * rsqrtf(bnv[c0] + BN_EPS) * bng[c0] + bnb[c0];
  v1 = (v1 - bnm[c0 + 1]) * rsqrtf(bnv[c0 + 1] + BN_EPS) * bng[c0 + 1] + bnb[c0 + 1];
  v0 = v0 > 0.f ? v0 : expm1f(v0);
  v1 = v1 > 0.f ? v1 : expm1f(v1);
  *(float2*)(out + (size_t)n * 128 + c0) = make_float2(v0, v1);
}

// ---------------- aggregation, H=1 C=32 (width 32), wave per dst node ----------------
__global__ __launch_bounds__(256) void k_agg1(const float* __restrict__ h, const float* __restrict__ als,
    const float* __restrict__ ald, const int* __restrict__ rs, const int* __restrict__ col,
    const float* __restrict__ bias, const float* __restrict__ bng,
    const float* __restrict__ bnb, const float* __restrict__ bnm,
    const float* __restrict__ bnv, float* __restrict__ out, int N) {
  int lane = threadIdx.x & 63;
  int n = blockIdx.x * 4 + (threadIdx.x >> 6);
  if (n >= N) return;
  int row = rs[n], deg = rs[n + 1] - row;
  float ad = ald[n];
  float m = -1e30f;
  for (int k = lane; k < deg; k += 64) {
    int s = col[row + k];
    m = fmaxf(m, lrelu(als[s] + ad));
  }
  #pragma unroll
  for (int off = 32; off; off >>= 1) m = fmaxf(m, __shfl_xor(m, off));
  float su = 0.f;
  for (int k = lane; k < deg; k += 64) {
    int s = col[row + k];
    su += __expf(lrelu(als[s] + ad) - m);
  }
  #pragma unroll
  for (int off = 32; off; off >>= 1) su += __shfl_xor(su, off);
  float inv = 1.f / (su + 1e-16f);
  int c = lane & 31;
  float acc = 0.f;
  for (int base = 0; base < deg; base += 64) {
    int k = base + lane;
    int sv = 0; float al = 0.f;
    if (k < deg) {
      sv = col[row + k];
      al = __expf(lrelu(als[sv] + ad) - m) * inv;
    }
    int cnt = min(64, deg - base);
    for (int k2 = 0; k2 < cnt; k2++) {
      int s2v = __shfl(sv, k2);
      float alpha = __shfl(al, k2);
      float hv = h[(size_t)s2v * 32 + c];
      acc = fmaf(alpha, hv, acc);
    }
  }
  if (lane < 32) {
    float v = acc + bias[c];
    v = (v - bnm[c]) * rsqrtf(bnv[c] + BN_EPS) * bng[c] + bnb[c];
    v = v > 0.f ? v : expm1f(v);
    out[(size_t)n * 32 + c] = v;
  }
}

// ---------------- per-graph pooling + MLP head (FLOAT32 output) ----------------
__global__ __launch_bounds__(64) void k_pool(const float* __restrict__ x3, const int* __restrict__ batch,
    const float* __restrict__ u, const float* __restrict__ l1w,
    const float* __restrict__ l1b, const float* __restrict__ l2w,
    const float* __restrict__ l2b, float* __restrict__ out, int N, int G) {
  int g = blockIdx.x;
  int lane = threadIdx.x;
  int lo = 0, hi = N;
  while (lo < hi) { int mid = (lo + hi) >> 1; if (batch[mid] < g) lo = mid + 1; else hi = mid; }
  int start = lo;
  hi = N;
  while (lo < hi) { int mid = (lo + hi) >> 1; if (batch[mid] < g + 1) lo = mid + 1; else hi = mid; }
  int end = lo;
  int c = lane & 31, half = lane >> 5;
  float sum = 0.f, mx = -1e30f;
  for (int i = start + half; i < end; i += 2) {
    float v = x3[(size_t)i * 32 + c];
    sum += v; mx = fmaxf(mx, v);
  }
  sum += __shfl_xor(sum, 32);
  mx = fmaxf(mx, __shfl_xor(mx, 32));
  __shared__ float comb[74];
  if (lane < 32) {
    float cnt = (float)(end - start);
    comb[lane] = sum / cnt;
    comb[32 + lane] = mx;
  }
  if (lane < 10) comb[64 + lane] = u[g * 10 + lane];
  __syncthreads();
  if (lane < 32) {
    float acc = l1b[lane];
    #pragma unroll
    for (int k = 0; k < 74; k++) acc = fmaf(comb[k], l1w[k * 32 + lane], acc);
    acc = fmaxf(acc, 0.f);                       // ReLU
    float v = acc * l2w[lane];
    #pragma unroll
    for (int off = 16; off; off >>= 1) v += __shfl_xor(v, off, 32);
    if (lane == 0) out[g] = 1.f / (1.f + __expf(-(v + l2b[0])));
  }
}

extern "C" void kernel_launch(void* const* d_in, const int* in_sizes, int n_in,
                              void* d_out, int out_size, void* d_ws, size_t ws_size,
                              hipStream_t stream) {
  const int* EI    = (const int*)d_in[1];
  const int* BATCH = (const int*)d_in[2];
  float* OUT = (float*)d_out;            // reference returns float32

  int N = in_sizes[2];          // batch has N elements
  int E = in_sizes[1] / 2;      // edge_index is [2,E]
  int G = in_sizes[3] / 10;     // u is [G,10]
  int EN = E + N;

  char* ws = (char*)d_ws;
  size_t off = 0;
  auto alloc = [&](size_t bytes) {
    void* p = ws + off;
    off = (off + bytes + 255) & ~(size_t)255;
    return p;
  };
  float* f_xa  = (float*)alloc((size_t)N * 128 * 4);
  float* f_h   = (float*)alloc((size_t)N * 128 * 4);
  float* f_als = (float*)alloc((size_t)N * 4 * 4);
  float* f_ald = (float*)alloc((size_t)N * 4 * 4);
  int* i_deg = (int*)alloc((size_t)(N + 1) * 4);
  int* i_rs  = (int*)alloc((size_t)(N + 1) * 4);
  int* i_cur = (int*)alloc((size_t)N * 4);
  int* i_col = (int*)alloc((size_t)EN * 4);
  int* i_flag = (int*)alloc(256);

  // f32 copies of all 30 float inputs (skip d_in[1], d_in[2] = ints)
  CvtArgs ca;
  float* fptr[32];
  int maxn = 0, na = 0;
  for (int i = 0; i < 32; i++) {
    if (i == 1 || i == 2) { fptr[i] = nullptr; continue; }
    int n = in_sizes[i];
    fptr[i] = (float*)alloc((size_t)n * 4);
    ca.src[na] = d_in[i];
    ca.dst[na] = fptr[i];
    ca.n[na] = n;
    if (n > maxn) maxn = n;
    na++;
  }

  // dtype detect + convert
  k_detect<<<1, 256, 0, stream>>>((const unsigned short*)d_in[12], in_sizes[12], i_flag);
  dim3 cgrid((maxn + 255) / 256, na);
  k_cvt_all<<<cgrid, 256, 0, stream>>>(ca, i_flag);

  // CSR build
  hipMemsetAsync(i_deg, 0, (size_t)N * 4, stream);
  k_count<<<(EN + 255) / 256, 256, 0, stream>>>(EI, i_deg, E, N);
  k_scan<<<1, 1024, 0, stream>>>(i_deg, i_rs, i_cur, N);
  k_scatter<<<(EN + 255) / 256, 256, 0, stream>>>(EI, i_cur, i_col, E, N);

  // layer 0
  k_gemm0<<<(N * 128 + 255) / 256, 256, 0, stream>>>(fptr[0], fptr[4], fptr[5], fptr[6], f_h, f_als, f_ald, N);
  k_agg4<<<(N + 3) / 4, 256, 0, stream>>>(f_h, f_als, f_ald, i_rs, i_col, fptr[7], fptr[8], fptr[9], fptr[10], fptr[11], f_xa, N);
  // layer 1
  k_gemm<128, 4><<<(N + 1) / 2, 256, 0, stream>>>(f_xa, fptr[12], fptr[13], fptr[14], f_h, f_als, f_ald, N);
  k_agg4<<<(N + 3) / 4, 256, 0, stream>>>(f_h, f_als, f_ald, i_rs, i_col, fptr[15], fptr[16], fptr[17], fptr[18], fptr[19], f_xa, N);
  // layer 2
  k_gemm<32, 1><<<(N + 7) / 8, 256, 0, stream>>>(f_xa, fptr[20], fptr[21], fptr[22], f_h, f_als, f_ald, N);
  k_agg1<<<(N + 3) / 4, 256, 0, stream>>>(f_h, f_als, f_ald, i_rs, i_col, fptr[23], fptr[24], fptr[25], fptr[26], fptr[27], f_xa, N);

  // pooling + MLP head
  k_pool<<<G, 64, 0, stream>>>(f_xa, BATCH, fptr[3], fptr[28], fptr[29], fptr[30], fptr[31], OUT, N, G);
}

// Round 5
// 544.539 us; speedup vs baseline: 1.0945x; 1.0945x over previous
//
#include <hip/hip_runtime.h>
#include <hip/hip_bf16.h>
#include <math.h>

#define LRELU_NEG 0.2f
#define BN_EPS 1e-5f

__device__ __forceinline__ float lrelu(float x) { return x > 0.f ? x : LRELU_NEG * x; }
__device__ __forceinline__ float b2f(__hip_bfloat16 v) { return __bfloat162float(v); }

// ---------------- dtype detection: are float inputs bf16 or f32? ----------------
__global__ __launch_bounds__(256) void k_detect(const unsigned short* __restrict__ w, int n,
                                                int* __restrict__ flag) {
  __shared__ int bad_s;
  if (threadIdx.x == 0) bad_s = 0;
  __syncthreads();
  int bad = 0;
  for (int i = 2 * threadIdx.x; i < n; i += 512) {
    unsigned short u = w[i];
    if ((u & 0x7FFF) == 0) continue;
    int ex = (u >> 7) & 0xFF;
    if (ex > 131 || ex < 90) bad++;
  }
  atomicAdd(&bad_s, bad);
  __syncthreads();
  if (threadIdx.x == 0) *flag = (bad_s < 2048) ? 1 : 0;   // 1 = inputs are bf16
}

// ---------------- unified input conversion -> f32 in ws ----------------
struct CvtArgs {
  const void* src[30];
  float* dst[30];
  int n[30];
};

__global__ __launch_bounds__(256) void k_cvt_all(CvtArgs a, const int* __restrict__ flag) {
  int ai = blockIdx.y;
  int n = a.n[ai];
  int i = blockIdx.x * 256 + threadIdx.x;
  if (i >= n) return;
  if (*flag) {
    a.dst[ai][i] = b2f(((const __hip_bfloat16*)a.src[ai])[i]);
  } else {
    a.dst[ai][i] = ((const float*)a.src[ai])[i];
  }
}

// ---------------- CSR build ----------------
__global__ void k_count(const int* __restrict__ ei, int* __restrict__ deg, int E, int N) {
  int e = blockIdx.x * 256 + threadIdx.x;
  if (e >= E + N) return;
  int dst = (e < E) ? ei[E + e] : (e - E);   // self-loops appended
  atomicAdd(&deg[dst], 1);
}

__global__ __launch_bounds__(1024) void k_scan(const int* __restrict__ deg, int* __restrict__ rs,
                                               int* __restrict__ cur, int N) {
  __shared__ int lds[1024];
  int tid = threadIdx.x;
  int running = 0;
  for (int base = 0; base <= N; base += 1024) {
    int idx = base + tid;
    int v = (idx < N) ? deg[idx] : 0;
    int x = v;
    lds[tid] = x;
    __syncthreads();
    for (int off = 1; off < 1024; off <<= 1) {
      int y = (tid >= off) ? lds[tid - off] : 0;
      __syncthreads();
      x += y;
      lds[tid] = x;
      __syncthreads();
    }
    int excl = running + x - v;
    if (idx <= N) rs[idx] = excl;
    if (idx < N) cur[idx] = excl;
    running += lds[1023];
    __syncthreads();
  }
}

__global__ void k_scatter(const int* __restrict__ ei, int* __restrict__ cur,
                          int* __restrict__ col, int E, int N) {
  int e = blockIdx.x * 256 + threadIdx.x;
  if (e >= E + N) return;
  int src, dst;
  if (e < E) { src = ei[e]; dst = ei[E + e]; }
  else       { src = e - E; dst = e - E; }
  int pos = atomicAdd(&cur[dst], 1);
  col[pos] = src;
}

// ---------------- layer-0 GEMM (din=4, dout=128) + attention logits ----------------
__global__ __launch_bounds__(256) void k_gemm0(const float* __restrict__ x, const float* __restrict__ W,
    const float* __restrict__ a_s, const float* __restrict__ a_d,
    float* __restrict__ h, float* __restrict__ als, float* __restrict__ ald, int N) {
  int t = blockIdx.x * 256 + threadIdx.x;
  int nrow = t >> 7, c = t & 127;
  if (nrow >= N) return;
  float x0 = x[nrow * 4 + 0];
  float x1 = x[nrow * 4 + 1];
  float x2 = x[nrow * 4 + 2];
  float x3 = x[nrow * 4 + 3];
  float acc = fmaf(x0, W[c], fmaf(x1, W[128 + c], fmaf(x2, W[256 + c], x3 * W[384 + c])));
  h[(size_t)nrow * 128 + c] = acc;
  int hh = c >> 5, cc = c & 31;
  float ps = acc * a_s[hh * 32 + cc];
  float pd = acc * a_d[hh * 32 + cc];
  #pragma unroll
  for (int off = 16; off; off >>= 1) { ps += __shfl_xor(ps, off, 32); pd += __shfl_xor(pd, off, 32); }
  if (cc == 0) { als[nrow * 4 + hh] = ps; ald[nrow * 4 + hh] = pd; }
}

// ---------------- register-blocked GEMM (din=128) + attention logits ----------------
// 16 rows per thread, DOUT cols per col-group. Block = 256 threads.
// ROWS = 256/DOUT*16 rows per block. x tile staged in LDS [ROWS][132] (pad 4).
template <int DOUT, int HEADS>
__global__ __launch_bounds__(256) void k_gemm_v2(const float* __restrict__ x, const float* __restrict__ W,
    const float* __restrict__ a_s, const float* __restrict__ a_d,
    float* __restrict__ h, float* __restrict__ als, float* __restrict__ ald, int N) {
  constexpr int RPT = 16;
  constexpr int COLG = 256 / DOUT;
  constexpr int ROWS = COLG * RPT;
  __shared__ float xs[ROWS][132];
  int tid = threadIdx.x;
  int c = tid % DOUT;
  int rg = tid / DOUT;
  int row0 = blockIdx.x * ROWS;

  // stage x tile: float4 chunks, coalesced global, conflict-free LDS writes
  for (int i = tid * 4; i < ROWS * 128; i += 1024) {
    int rr = i >> 7, k0 = i & 127;
    int gr = row0 + rr;
    float4 v = (gr < N) ? *(const float4*)(x + (size_t)gr * 128 + k0)
                        : make_float4(0.f, 0.f, 0.f, 0.f);
    *(float4*)&xs[rr][k0] = v;
  }
  __syncthreads();

  float acc[RPT];
  #pragma unroll
  for (int j = 0; j < RPT; j++) acc[j] = 0.f;

  const float* wp = W + c;
  #pragma unroll 2
  for (int k0 = 0; k0 < 128; k0 += 4) {
    float w0 = wp[(size_t)(k0 + 0) * DOUT];
    float w1 = wp[(size_t)(k0 + 1) * DOUT];
    float w2 = wp[(size_t)(k0 + 2) * DOUT];
    float w3 = wp[(size_t)(k0 + 3) * DOUT];
    #pragma unroll
    for (int j = 0; j < RPT; j++) {
      float4 xv = *(const float4*)&xs[rg * RPT + j][k0];
      acc[j] = fmaf(xv.x, w0, fmaf(xv.y, w1, fmaf(xv.z, w2, fmaf(xv.w, w3, acc[j]))));
    }
  }

  // h writes (coalesced over c)
  #pragma unroll
  for (int j = 0; j < RPT; j++) {
    int gr = row0 + rg * RPT + j;
    if (gr < N) h[(size_t)gr * DOUT + c] = acc[j];
  }
  // attention logits: reduce over 32-channel head groups (c-consecutive lanes)
  int cc = c & 31, hh = c >> 5;
  float asv = a_s[hh * 32 + cc];
  float adv = a_d[hh * 32 + cc];
  #pragma unroll
  for (int j = 0; j < RPT; j++) {
    float ps = acc[j] * asv;
    float pd = acc[j] * adv;
    #pragma unroll
    for (int off = 16; off; off >>= 1) {
      ps += __shfl_xor(ps, off, 32);
      pd += __shfl_xor(pd, off, 32);
    }
    if (cc == 0) {
      int gr = row0 + rg * RPT + j;
      if (gr < N) { als[(size_t)gr * HEADS + hh] = ps; ald[(size_t)gr * HEADS + hh] = pd; }
    }
  }
}

// ---------------- aggregation, H=4 C=32 (width 128), wave per dst node ----------------
__global__ __launch_bounds__(256) void k_agg4(const float* __restrict__ h, const float* __restrict__ als,
    const float* __restrict__ ald, const int* __restrict__ rs, const int* __restrict__ col,
    const float* __restrict__ bias, const float* __restrict__ bng,
    const float* __restrict__ bnb, const float* __restrict__ bnm,
    const float* __restrict__ bnv, float* __restrict__ out, int N) {
  int lane = threadIdx.x & 63;
  int n = blockIdx.x * 4 + (threadIdx.x >> 6);
  if (n >= N) return;
  int row = rs[n], deg = rs[n + 1] - row;
  float4 ad4 = *(const float4*)(ald + (size_t)n * 4);
  float m0 = -1e30f, m1 = -1e30f, m2 = -1e30f, m3 = -1e30f;
  for (int k = lane; k < deg; k += 64) {
    int s = col[row + k];
    float4 a4 = *(const float4*)(als + (size_t)s * 4);
    m0 = fmaxf(m0, lrelu(a4.x + ad4.x));
    m1 = fmaxf(m1, lrelu(a4.y + ad4.y));
    m2 = fmaxf(m2, lrelu(a4.z + ad4.z));
    m3 = fmaxf(m3, lrelu(a4.w + ad4.w));
  }
  #pragma unroll
  for (int off = 32; off; off >>= 1) {
    m0 = fmaxf(m0, __shfl_xor(m0, off));
    m1 = fmaxf(m1, __shfl_xor(m1, off));
    m2 = fmaxf(m2, __shfl_xor(m2, off));
    m3 = fmaxf(m3, __shfl_xor(m3, off));
  }
  float s0 = 0.f, s1 = 0.f, s2 = 0.f, s3 = 0.f;
  for (int k = lane; k < deg; k += 64) {
    int s = col[row + k];
    float4 a4 = *(const float4*)(als + (size_t)s * 4);
    s0 += __expf(lrelu(a4.x + ad4.x) - m0);
    s1 += __expf(lrelu(a4.y + ad4.y) - m1);
    s2 += __expf(lrelu(a4.z + ad4.z) - m2);
    s3 += __expf(lrelu(a4.w + ad4.w) - m3);
  }
  #pragma unroll
  for (int off = 32; off; off >>= 1) {
    s0 += __shfl_xor(s0, off); s1 += __shfl_xor(s1, off);
    s2 += __shfl_xor(s2, off); s3 += __shfl_xor(s3, off);
  }
  float i0 = 1.f / (s0 + 1e-16f), i1 = 1.f / (s1 + 1e-16f);
  float i2 = 1.f / (s2 + 1e-16f), i3 = 1.f / (s3 + 1e-16f);
  int hh = lane >> 4;       // channel pair c0=2*lane -> head = c0/32
  float acc0 = 0.f, acc1 = 0.f;
  for (int base = 0; base < deg; base += 64) {
    int k = base + lane;
    int sv = 0; float al0 = 0.f, al1 = 0.f, al2 = 0.f, al3 = 0.f;
    if (k < deg) {
      sv = col[row + k];
      float4 a4 = *(const float4*)(als + (size_t)sv * 4);
      al0 = __expf(lrelu(a4.x + ad4.x) - m0) * i0;
      al1 = __expf(lrelu(a4.y + ad4.y) - m1) * i1;
      al2 = __expf(lrelu(a4.z + ad4.z) - m2) * i2;
      al3 = __expf(lrelu(a4.w + ad4.w) - m3) * i3;
    }
    int cnt = min(64, deg - base);
    for (int k2 = 0; k2 < cnt; k2++) {
      int s2v = __shfl(sv, k2);
      float b0v = __shfl(al0, k2), b1v = __shfl(al1, k2);
      float b2v = __shfl(al2, k2), b3v = __shfl(al3, k2);
      float alpha = hh == 0 ? b0v : hh == 1 ? b1v : hh == 2 ? b2v : b3v;
      float2 hv = *(const float2*)(h + (size_t)s2v * 128 + 2 * lane);
      acc0 = fmaf(alpha, hv.x, acc0);
      acc1 = fmaf(alpha, hv.y, acc1);
    }
  }
  int c0 = 2 * lane;
  float v0 = acc0 + bias[c0];
  float v1 = acc1 + bias[c0 + 1];
  v0 = (v0 - bnm[c0]) * rsqrtf(bnv[c0] + BN_EPS) * bng[c0] + bnb[c0];
  v1 = (v1 - bnm[c0 + 1]) * rsqrtf(bnv[c0 + 1] + BN_EPS) * bng[c0 + 1] + bnb[c0 + 1];
  v0 = v0 > 0.f ? v0 : expm1f(v0);
  v1 = v1 > 0.f ? v1 : expm1f(v1);
  *(float2*)(out + (size_t)n * 128 + c0) = make_float2(v0, v1);
}

// ---------------- aggregation, H=1 C=32 (width 32), wave per dst node ----------------
__global__ __launch_bounds__(256) void k_agg1(const float* __restrict__ h, const float* __restrict__ als,
    const float* __restrict__ ald, const int* __restrict__ rs, const int* __restrict__ col,
    const float* __restrict__ bias, const float* __restrict__ bng,
    const float* __restrict__ bnb, const float* __restrict__ bnm,
    const float* __restrict__ bnv, float* __restrict__ out, int N) {
  int lane = threadIdx.x & 63;
  int n = blockIdx.x * 4 + (threadIdx.x >> 6);
  if (n >= N) return;
  int row = rs[n], deg = rs[n + 1] - row;
  float ad = ald[n];
  float m = -1e30f;
  for (int k = lane; k < deg; k += 64) {
    int s = col[row + k];
    m = fmaxf(m, lrelu(als[s] + ad));
  }
  #pragma unroll
  for (int off = 32; off; off >>= 1) m = fmaxf(m, __shfl_xor(m, off));
  float su = 0.f;
  for (int k = lane; k < deg; k += 64) {
    int s = col[row + k];
    su += __expf(lrelu(als[s] + ad) - m);
  }
  #pragma unroll
  for (int off = 32; off; off >>= 1) su += __shfl_xor(su, off);
  float inv = 1.f / (su + 1e-16f);
  int c = lane & 31;
  float acc = 0.f;
  for (int base = 0; base < deg; base += 64) {
    int k = base + lane;
    int sv = 0; float al = 0.f;
    if (k < deg) {
      sv = col[row + k];
      al = __expf(lrelu(als[sv] + ad) - m) * inv;
    }
    int cnt = min(64, deg - base);
    for (int k2 = 0; k2 < cnt; k2++) {
      int s2v = __shfl(sv, k2);
      float alpha = __shfl(al, k2);
      float hv = h[(size_t)s2v * 32 + c];
      acc = fmaf(alpha, hv, acc);
    }
  }
  if (lane < 32) {
    float v = acc + bias[c];
    v = (v - bnm[c]) * rsqrtf(bnv[c] + BN_EPS) * bng[c] + bnb[c];
    v = v > 0.f ? v : expm1f(v);
    out[(size_t)n * 32 + c] = v;
  }
}

// ---------------- per-graph pooling + MLP head (FLOAT32 output) ----------------
__global__ __launch_bounds__(64) void k_pool(const float* __restrict__ x3, const int* __restrict__ batch,
    const float* __restrict__ u, const float* __restrict__ l1w,
    const float* __restrict__ l1b, const float* __restrict__ l2w,
    const float* __restrict__ l2b, float* __restrict__ out, int N, int G) {
  int g = blockIdx.x;
  int lane = threadIdx.x;
  int lo = 0, hi = N;
  while (lo < hi) { int mid = (lo + hi) >> 1; if (batch[mid] < g) lo = mid + 1; else hi = mid; }
  int start = lo;
  hi = N;
  while (lo < hi) { int mid = (lo + hi) >> 1; if (batch[mid] < g + 1) lo = mid + 1; else hi = mid; }
  int end = lo;
  int c = lane & 31, half = lane >> 5;
  float sum = 0.f, mx = -1e30f;
  for (int i = start + half; i < end; i += 2) {
    float v = x3[(size_t)i * 32 + c];
    sum += v; mx = fmaxf(mx, v);
  }
  sum += __shfl_xor(sum, 32);
  mx = fmaxf(mx, __shfl_xor(mx, 32));
  __shared__ float comb[74];
  if (lane < 32) {
    float cnt = (float)(end - start);
    comb[lane] = sum / cnt;
    comb[32 + lane] = mx;
  }
  if (lane < 10) comb[64 + lane] = u[g * 10 + lane];
  __syncthreads();
  if (lane < 32) {
    float acc = l1b[lane];
    #pragma unroll
    for (int k = 0; k < 74; k++) acc = fmaf(comb[k], l1w[k * 32 + lane], acc);
    acc = fmaxf(acc, 0.f);                       // ReLU
    float v = acc * l2w[lane];
    #pragma unroll
    for (int off = 16; off; off >>= 1) v += __shfl_xor(v, off, 32);
    if (lane == 0) out[g] = 1.f / (1.f + __expf(-(v + l2b[0])));
  }
}

extern "C" void kernel_launch(void* const* d_in, const int* in_sizes, int n_in,
                              void* d_out, int out_size, void* d_ws, size_t ws_size,
                              hipStream_t stream) {
  const int* EI    = (const int*)d_in[1];
  const int* BATCH = (const int*)d_in[2];
  float* OUT = (float*)d_out;            // reference returns float32

  int N = in_sizes[2];          // batch has N elements
  int E = in_sizes[1] / 2;      // edge_index is [2,E]
  int G = in_sizes[3] / 10;     // u is [G,10]
  int EN = E + N;

  char* ws = (char*)d_ws;
  size_t off = 0;
  auto alloc = [&](size_t bytes) {
    void* p = ws + off;
    off = (off + bytes + 255) & ~(size_t)255;
    return p;
  };
  float* f_xa  = (float*)alloc((size_t)N * 128 * 4);
  float* f_h   = (float*)alloc((size_t)N * 128 * 4);
  float* f_als = (float*)alloc((size_t)N * 4 * 4);
  float* f_ald = (float*)alloc((size_t)N * 4 * 4);
  int* i_deg = (int*)alloc((size_t)(N + 1) * 4);
  int* i_rs  = (int*)alloc((size_t)(N + 1) * 4);
  int* i_cur = (int*)alloc((size_t)N * 4);
  int* i_col = (int*)alloc((size_t)EN * 4);
  int* i_flag = (int*)alloc(256);

  // f32 copies of all 30 float inputs (skip d_in[1], d_in[2] = ints)
  CvtArgs ca;
  float* fptr[32];
  int maxn = 0, na = 0;
  for (int i = 0; i < 32; i++) {
    if (i == 1 || i == 2) { fptr[i] = nullptr; continue; }
    int n = in_sizes[i];
    fptr[i] = (float*)alloc((size_t)n * 4);
    ca.src[na] = d_in[i];
    ca.dst[na] = fptr[i];
    ca.n[na] = n;
    if (n > maxn) maxn = n;
    na++;
  }

  // dtype detect + convert
  k_detect<<<1, 256, 0, stream>>>((const unsigned short*)d_in[12], in_sizes[12], i_flag);
  dim3 cgrid((maxn + 255) / 256, na);
  k_cvt_all<<<cgrid, 256, 0, stream>>>(ca, i_flag);

  // CSR build
  hipMemsetAsync(i_deg, 0, (size_t)N * 4, stream);
  k_count<<<(EN + 255) / 256, 256, 0, stream>>>(EI, i_deg, E, N);
  k_scan<<<1, 1024, 0, stream>>>(i_deg, i_rs, i_cur, N);
  k_scatter<<<(EN + 255) / 256, 256, 0, stream>>>(EI, i_cur, i_col, E, N);

  // layer 0
  k_gemm0<<<(N * 128 + 255) / 256, 256, 0, stream>>>(fptr[0], fptr[4], fptr[5], fptr[6], f_h, f_als, f_ald, N);
  k_agg4<<<(N + 3) / 4, 256, 0, stream>>>(f_h, f_als, f_ald, i_rs, i_col, fptr[7], fptr[8], fptr[9], fptr[10], fptr[11], f_xa, N);
  // layer 1  (32 rows per block)
  k_gemm_v2<128, 4><<<(N + 31) / 32, 256, 0, stream>>>(f_xa, fptr[12], fptr[13], fptr[14], f_h, f_als, f_ald, N);
  k_agg4<<<(N + 3) / 4, 256, 0, stream>>>(f_h, f_als, f_ald, i_rs, i_col, fptr[15], fptr[16], fptr[17], fptr[18], fptr[19], f_xa, N);
  // layer 2  (128 rows per block)
  k_gemm_v2<32, 1><<<(N + 127) / 128, 256, 0, stream>>>(f_xa, fptr[20], fptr[21], fptr[22], f_h, f_als, f_ald, N);
  k_agg1<<<(N + 3) / 4, 256, 0, stream>>>(f_h, f_als, f_ald, i_rs, i_col, fptr[23], fptr[24], fptr[25], fptr[26], fptr[27], f_xa, N);

  // pooling + MLP head
  k_pool<<<G, 64, 0, stream>>>(f_xa, BATCH, fptr[3], fptr[28], fptr[29], fptr[30], fptr[31], OUT, N, G);
}

// Round 6
// 397.698 us; speedup vs baseline: 1.4986x; 1.3692x over previous
//
#include <hip/hip_runtime.h>
#include <hip/hip_bf16.h>
#include <math.h>

#define LRELU_NEG 0.2f
#define BN_EPS 1e-5f

__device__ __forceinline__ float lrelu(float x) { return x > 0.f ? x : LRELU_NEG * x; }
__device__ __forceinline__ float b2f(__hip_bfloat16 v) { return __bfloat162float(v); }

// ---------------- dtype detection: are float inputs bf16 or f32? ----------------
__global__ __launch_bounds__(256) void k_detect(const unsigned short* __restrict__ w, int n,
                                                int* __restrict__ flag) {
  __shared__ int bad_s;
  if (threadIdx.x == 0) bad_s = 0;
  __syncthreads();
  int bad = 0;
  for (int i = 2 * threadIdx.x; i < n; i += 512) {
    unsigned short u = w[i];
    if ((u & 0x7FFF) == 0) continue;
    int ex = (u >> 7) & 0xFF;
    if (ex > 131 || ex < 90) bad++;
  }
  atomicAdd(&bad_s, bad);
  __syncthreads();
  if (threadIdx.x == 0) *flag = (bad_s < 2048) ? 1 : 0;   // 1 = inputs are bf16
}

// ---------------- unified input conversion -> f32 in ws ----------------
struct CvtArgs {
  const void* src[30];
  float* dst[30];
  int n[30];
};

__global__ __launch_bounds__(256) void k_cvt_all(CvtArgs a, const int* __restrict__ flag) {
  int ai = blockIdx.y;
  int n = a.n[ai];
  int i = blockIdx.x * 256 + threadIdx.x;
  if (i >= n) return;
  if (*flag) {
    a.dst[ai][i] = b2f(((const __hip_bfloat16*)a.src[ai])[i]);
  } else {
    a.dst[ai][i] = ((const float*)a.src[ai])[i];
  }
}

// ---------------- CSR build ----------------
__global__ void k_count(const int* __restrict__ ei, int* __restrict__ deg, int E, int N) {
  int e = blockIdx.x * 256 + threadIdx.x;
  if (e >= E + N) return;
  int dst = (e < E) ? ei[E + e] : (e - E);   // self-loops appended
  atomicAdd(&deg[dst], 1);
}

// wave-shfl scan: 16 waves, 3 barriers per 1024-chunk
__global__ __launch_bounds__(1024) void k_scan(const int* __restrict__ deg, int* __restrict__ rs,
                                               int* __restrict__ cur, int N) {
  __shared__ int wpre[16];
  __shared__ int running_s;
  int tid = threadIdx.x, lane = tid & 63, wid = tid >> 6;
  if (tid == 0) running_s = 0;
  __syncthreads();
  for (int base = 0; base <= N; base += 1024) {
    int idx = base + tid;
    int v = (idx < N) ? deg[idx] : 0;
    int x = v;
    #pragma unroll
    for (int off = 1; off < 64; off <<= 1) {
      int y = __shfl_up(x, off);
      if (lane >= off) x += y;
    }
    if (lane == 63) wpre[wid] = x;
    __syncthreads();
    if (tid == 0) {
      int acc = running_s;
      #pragma unroll
      for (int w = 0; w < 16; w++) { int t = wpre[w]; wpre[w] = acc; acc += t; }
      running_s = acc;
    }
    __syncthreads();
    int excl = wpre[wid] + x - v;
    if (idx <= N) rs[idx] = excl;
    if (idx < N) cur[idx] = excl;
    __syncthreads();
  }
}

__global__ void k_scatter(const int* __restrict__ ei, int* __restrict__ cur,
                          int* __restrict__ col, int E, int N) {
  int e = blockIdx.x * 256 + threadIdx.x;
  if (e >= E + N) return;
  int src, dst;
  if (e < E) { src = ei[e]; dst = ei[E + e]; }
  else       { src = e - E; dst = e - E; }
  int pos = atomicAdd(&cur[dst], 1);
  col[pos] = src;
}

// ---------------- layer-0 GEMM (din=4, dout=128) + attention logits ----------------
__global__ __launch_bounds__(256) void k_gemm0(const float* __restrict__ x, const float* __restrict__ W,
    const float* __restrict__ a_s, const float* __restrict__ a_d,
    __hip_bfloat16* __restrict__ h, float* __restrict__ als, float* __restrict__ ald, int N) {
  int t = blockIdx.x * 256 + threadIdx.x;
  int nrow = t >> 7, c = t & 127;
  if (nrow >= N) return;
  float x0 = x[nrow * 4 + 0];
  float x1 = x[nrow * 4 + 1];
  float x2 = x[nrow * 4 + 2];
  float x3 = x[nrow * 4 + 3];
  float acc = fmaf(x0, W[c], fmaf(x1, W[128 + c], fmaf(x2, W[256 + c], x3 * W[384 + c])));
  h[(size_t)nrow * 128 + c] = __float2bfloat16(acc);
  int hh = c >> 5, cc = c & 31;
  float ps = acc * a_s[hh * 32 + cc];
  float pd = acc * a_d[hh * 32 + cc];
  #pragma unroll
  for (int off = 16; off; off >>= 1) { ps += __shfl_xor(ps, off, 32); pd += __shfl_xor(pd, off, 32); }
  if (cc == 0) { als[nrow * 4 + hh] = ps; ald[nrow * 4 + hh] = pd; }
}

// ---------------- register-blocked GEMM (din=128) + attention logits ----------------
template <int DOUT, int HEADS>
__global__ __launch_bounds__(256) void k_gemm_v2(const float* __restrict__ x, const float* __restrict__ W,
    const float* __restrict__ a_s, const float* __restrict__ a_d,
    __hip_bfloat16* __restrict__ h, float* __restrict__ als, float* __restrict__ ald, int N) {
  constexpr int RPT = 16;
  constexpr int COLG = 256 / DOUT;
  constexpr int ROWS = COLG * RPT;
  __shared__ float xs[ROWS][132];
  int tid = threadIdx.x;
  int c = tid % DOUT;
  int rg = tid / DOUT;
  int row0 = blockIdx.x * ROWS;

  for (int i = tid * 4; i < ROWS * 128; i += 1024) {
    int rr = i >> 7, k0 = i & 127;
    int gr = row0 + rr;
    float4 v = (gr < N) ? *(const float4*)(x + (size_t)gr * 128 + k0)
                        : make_float4(0.f, 0.f, 0.f, 0.f);
    *(float4*)&xs[rr][k0] = v;
  }
  __syncthreads();

  float acc[RPT];
  #pragma unroll
  for (int j = 0; j < RPT; j++) acc[j] = 0.f;

  const float* wp = W + c;
  #pragma unroll 2
  for (int k0 = 0; k0 < 128; k0 += 4) {
    float w0 = wp[(size_t)(k0 + 0) * DOUT];
    float w1 = wp[(size_t)(k0 + 1) * DOUT];
    float w2 = wp[(size_t)(k0 + 2) * DOUT];
    float w3 = wp[(size_t)(k0 + 3) * DOUT];
    #pragma unroll
    for (int j = 0; j < RPT; j++) {
      float4 xv = *(const float4*)&xs[rg * RPT + j][k0];
      acc[j] = fmaf(xv.x, w0, fmaf(xv.y, w1, fmaf(xv.z, w2, fmaf(xv.w, w3, acc[j]))));
    }
  }

  #pragma unroll
  for (int j = 0; j < RPT; j++) {
    int gr = row0 + rg * RPT + j;
    if (gr < N) h[(size_t)gr * DOUT + c] = __float2bfloat16(acc[j]);
  }
  int cc = c & 31, hh = c >> 5;
  float asv = a_s[hh * 32 + cc];
  float adv = a_d[hh * 32 + cc];
  #pragma unroll
  for (int j = 0; j < RPT; j++) {
    float ps = acc[j] * asv;
    float pd = acc[j] * adv;
    #pragma unroll
    for (int off = 16; off; off >>= 1) {
      ps += __shfl_xor(ps, off, 32);
      pd += __shfl_xor(pd, off, 32);
    }
    if (cc == 0) {
      int gr = row0 + rg * RPT + j;
      if (gr < N) { als[(size_t)gr * HEADS + hh] = ps; ald[(size_t)gr * HEADS + hh] = pd; }
    }
  }
}

// ---------------- aggregation, H=4 C=32, wave per dst node, bf16 h ----------------
__global__ __launch_bounds__(256) void k_agg4(const __hip_bfloat16* __restrict__ h, const float* __restrict__ als,
    const float* __restrict__ ald, const int* __restrict__ rs, const int* __restrict__ col,
    const float* __restrict__ bias, const float* __restrict__ bng,
    const float* __restrict__ bnb, const float* __restrict__ bnm,
    const float* __restrict__ bnv, float* __restrict__ out, int N) {
  __shared__ int svs[4][64];
  __shared__ float alps[4][64][4];
  int lane = threadIdx.x & 63;
  int w = threadIdx.x >> 6;
  int n = blockIdx.x * 4 + w;
  if (n >= N) return;
  int row = rs[n], deg = rs[n + 1] - row;
  float4 ad4 = *(const float4*)(ald + (size_t)n * 4);

  // pass 1: exp (no max-sub: logits are O(10), f32-safe), keep chunk-0 p in regs
  float s0 = 0.f, s1 = 0.f, s2 = 0.f, s3 = 0.f;
  float p0 = 0.f, p1 = 0.f, p2 = 0.f, p3 = 0.f;
  int sv0 = 0;
  for (int base = 0; base < deg; base += 64) {
    int k = base + lane;
    int sv = 0; float q0 = 0.f, q1 = 0.f, q2 = 0.f, q3 = 0.f;
    if (k < deg) {
      sv = col[row + k];
      float4 a4 = *(const float4*)(als + (size_t)sv * 4);
      q0 = __expf(lrelu(a4.x + ad4.x));
      q1 = __expf(lrelu(a4.y + ad4.y));
      q2 = __expf(lrelu(a4.z + ad4.z));
      q3 = __expf(lrelu(a4.w + ad4.w));
    }
    if (base == 0) { sv0 = sv; p0 = q0; p1 = q1; p2 = q2; p3 = q3; }
    s0 += q0; s1 += q1; s2 += q2; s3 += q3;
  }
  #pragma unroll
  for (int off = 32; off; off >>= 1) {
    s0 += __shfl_xor(s0, off); s1 += __shfl_xor(s1, off);
    s2 += __shfl_xor(s2, off); s3 += __shfl_xor(s3, off);
  }
  float i0 = 1.f / (s0 + 1e-16f), i1 = 1.f / (s1 + 1e-16f);
  float i2 = 1.f / (s2 + 1e-16f), i3 = 1.f / (s3 + 1e-16f);

  int hh = lane >> 4;       // head of channel pair c0=2*lane
  float acc0 = 0.f, acc1 = 0.f;
  for (int base = 0; base < deg; base += 64) {
    int cnt = min(64, deg - base);
    int sv; float a0, a1, a2, a3;
    if (base == 0) {
      sv = sv0; a0 = p0 * i0; a1 = p1 * i1; a2 = p2 * i2; a3 = p3 * i3;
    } else {
      int k = base + lane;
      sv = 0; a0 = a1 = a2 = a3 = 0.f;
      if (k < deg) {
        sv = col[row + k];
        float4 a4 = *(const float4*)(als + (size_t)sv * 4);
        a0 = __expf(lrelu(a4.x + ad4.x)) * i0;
        a1 = __expf(lrelu(a4.y + ad4.y)) * i1;
        a2 = __expf(lrelu(a4.z + ad4.z)) * i2;
        a3 = __expf(lrelu(a4.w + ad4.w)) * i3;
      }
    }
    svs[w][lane] = sv;
    *(float4*)&alps[w][lane][0] = make_float4(a0, a1, a2, a3);
    // wave-synchronous LDS (no barrier needed; [w]-private)
    for (int k2 = 0; k2 < cnt; k2 += 4) {
      #pragma unroll
      for (int i = 0; i < 4; i++) {
        int ee = k2 + i;
        int e = min(ee, 63);
        float alpha = (ee < cnt) ? alps[w][e][hh] : 0.f;
        int s_ = svs[w][e];
        unsigned int hv = *((const unsigned int*)(h + (size_t)s_ * 128) + lane);
        float lo = __uint_as_float(hv << 16);
        float hi_ = __uint_as_float(hv & 0xFFFF0000u);
        acc0 = fmaf(alpha, lo, acc0);
        acc1 = fmaf(alpha, hi_, acc1);
      }
    }
  }
  int c0 = 2 * lane;
  float v0 = acc0 + bias[c0];
  float v1 = acc1 + bias[c0 + 1];
  v0 = (v0 - bnm[c0]) * rsqrtf(bnv[c0] + BN_EPS) * bng[c0] + bnb[c0];
  v1 = (v1 - bnm[c0 + 1]) * rsqrtf(bnv[c0 + 1] + BN_EPS) * bng[c0 + 1] + bnb[c0 + 1];
  v0 = v0 > 0.f ? v0 : expm1f(v0);
  v1 = v1 > 0.f ? v1 : expm1f(v1);
  *(float2*)(out + (size_t)n * 128 + c0) = make_float2(v0, v1);
}

// ---------------- aggregation, H=1 C=32, wave per dst node, bf16 h ----------------
__global__ __launch_bounds__(256) void k_agg1(const __hip_bfloat16* __restrict__ h, const float* __restrict__ als,
    const float* __restrict__ ald, const int* __restrict__ rs, const int* __restrict__ col,
    const float* __restrict__ bias, const float* __restrict__ bng,
    const float* __restrict__ bnb, const float* __restrict__ bnm,
    const float* __restrict__ bnv, float* __restrict__ out, int N) {
  __shared__ int svs[4][64];
  __shared__ float alp[4][64];
  int lane = threadIdx.x & 63;
  int w = threadIdx.x >> 6;
  int n = blockIdx.x * 4 + w;
  if (n >= N) return;
  int row = rs[n], deg = rs[n + 1] - row;
  float ad = ald[n];

  float s = 0.f, p = 0.f;
  int sv0 = 0;
  for (int base = 0; base < deg; base += 64) {
    int k = base + lane;
    int sv = 0; float q = 0.f;
    if (k < deg) {
      sv = col[row + k];
      q = __expf(lrelu(als[sv] + ad));
    }
    if (base == 0) { sv0 = sv; p = q; }
    s += q;
  }
  #pragma unroll
  for (int off = 32; off; off >>= 1) s += __shfl_xor(s, off);
  float inv = 1.f / (s + 1e-16f);

  int c = lane & 31, eh = lane >> 5;   // half-wave handles alternating edges
  float acc = 0.f;
  for (int base = 0; base < deg; base += 64) {
    int cnt = min(64, deg - base);
    int sv; float a;
    if (base == 0) { sv = sv0; a = p * inv; }
    else {
      int k = base + lane;
      sv = 0; a = 0.f;
      if (k < deg) { sv = col[row + k]; a = __expf(lrelu(als[sv] + ad)) * inv; }
    }
    svs[w][lane] = sv;
    alp[w][lane] = a;
    for (int k2 = 0; k2 < cnt; k2 += 4) {
      int ee0 = k2 + eh, ee1 = k2 + 2 + eh;
      int e0 = min(ee0, 63), e1 = min(ee1, 63);
      float a0 = (ee0 < cnt) ? alp[w][e0] : 0.f;
      float a1 = (ee1 < cnt) ? alp[w][e1] : 0.f;
      int s0v = svs[w][e0], s1v = svs[w][e1];
      float h0 = b2f(h[(size_t)s0v * 32 + c]);
      float h1 = b2f(h[(size_t)s1v * 32 + c]);
      acc = fmaf(a0, h0, fmaf(a1, h1, acc));
    }
  }
  acc += __shfl_xor(acc, 32);
  if (lane < 32) {
    float v = acc + bias[c];
    v = (v - bnm[c]) * rsqrtf(bnv[c] + BN_EPS) * bng[c] + bnb[c];
    v = v > 0.f ? v : expm1f(v);
    out[(size_t)n * 32 + c] = v;
  }
}

// ---------------- per-graph pooling + MLP head (FLOAT32 output) ----------------
__global__ __launch_bounds__(64) void k_pool(const float* __restrict__ x3, const int* __restrict__ batch,
    const float* __restrict__ u, const float* __restrict__ l1w,
    const float* __restrict__ l1b, const float* __restrict__ l2w,
    const float* __restrict__ l2b, float* __restrict__ out, int N, int G) {
  int g = blockIdx.x;
  int lane = threadIdx.x;
  int lo = 0, hi = N;
  while (lo < hi) { int mid = (lo + hi) >> 1; if (batch[mid] < g) lo = mid + 1; else hi = mid; }
  int start = lo;
  hi = N;
  while (lo < hi) { int mid = (lo + hi) >> 1; if (batch[mid] < g + 1) lo = mid + 1; else hi = mid; }
  int end = lo;
  int c = lane & 31, half = lane >> 5;
  float sum = 0.f, mx = -1e30f;
  for (int i = start + half; i < end; i += 2) {
    float v = x3[(size_t)i * 32 + c];
    sum += v; mx = fmaxf(mx, v);
  }
  sum += __shfl_xor(sum, 32);
  mx = fmaxf(mx, __shfl_xor(mx, 32));
  __shared__ float comb[74];
  if (lane < 32) {
    float cnt = (float)(end - start);
    comb[lane] = sum / cnt;
    comb[32 + lane] = mx;
  }
  if (lane < 10) comb[64 + lane] = u[g * 10 + lane];
  __syncthreads();
  if (lane < 32) {
    float acc = l1b[lane];
    #pragma unroll
    for (int k = 0; k < 74; k++) acc = fmaf(comb[k], l1w[k * 32 + lane], acc);
    acc = fmaxf(acc, 0.f);                       // ReLU
    float v = acc * l2w[lane];
    #pragma unroll
    for (int off = 16; off; off >>= 1) v += __shfl_xor(v, off, 32);
    if (lane == 0) out[g] = 1.f / (1.f + __expf(-(v + l2b[0])));
  }
}

extern "C" void kernel_launch(void* const* d_in, const int* in_sizes, int n_in,
                              void* d_out, int out_size, void* d_ws, size_t ws_size,
                              hipStream_t stream) {
  const int* EI    = (const int*)d_in[1];
  const int* BATCH = (const int*)d_in[2];
  float* OUT = (float*)d_out;            // reference returns float32

  int N = in_sizes[2];          // batch has N elements
  int E = in_sizes[1] / 2;      // edge_index is [2,E]
  int G = in_sizes[3] / 10;     // u is [G,10]
  int EN = E + N;

  char* ws = (char*)d_ws;
  size_t off = 0;
  auto alloc = [&](size_t bytes) {
    void* p = ws + off;
    off = (off + bytes + 255) & ~(size_t)255;
    return p;
  };
  float* f_xa  = (float*)alloc((size_t)N * 128 * 4);
  __hip_bfloat16* f_h = (__hip_bfloat16*)alloc((size_t)N * 128 * 2);
  float* f_als = (float*)alloc((size_t)N * 4 * 4);
  float* f_ald = (float*)alloc((size_t)N * 4 * 4);
  int* i_deg = (int*)alloc((size_t)(N + 1) * 4);
  int* i_rs  = (int*)alloc((size_t)(N + 1) * 4);
  int* i_cur = (int*)alloc((size_t)N * 4);
  int* i_col = (int*)alloc((size_t)EN * 4);
  int* i_flag = (int*)alloc(256);

  // f32 copies of all 30 float inputs (skip d_in[1], d_in[2] = ints)
  CvtArgs ca;
  float* fptr[32];
  int maxn = 0, na = 0;
  for (int i = 0; i < 32; i++) {
    if (i == 1 || i == 2) { fptr[i] = nullptr; continue; }
    int n = in_sizes[i];
    fptr[i] = (float*)alloc((size_t)n * 4);
    ca.src[na] = d_in[i];
    ca.dst[na] = fptr[i];
    ca.n[na] = n;
    if (n > maxn) maxn = n;
    na++;
  }

  // dtype detect + convert
  k_detect<<<1, 256, 0, stream>>>((const unsigned short*)d_in[12], in_sizes[12], i_flag);
  dim3 cgrid((maxn + 255) / 256, na);
  k_cvt_all<<<cgrid, 256, 0, stream>>>(ca, i_flag);

  // CSR build
  hipMemsetAsync(i_deg, 0, (size_t)N * 4, stream);
  k_count<<<(EN + 255) / 256, 256, 0, stream>>>(EI, i_deg, E, N);
  k_scan<<<1, 1024, 0, stream>>>(i_deg, i_rs, i_cur, N);
  k_scatter<<<(EN + 255) / 256, 256, 0, stream>>>(EI, i_cur, i_col, E, N);

  // layer 0
  k_gemm0<<<(N * 128 + 255) / 256, 256, 0, stream>>>(fptr[0], fptr[4], fptr[5], fptr[6], f_h, f_als, f_ald, N);
  k_agg4<<<(N + 3) / 4, 256, 0, stream>>>(f_h, f_als, f_ald, i_rs, i_col, fptr[7], fptr[8], fptr[9], fptr[10], fptr[11], f_xa, N);
  // layer 1  (32 rows per block)
  k_gemm_v2<128, 4><<<(N + 31) / 32, 256, 0, stream>>>(f_xa, fptr[12], fptr[13], fptr[14], f_h, f_als, f_ald, N);
  k_agg4<<<(N + 3) / 4, 256, 0, stream>>>(f_h, f_als, f_ald, i_rs, i_col, fptr[15], fptr[16], fptr[17], fptr[18], fptr[19], f_xa, N);
  // layer 2  (128 rows per block)
  k_gemm_v2<32, 1><<<(N + 127) / 128, 256, 0, stream>>>(f_xa, fptr[20], fptr[21], fptr[22], f_h, f_als, f_ald, N);
  k_agg1<<<(N + 3) / 4, 256, 0, stream>>>(f_h, f_als, f_ald, i_rs, i_col, fptr[23], fptr[24], fptr[25], fptr[26], fptr[27], f_xa, N);

  // pooling + MLP head
  k_pool<<<G, 64, 0, stream>>>(f_xa, BATCH, fptr[3], fptr[28], fptr[29], fptr[30], fptr[31], OUT, N, G);
}

// Round 7
// 350.200 us; speedup vs baseline: 1.7019x; 1.1356x over previous
//
#include <hip/hip_runtime.h>
#include <hip/hip_bf16.h>
#include <math.h>

#define LRELU_NEG 0.2f
#define BN_EPS 1e-5f

typedef __attribute__((ext_vector_type(8))) short bf16x8;
typedef __attribute__((ext_vector_type(4))) float f32x4;

__device__ __forceinline__ float lrelu(float x) { return x > 0.f ? x : LRELU_NEG * x; }
__device__ __forceinline__ float b2f(__hip_bfloat16 v) { return __bfloat162float(v); }
__device__ __forceinline__ unsigned short f2bu(float v) {
  __hip_bfloat16 b = __float2bfloat16(v);
  return *(unsigned short*)&b;
}

// ---------------- dtype detection: are float inputs bf16 or f32? ----------------
__global__ __launch_bounds__(256) void k_detect(const unsigned short* __restrict__ w, int n,
                                                int* __restrict__ flag) {
  __shared__ int bad_s;
  if (threadIdx.x == 0) bad_s = 0;
  __syncthreads();
  int bad = 0;
  for (int i = 2 * threadIdx.x; i < n; i += 512) {
    unsigned short u = w[i];
    if ((u & 0x7FFF) == 0) continue;
    int ex = (u >> 7) & 0xFF;
    if (ex > 131 || ex < 90) bad++;
  }
  atomicAdd(&bad_s, bad);
  __syncthreads();
  if (threadIdx.x == 0) *flag = (bad_s < 2048) ? 1 : 0;   // 1 = inputs are bf16
}

// ---------------- unified input conversion -> f32 in ws ----------------
struct CvtArgs {
  const void* src[30];
  float* dst[30];
  int n[30];
};

__global__ __launch_bounds__(256) void k_cvt_all(CvtArgs a, const int* __restrict__ flag) {
  int ai = blockIdx.y;
  int n = a.n[ai];
  int i = blockIdx.x * 256 + threadIdx.x;
  if (i >= n) return;
  if (*flag) {
    a.dst[ai][i] = b2f(((const __hip_bfloat16*)a.src[ai])[i]);
  } else {
    a.dst[ai][i] = ((const float*)a.src[ai])[i];
  }
}

// ---------------- weight folding: W' = [W | W a_s | W a_d], transposed bf16 ----------------
__global__ __launch_bounds__(256) void k_foldW(const float* __restrict__ W0, const float* __restrict__ as0, const float* __restrict__ ad0,
                                               const float* __restrict__ W1, const float* __restrict__ as1, const float* __restrict__ ad1,
                                               const float* __restrict__ W2, const float* __restrict__ as2, const float* __restrict__ ad2,
                                               float* __restrict__ W0p, __hip_bfloat16* __restrict__ Wt1, __hip_bfloat16* __restrict__ Wt2) {
  int idx = blockIdx.x * 256 + threadIdx.x;
  if (idx < 576) {                  // W0p [4][144] f32 (row-major, K=4)
    int k = idx / 144, c = idx % 144;
    float v = 0.f;
    if (c < 128) v = W0[k * 128 + c];
    else if (c < 136) {
      int hh = (c - 128) & 3; const float* a = (c < 132) ? as0 : ad0;
      float s = 0.f;
      for (int cc = 0; cc < 32; cc++) s += W0[k * 128 + hh * 32 + cc] * a[hh * 32 + cc];
      v = s;
    }
    W0p[k * 144 + c] = v;
    return;
  }
  idx -= 576;
  if (idx < 144 * 128) {            // Wt1 [144 cols][128 k] bf16 (transposed)
    int c = idx >> 7, k = idx & 127;
    float v = 0.f;
    if (c < 128) v = W1[k * 128 + c];
    else if (c < 136) {
      int hh = (c - 128) & 3; const float* a = (c < 132) ? as1 : ad1;
      float s = 0.f;
      for (int cc = 0; cc < 32; cc++) s += W1[k * 128 + hh * 32 + cc] * a[hh * 32 + cc];
      v = s;
    }
    Wt1[c * 128 + k] = __float2bfloat16(v);
    return;
  }
  idx -= 144 * 128;
  if (idx < 48 * 128) {             // Wt2 [48 cols][128 k] bf16
    int c = idx >> 7, k = idx & 127;
    float v = 0.f;
    if (c < 32) v = W2[k * 32 + c];
    else if (c == 32) { float s = 0.f; for (int cc = 0; cc < 32; cc++) s += W2[k * 32 + cc] * as2[cc]; v = s; }
    else if (c == 33) { float s = 0.f; for (int cc = 0; cc < 32; cc++) s += W2[k * 32 + cc] * ad2[cc]; v = s; }
    Wt2[c * 128 + k] = __float2bfloat16(v);
  }
}

// ---------------- CSR build ----------------
__global__ void k_count(const int* __restrict__ ei, int* __restrict__ deg, int E, int N) {
  int e = blockIdx.x * 256 + threadIdx.x;
  if (e >= E + N) return;
  int dst = (e < E) ? ei[E + e] : (e - E);   // self-loops appended
  atomicAdd(&deg[dst], 1);
}

__global__ __launch_bounds__(1024) void k_scan(const int* __restrict__ deg, int* __restrict__ rs,
                                               int* __restrict__ cur, int N) {
  __shared__ int wpre[16];
  __shared__ int running_s;
  int tid = threadIdx.x, lane = tid & 63, wid = tid >> 6;
  if (tid == 0) running_s = 0;
  __syncthreads();
  for (int base = 0; base <= N; base += 1024) {
    int idx = base + tid;
    int v = (idx < N) ? deg[idx] : 0;
    int x = v;
    #pragma unroll
    for (int off = 1; off < 64; off <<= 1) {
      int y = __shfl_up(x, off);
      if (lane >= off) x += y;
    }
    if (lane == 63) wpre[wid] = x;
    __syncthreads();
    if (tid == 0) {
      int acc = running_s;
      #pragma unroll
      for (int w = 0; w < 16; w++) { int t = wpre[w]; wpre[w] = acc; acc += t; }
      running_s = acc;
    }
    __syncthreads();
    int excl = wpre[wid] + x - v;
    if (idx <= N) rs[idx] = excl;
    if (idx < N) cur[idx] = excl;
    __syncthreads();
  }
}

__global__ void k_scatter(const int* __restrict__ ei, int* __restrict__ cur,
                          int* __restrict__ col, int E, int N) {
  int e = blockIdx.x * 256 + threadIdx.x;
  if (e >= E + N) return;
  int src, dst;
  if (e < E) { src = ei[e]; dst = ei[E + e]; }
  else       { src = e - E; dst = e - E; }
  int pos = atomicAdd(&cur[dst], 1);
  col[pos] = src;
}

// ---------------- layer-0 GEMM (K=4), folded logits ----------------
__global__ __launch_bounds__(256) void k_gemm0(const float* __restrict__ x, const float* __restrict__ W0p,
    __hip_bfloat16* __restrict__ h, float* __restrict__ als, float* __restrict__ ald, int N) {
  int t = blockIdx.x * 256 + threadIdx.x;
  int nrow = t / 144, c = t - nrow * 144;
  if (nrow >= N || c >= 136) return;
  float4 xv = *(const float4*)(x + (size_t)nrow * 4);
  float acc = fmaf(xv.x, W0p[c], fmaf(xv.y, W0p[144 + c], fmaf(xv.z, W0p[288 + c], xv.w * W0p[432 + c])));
  if (c < 128)      h[(size_t)nrow * 128 + c] = __float2bfloat16(acc);
  else if (c < 132) als[(size_t)nrow * 4 + (c - 128)] = acc;
  else              ald[(size_t)nrow * 4 + (c - 132)] = acc;
}

// ---------------- MFMA GEMM: h/als/ald = xa @ [W | Wa_s | Wa_d]  ----------------
// A = xa bf16 [N][128]; B = Wt bf16 [CT*16 cols][128 k] (pre-transposed).
// 64 rows/block, 4 waves (wave w -> rows w*16..+15). XOR-swizzled LDS (slot ^= row&7).
template <int CT, int DOUT, int HEADS>
__global__ __launch_bounds__(256) void k_mm(const __hip_bfloat16* __restrict__ xa,
    const __hip_bfloat16* __restrict__ Wt,
    __hip_bfloat16* __restrict__ h, float* __restrict__ als, float* __restrict__ ald, int N) {
  __shared__ unsigned short A_s[64 * 128];
  __shared__ unsigned short B_s[CT * 16 * 128];
  int tid = threadIdx.x;
  int row0 = blockIdx.x * 64;

  // stage A (64 rows x 128 bf16 = 1024 float4 chunks), swizzled
  for (int i = tid; i < 1024; i += 256) {
    int r = i >> 4, slot = i & 15;
    int gr = row0 + r;
    float4 v = make_float4(0.f, 0.f, 0.f, 0.f);
    if (gr < N) v = ((const float4*)(xa + (size_t)gr * 128))[slot];
    *(float4*)((char*)A_s + r * 256 + ((slot ^ (r & 7)) << 4)) = v;
  }
  // stage B (CT*16 rows x 128 bf16), swizzled; Wt row-major -> coalesced
  for (int i = tid; i < CT * 256; i += 256) {
    int r = i >> 4, slot = i & 15;
    float4 v = ((const float4*)Wt)[i];
    *(float4*)((char*)B_s + r * 256 + ((slot ^ (r & 7)) << 4)) = v;
  }
  __syncthreads();

  int l = tid & 63, w = tid >> 6;
  int lr = l & 15, lg = l >> 4;
  f32x4 acc[CT];
  #pragma unroll
  for (int ct = 0; ct < CT; ct++) acc[ct] = (f32x4){0.f, 0.f, 0.f, 0.f};

  int rA = w * 16 + lr;
  #pragma unroll
  for (int k0 = 0; k0 < 4; k0++) {
    int slot = k0 * 4 + lg;
    bf16x8 a = *(const bf16x8*)((const char*)A_s + rA * 256 + ((slot ^ (rA & 7)) << 4));
    #pragma unroll
    for (int ct = 0; ct < CT; ct++) {
      int rB = ct * 16 + lr;
      bf16x8 b = *(const bf16x8*)((const char*)B_s + rB * 256 + ((slot ^ (rB & 7)) << 4));
      acc[ct] = __builtin_amdgcn_mfma_f32_16x16x32_bf16(a, b, acc[ct], 0, 0, 0);
    }
  }

  // epilogue: D layout col=lane&15, row=(lane>>4)*4+reg (m89-verified)
  #pragma unroll
  for (int ct = 0; ct < CT; ct++) {
    #pragma unroll
    for (int j = 0; j < 4; j++) {
      int gr = row0 + w * 16 + lg * 4 + j;
      if (gr >= N) continue;
      int col = ct * 16 + lr;
      float v = acc[ct][j];
      if (col < DOUT)                 h[(size_t)gr * DOUT + col] = __float2bfloat16(v);
      else if (col < DOUT + HEADS)    als[(size_t)gr * HEADS + (col - DOUT)] = v;
      else if (col < DOUT + 2*HEADS)  ald[(size_t)gr * HEADS + (col - DOUT - HEADS)] = v;
    }
  }
}

// ---------------- aggregation, H=4 C=32, wave per dst node, bf16 h, bf16 out ----------------
__global__ __launch_bounds__(256) void k_agg4(const __hip_bfloat16* __restrict__ h, const float* __restrict__ als,
    const float* __restrict__ ald, const int* __restrict__ rs, const int* __restrict__ col,
    const float* __restrict__ bias, const float* __restrict__ bng,
    const float* __restrict__ bnb, const float* __restrict__ bnm,
    const float* __restrict__ bnv, __hip_bfloat16* __restrict__ out, int N) {
  __shared__ int svs[4][64];
  __shared__ float alps[4][64][4];
  int lane = threadIdx.x & 63;
  int w = threadIdx.x >> 6;
  int n = blockIdx.x * 4 + w;
  if (n >= N) return;
  int row = rs[n], deg = rs[n + 1] - row;
  float4 ad4 = *(const float4*)(ald + (size_t)n * 4);

  float s0 = 0.f, s1 = 0.f, s2 = 0.f, s3 = 0.f;
  float p0 = 0.f, p1 = 0.f, p2 = 0.f, p3 = 0.f;
  int sv0 = 0;
  for (int base = 0; base < deg; base += 64) {
    int k = base + lane;
    int sv = 0; float q0 = 0.f, q1 = 0.f, q2 = 0.f, q3 = 0.f;
    if (k < deg) {
      sv = col[row + k];
      float4 a4 = *(const float4*)(als + (size_t)sv * 4);
      q0 = __expf(lrelu(a4.x + ad4.x));
      q1 = __expf(lrelu(a4.y + ad4.y));
      q2 = __expf(lrelu(a4.z + ad4.z));
      q3 = __expf(lrelu(a4.w + ad4.w));
    }
    if (base == 0) { sv0 = sv; p0 = q0; p1 = q1; p2 = q2; p3 = q3; }
    s0 += q0; s1 += q1; s2 += q2; s3 += q3;
  }
  #pragma unroll
  for (int off = 32; off; off >>= 1) {
    s0 += __shfl_xor(s0, off); s1 += __shfl_xor(s1, off);
    s2 += __shfl_xor(s2, off); s3 += __shfl_xor(s3, off);
  }
  float i0 = 1.f / (s0 + 1e-16f), i1 = 1.f / (s1 + 1e-16f);
  float i2 = 1.f / (s2 + 1e-16f), i3 = 1.f / (s3 + 1e-16f);

  int hh = lane >> 4;
  float acc0 = 0.f, acc1 = 0.f;
  for (int base = 0; base < deg; base += 64) {
    int cnt = min(64, deg - base);
    int sv; float a0, a1, a2, a3;
    if (base == 0) {
      sv = sv0; a0 = p0 * i0; a1 = p1 * i1; a2 = p2 * i2; a3 = p3 * i3;
    } else {
      int k = base + lane;
      sv = 0; a0 = a1 = a2 = a3 = 0.f;
      if (k < deg) {
        sv = col[row + k];
        float4 a4 = *(const float4*)(als + (size_t)sv * 4);
        a0 = __expf(lrelu(a4.x + ad4.x)) * i0;
        a1 = __expf(lrelu(a4.y + ad4.y)) * i1;
        a2 = __expf(lrelu(a4.z + ad4.z)) * i2;
        a3 = __expf(lrelu(a4.w + ad4.w)) * i3;
      }
    }
    svs[w][lane] = sv;
    *(float4*)&alps[w][lane][0] = make_float4(a0, a1, a2, a3);
    for (int k2 = 0; k2 < cnt; k2 += 4) {
      #pragma unroll
      for (int i = 0; i < 4; i++) {
        int ee = k2 + i;
        int e = min(ee, 63);
        float alpha = (ee < cnt) ? alps[w][e][hh] : 0.f;
        int s_ = svs[w][e];
        unsigned int hv = *((const unsigned int*)(h + (size_t)s_ * 128) + lane);
        float lo = __uint_as_float(hv << 16);
        float hi_ = __uint_as_float(hv & 0xFFFF0000u);
        acc0 = fmaf(alpha, lo, acc0);
        acc1 = fmaf(alpha, hi_, acc1);
      }
    }
  }
  int c0 = 2 * lane;
  float v0 = acc0 + bias[c0];
  float v1 = acc1 + bias[c0 + 1];
  v0 = (v0 - bnm[c0]) * rsqrtf(bnv[c0] + BN_EPS) * bng[c0] + bnb[c0];
  v1 = (v1 - bnm[c0 + 1]) * rsqrtf(bnv[c0 + 1] + BN_EPS) * bng[c0 + 1] + bnb[c0 + 1];
  v0 = v0 > 0.f ? v0 : expm1f(v0);
  v1 = v1 > 0.f ? v1 : expm1f(v1);
  unsigned int packed = ((unsigned int)f2bu(v1) << 16) | f2bu(v0);
  *(unsigned int*)((unsigned short*)out + (size_t)n * 128 + c0) = packed;
}

// ---------------- aggregation, H=1 C=32, wave per dst node, bf16 h, bf16 out ----------------
__global__ __launch_bounds__(256) void k_agg1(const __hip_bfloat16* __restrict__ h, const float* __restrict__ als,
    const float* __restrict__ ald, const int* __restrict__ rs, const int* __restrict__ col,
    const float* __restrict__ bias, const float* __restrict__ bng,
    const float* __restrict__ bnb, const float* __restrict__ bnm,
    const float* __restrict__ bnv, __hip_bfloat16* __restrict__ out, int N) {
  __shared__ int svs[4][64];
  __shared__ float alp[4][64];
  int lane = threadIdx.x & 63;
  int w = threadIdx.x >> 6;
  int n = blockIdx.x * 4 + w;
  if (n >= N) return;
  int row = rs[n], deg = rs[n + 1] - row;
  float ad = ald[n];

  float s = 0.f, p = 0.f;
  int sv0 = 0;
  for (int base = 0; base < deg; base += 64) {
    int k = base + lane;
    int sv = 0; float q = 0.f;
    if (k < deg) {
      sv = col[row + k];
      q = __expf(lrelu(als[sv] + ad));
    }
    if (base == 0) { sv0 = sv; p = q; }
    s += q;
  }
  #pragma unroll
  for (int off = 32; off; off >>= 1) s += __shfl_xor(s, off);
  float inv = 1.f / (s + 1e-16f);

  int c = lane & 31, eh = lane >> 5;
  float acc = 0.f;
  for (int base = 0; base < deg; base += 64) {
    int cnt = min(64, deg - base);
    int sv; float a;
    if (base == 0) { sv = sv0; a = p * inv; }
    else {
      int k = base + lane;
      sv = 0; a = 0.f;
      if (k < deg) { sv = col[row + k]; a = __expf(lrelu(als[sv] + ad)) * inv; }
    }
    svs[w][lane] = sv;
    alp[w][lane] = a;
    for (int k2 = 0; k2 < cnt; k2 += 4) {
      int ee0 = k2 + eh, ee1 = k2 + 2 + eh;
      int e0 = min(ee0, 63), e1 = min(ee1, 63);
      float a0 = (ee0 < cnt) ? alp[w][e0] : 0.f;
      float a1 = (ee1 < cnt) ? alp[w][e1] : 0.f;
      int s0v = svs[w][e0], s1v = svs[w][e1];
      float h0 = b2f(h[(size_t)s0v * 32 + c]);
      float h1 = b2f(h[(size_t)s1v * 32 + c]);
      acc = fmaf(a0, h0, fmaf(a1, h1, acc));
    }
  }
  acc += __shfl_xor(acc, 32);
  if (lane < 32) {
    float v = acc + bias[c];
    v = (v - bnm[c]) * rsqrtf(bnv[c] + BN_EPS) * bng[c] + bnb[c];
    v = v > 0.f ? v : expm1f(v);
    out[(size_t)n * 32 + c] = __float2bfloat16(v);
  }
}

// ---------------- per-graph pooling + MLP head (bf16 x3, FLOAT32 output) ----------------
__global__ __launch_bounds__(64) void k_pool(const __hip_bfloat16* __restrict__ x3, const int* __restrict__ batch,
    const float* __restrict__ u, const float* __restrict__ l1w,
    const float* __restrict__ l1b, const float* __restrict__ l2w,
    const float* __restrict__ l2b, float* __restrict__ out, int N, int G) {
  int g = blockIdx.x;
  int lane = threadIdx.x;
  int lo = 0, hi = N;
  while (lo < hi) { int mid = (lo + hi) >> 1; if (batch[mid] < g) lo = mid + 1; else hi = mid; }
  int start = lo;
  hi = N;
  while (lo < hi) { int mid = (lo + hi) >> 1; if (batch[mid] < g + 1) lo = mid + 1; else hi = mid; }
  int end = lo;
  int c = lane & 31, half = lane >> 5;
  float sum = 0.f, mx = -1e30f;
  for (int i = start + half; i < end; i += 2) {
    float v = b2f(x3[(size_t)i * 32 + c]);
    sum += v; mx = fmaxf(mx, v);
  }
  sum += __shfl_xor(sum, 32);
  mx = fmaxf(mx, __shfl_xor(mx, 32));
  __shared__ float comb[74];
  if (lane < 32) {
    float cnt = (float)(end - start);
    comb[lane] = sum / cnt;
    comb[32 + lane] = mx;
  }
  if (lane < 10) comb[64 + lane] = u[g * 10 + lane];
  __syncthreads();
  if (lane < 32) {
    float acc = l1b[lane];
    #pragma unroll
    for (int k = 0; k < 74; k++) acc = fmaf(comb[k], l1w[k * 32 + lane], acc);
    acc = fmaxf(acc, 0.f);
    float v = acc * l2w[lane];
    #pragma unroll
    for (int off = 16; off; off >>= 1) v += __shfl_xor(v, off, 32);
    if (lane == 0) out[g] = 1.f / (1.f + __expf(-(v + l2b[0])));
  }
}

extern "C" void kernel_launch(void* const* d_in, const int* in_sizes, int n_in,
                              void* d_out, int out_size, void* d_ws, size_t ws_size,
                              hipStream_t stream) {
  const int* EI    = (const int*)d_in[1];
  const int* BATCH = (const int*)d_in[2];
  float* OUT = (float*)d_out;

  int N = in_sizes[2];
  int E = in_sizes[1] / 2;
  int G = in_sizes[3] / 10;
  int EN = E + N;

  char* ws = (char*)d_ws;
  size_t off = 0;
  auto alloc = [&](size_t bytes) {
    void* p = ws + off;
    off = (off + bytes + 255) & ~(size_t)255;
    return p;
  };
  __hip_bfloat16* f_xa = (__hip_bfloat16*)alloc((size_t)N * 128 * 2);
  __hip_bfloat16* f_h  = (__hip_bfloat16*)alloc((size_t)N * 128 * 2);
  float* f_als = (float*)alloc((size_t)N * 4 * 4);
  float* f_ald = (float*)alloc((size_t)N * 4 * 4);
  float* fW0p  = (float*)alloc(576 * 4);
  __hip_bfloat16* fWt1 = (__hip_bfloat16*)alloc(144 * 128 * 2);
  __hip_bfloat16* fWt2 = (__hip_bfloat16*)alloc(48 * 128 * 2);
  int* i_deg = (int*)alloc((size_t)(N + 1) * 4);
  int* i_rs  = (int*)alloc((size_t)(N + 1) * 4);
  int* i_cur = (int*)alloc((size_t)N * 4);
  int* i_col = (int*)alloc((size_t)EN * 4);
  int* i_flag = (int*)alloc(256);

  // f32 copies of all 30 float inputs (skip d_in[1], d_in[2] = ints)
  CvtArgs ca;
  float* fptr[32];
  int maxn = 0, na = 0;
  for (int i = 0; i < 32; i++) {
    if (i == 1 || i == 2) { fptr[i] = nullptr; continue; }
    int n = in_sizes[i];
    fptr[i] = (float*)alloc((size_t)n * 4);
    ca.src[na] = d_in[i];
    ca.dst[na] = fptr[i];
    ca.n[na] = n;
    if (n > maxn) maxn = n;
    na++;
  }

  // dtype detect + convert
  k_detect<<<1, 256, 0, stream>>>((const unsigned short*)d_in[12], in_sizes[12], i_flag);
  dim3 cgrid((maxn + 255) / 256, na);
  k_cvt_all<<<cgrid, 256, 0, stream>>>(ca, i_flag);

  // weight folding (after cvt)
  k_foldW<<<99, 256, 0, stream>>>(fptr[4], fptr[5], fptr[6],
                                  fptr[12], fptr[13], fptr[14],
                                  fptr[20], fptr[21], fptr[22],
                                  fW0p, fWt1, fWt2);

  // CSR build
  hipMemsetAsync(i_deg, 0, (size_t)N * 4, stream);
  k_count<<<(EN + 255) / 256, 256, 0, stream>>>(EI, i_deg, E, N);
  k_scan<<<1, 1024, 0, stream>>>(i_deg, i_rs, i_cur, N);
  k_scatter<<<(EN + 255) / 256, 256, 0, stream>>>(EI, i_cur, i_col, E, N);

  // layer 0
  k_gemm0<<<(N * 144 + 255) / 256, 256, 0, stream>>>(fptr[0], fW0p, f_h, f_als, f_ald, N);
  k_agg4<<<(N + 3) / 4, 256, 0, stream>>>(f_h, f_als, f_ald, i_rs, i_col, fptr[7], fptr[8], fptr[9], fptr[10], fptr[11], f_xa, N);
  // layer 1 (MFMA)
  k_mm<9, 128, 4><<<(N + 63) / 64, 256, 0, stream>>>(f_xa, fWt1, f_h, f_als, f_ald, N);
  k_agg4<<<(N + 3) / 4, 256, 0, stream>>>(f_h, f_als, f_ald, i_rs, i_col, fptr[15], fptr[16], fptr[17], fptr[18], fptr[19], f_xa, N);
  // layer 2 (MFMA)
  k_mm<3, 32, 1><<<(N + 63) / 64, 256, 0, stream>>>(f_xa, fWt2, f_h, f_als, f_ald, N);
  k_agg1<<<(N + 3) / 4, 256, 0, stream>>>(f_h, f_als, f_ald, i_rs, i_col, fptr[23], fptr[24], fptr[25], fptr[26], fptr[27], f_xa, N);

  // pooling + MLP head
  k_pool<<<G, 64, 0, stream>>>(f_xa, BATCH, fptr[3], fptr[28], fptr[29], fptr[30], fptr[31], OUT, N, G);
}

// Round 8
// 294.129 us; speedup vs baseline: 2.0263x; 1.1906x over previous
//
#include <hip/hip_runtime.h>
#include <hip/hip_bf16.h>
#include <math.h>

#define LRELU_NEG 0.2f
#define BN_EPS 1e-5f
#define CSR_SHIFT 7

typedef __attribute__((ext_vector_type(8))) short bf16x8;
typedef __attribute__((ext_vector_type(4))) float f32x4;

__device__ __forceinline__ float lrelu(float x) { return x > 0.f ? x : LRELU_NEG * x; }
__device__ __forceinline__ float b2f(__hip_bfloat16 v) { return __bfloat162float(v); }
__device__ __forceinline__ unsigned short f2bu(float v) {
  __hip_bfloat16 b = __float2bfloat16(v);
  return *(unsigned short*)&b;
}

// ---------------- dtype detection ----------------
__global__ __launch_bounds__(256) void k_detect(const unsigned short* __restrict__ w, int n,
                                                int* __restrict__ flag) {
  __shared__ int bad_s;
  if (threadIdx.x == 0) bad_s = 0;
  __syncthreads();
  int bad = 0;
  for (int i = 2 * threadIdx.x; i < n; i += 512) {
    unsigned short u = w[i];
    if ((u & 0x7FFF) == 0) continue;
    int ex = (u >> 7) & 0xFF;
    if (ex > 131 || ex < 90) bad++;
  }
  atomicAdd(&bad_s, bad);
  __syncthreads();
  if (threadIdx.x == 0) *flag = (bad_s < 2048) ? 1 : 0;
}

// ---------------- unified input conversion -> f32 in ws ----------------
struct CvtArgs {
  const void* src[30];
  float* dst[30];
  int n[30];
};

__global__ __launch_bounds__(256) void k_cvt_all(CvtArgs a, const int* __restrict__ flag) {
  int ai = blockIdx.y;
  int n = a.n[ai];
  int i = blockIdx.x * 256 + threadIdx.x;
  if (i >= n) return;
  if (*flag) {
    a.dst[ai][i] = b2f(((const __hip_bfloat16*)a.src[ai])[i]);
  } else {
    a.dst[ai][i] = ((const float*)a.src[ai])[i];
  }
}

// ---------------- weight folding ----------------
__global__ __launch_bounds__(256) void k_foldW(const float* __restrict__ W0, const float* __restrict__ as0, const float* __restrict__ ad0,
                                               const float* __restrict__ W1, const float* __restrict__ as1, const float* __restrict__ ad1,
                                               const float* __restrict__ W2, const float* __restrict__ as2, const float* __restrict__ ad2,
                                               float* __restrict__ W0p, __hip_bfloat16* __restrict__ Wt1, __hip_bfloat16* __restrict__ Wt2) {
  int idx = blockIdx.x * 256 + threadIdx.x;
  if (idx < 576) {                  // W0p [4][144]
    int k = idx / 144, c = idx % 144;
    float v = 0.f;
    if (c < 128) v = W0[k * 128 + c];
    else if (c < 136) {
      int hh = (c - 128) & 3; const float* a = (c < 132) ? as0 : ad0;
      float s = 0.f;
      for (int cc = 0; cc < 32; cc++) s += W0[k * 128 + hh * 32 + cc] * a[hh * 32 + cc];
      v = s;
    }
    W0p[k * 144 + c] = v;
    return;
  }
  idx -= 576;
  if (idx < 144 * 128) {            // Wt1 [144][128]
    int c = idx >> 7, k = idx & 127;
    float v = 0.f;
    if (c < 128) v = W1[k * 128 + c];
    else if (c < 136) {
      int hh = (c - 128) & 3; const float* a = (c < 132) ? as1 : ad1;
      float s = 0.f;
      for (int cc = 0; cc < 32; cc++) s += W1[k * 128 + hh * 32 + cc] * a[hh * 32 + cc];
      v = s;
    }
    Wt1[c * 128 + k] = __float2bfloat16(v);
    return;
  }
  idx -= 144 * 128;
  if (idx < 48 * 128) {             // Wt2 [48][128]
    int c = idx >> 7, k = idx & 127;
    float v = 0.f;
    if (c < 32) v = W2[k * 32 + c];
    else if (c == 32) { float s = 0.f; for (int cc = 0; cc < 32; cc++) s += W2[k * 32 + cc] * as2[cc]; v = s; }
    else if (c == 33) { float s = 0.f; for (int cc = 0; cc < 32; cc++) s += W2[k * 32 + cc] * ad2[cc]; v = s; }
    Wt2[c * 128 + k] = __float2bfloat16(v);
  }
}

// ================= bucketed CSR build =================
// bucket = dst >> 7 (128 nodes per bucket)
__global__ __launch_bounds__(256) void k_binhist(const int* __restrict__ ei, int* __restrict__ ghist,
                                                 int E, int EN) {
  __shared__ int hist[512];
  int tid = threadIdx.x;
  hist[tid] = 0; hist[tid + 256] = 0;
  __syncthreads();
  int base = blockIdx.x * 4096;
  for (int i = 0; i < 16; i++) {
    int e = base + i * 256 + tid;
    if (e < EN) {
      int dst = (e < E) ? ei[E + e] : (e - E);
      atomicAdd(&hist[dst >> CSR_SHIFT], 1);
    }
  }
  __syncthreads();
  if (hist[tid]) atomicAdd(&ghist[tid], hist[tid]);
  if (hist[tid + 256]) atomicAdd(&ghist[tid + 256], hist[tid + 256]);
}

__global__ __launch_bounds__(512) void k_bucketscan(const int* __restrict__ ghist,
                                                    int* __restrict__ bbase, int* __restrict__ gcursor) {
  __shared__ int wpre[8];
  int tid = threadIdx.x, lane = tid & 63, wid = tid >> 6;
  int v = ghist[tid];
  int x = v;
  #pragma unroll
  for (int off = 1; off < 64; off <<= 1) {
    int y = __shfl_up(x, off);
    if (lane >= off) x += y;
  }
  if (lane == 63) wpre[wid] = x;
  __syncthreads();
  if (tid == 0) {
    int acc = 0;
    #pragma unroll
    for (int w = 0; w < 8; w++) { int t = wpre[w]; wpre[w] = acc; acc += t; }
  }
  __syncthreads();
  int excl = wpre[wid] + x - v;
  bbase[tid] = excl;
  gcursor[tid] = excl;
  if (tid == 511) bbase[512] = excl + v;
}

__global__ __launch_bounds__(256) void k_binscatter(const int* __restrict__ ei, int* __restrict__ gcursor,
                                                    unsigned int* __restrict__ pairs, int E, int EN) {
  __shared__ int cnt[512];
  __shared__ int base[512];
  int tid = threadIdx.x;
  cnt[tid] = 0; cnt[tid + 256] = 0;
  __syncthreads();
  int eb = blockIdx.x * 4096;
  int srcs[16], dsts[16];
  #pragma unroll
  for (int i = 0; i < 16; i++) {
    int e = eb + i * 256 + tid;
    srcs[i] = -1; dsts[i] = 0;
    if (e < EN) {
      int s, d;
      if (e < E) { s = ei[e]; d = ei[E + e]; } else { s = e - E; d = s; }
      srcs[i] = s; dsts[i] = d;
      atomicAdd(&cnt[d >> CSR_SHIFT], 1);
    }
  }
  __syncthreads();
  for (int b = tid; b < 512; b += 256) {
    int c = cnt[b];
    base[b] = c ? atomicAdd(&gcursor[b], c) : 0;
    cnt[b] = 0;
  }
  __syncthreads();
  #pragma unroll
  for (int i = 0; i < 16; i++) {
    if (srcs[i] >= 0) {
      int b = dsts[i] >> CSR_SHIFT;
      int loc = atomicAdd(&cnt[b], 1);
      pairs[base[b] + loc] = ((unsigned int)srcs[i] << CSR_SHIFT) | (unsigned int)(dsts[i] & 127);
    }
  }
}

__global__ __launch_bounds__(128) void k_bucketdeg(const unsigned int* __restrict__ pairs,
                                                   const int* __restrict__ bbase,
                                                   int* __restrict__ deg, int N) {
  __shared__ int dcount[128];
  int b = blockIdx.x, tid = threadIdx.x;
  dcount[tid] = 0;
  __syncthreads();
  int s = bbase[b], e = bbase[b + 1];
  for (int i = s + tid; i < e; i += 128)
    atomicAdd(&dcount[pairs[i] & 127], 1);
  __syncthreads();
  int node = (b << CSR_SHIFT) + tid;
  if (node < N) deg[node] = dcount[tid];
}

__global__ __launch_bounds__(1024) void k_scan(const int* __restrict__ deg, int* __restrict__ rs, int N) {
  __shared__ int wpre[16];
  __shared__ int running_s;
  int tid = threadIdx.x, lane = tid & 63, wid = tid >> 6;
  if (tid == 0) running_s = 0;
  __syncthreads();
  for (int base = 0; base <= N; base += 1024) {
    int idx = base + tid;
    int v = (idx < N) ? deg[idx] : 0;
    int x = v;
    #pragma unroll
    for (int off = 1; off < 64; off <<= 1) {
      int y = __shfl_up(x, off);
      if (lane >= off) x += y;
    }
    if (lane == 63) wpre[wid] = x;
    __syncthreads();
    if (tid == 0) {
      int acc = running_s;
      #pragma unroll
      for (int w = 0; w < 16; w++) { int t = wpre[w]; wpre[w] = acc; acc += t; }
      running_s = acc;
    }
    __syncthreads();
    int excl = wpre[wid] + x - v;
    if (idx <= N) rs[idx] = excl;
    __syncthreads();
  }
}

__global__ __launch_bounds__(256) void k_scatter2(const unsigned int* __restrict__ pairs,
                                                  const int* __restrict__ bbase, const int* __restrict__ rs,
                                                  int* __restrict__ col, int N) {
  __shared__ int lcur[128];
  int b = blockIdx.x, tid = threadIdx.x;
  if (tid < 128) {
    int node = (b << CSR_SHIFT) + tid;
    lcur[tid] = (node < N) ? rs[node] : 0;
  }
  __syncthreads();
  int s = bbase[b], e = bbase[b + 1];
  for (int i = s + tid; i < e; i += 256) {
    unsigned int p = pairs[i];
    int pos = atomicAdd(&lcur[p & 127], 1);
    col[pos] = (int)(p >> CSR_SHIFT);
  }
}

// ---------------- layer-0 GEMM (K=4), folded logits ----------------
__global__ __launch_bounds__(256) void k_gemm0(const float* __restrict__ x, const float* __restrict__ W0p,
    __hip_bfloat16* __restrict__ h, float* __restrict__ als, float* __restrict__ ald, int N) {
  int t = blockIdx.x * 256 + threadIdx.x;
  int nrow = t / 144, c = t - nrow * 144;
  if (nrow >= N || c >= 136) return;
  float4 xv = *(const float4*)(x + (size_t)nrow * 4);
  float acc = fmaf(xv.x, W0p[c], fmaf(xv.y, W0p[144 + c], fmaf(xv.z, W0p[288 + c], xv.w * W0p[432 + c])));
  if (c < 128)      h[(size_t)nrow * 128 + c] = __float2bfloat16(acc);
  else if (c < 132) als[(size_t)nrow * 4 + (c - 128)] = acc;
  else              ald[(size_t)nrow * 4 + (c - 132)] = acc;
}

// ---------------- MFMA GEMM ----------------
template <int CT, int DOUT, int HEADS>
__global__ __launch_bounds__(256) void k_mm(const __hip_bfloat16* __restrict__ xa,
    const __hip_bfloat16* __restrict__ Wt,
    __hip_bfloat16* __restrict__ h, float* __restrict__ als, float* __restrict__ ald, int N) {
  __shared__ unsigned short A_s[64 * 128];
  __shared__ unsigned short B_s[CT * 16 * 128];
  int tid = threadIdx.x;
  int row0 = blockIdx.x * 64;

  for (int i = tid; i < 1024; i += 256) {
    int r = i >> 4, slot = i & 15;
    int gr = row0 + r;
    float4 v = make_float4(0.f, 0.f, 0.f, 0.f);
    if (gr < N) v = ((const float4*)(xa + (size_t)gr * 128))[slot];
    *(float4*)((char*)A_s + r * 256 + ((slot ^ (r & 7)) << 4)) = v;
  }
  for (int i = tid; i < CT * 256; i += 256) {
    int r = i >> 4, slot = i & 15;
    float4 v = ((const float4*)Wt)[i];
    *(float4*)((char*)B_s + r * 256 + ((slot ^ (r & 7)) << 4)) = v;
  }
  __syncthreads();

  int l = tid & 63, w = tid >> 6;
  int lr = l & 15, lg = l >> 4;
  f32x4 acc[CT];
  #pragma unroll
  for (int ct = 0; ct < CT; ct++) acc[ct] = (f32x4){0.f, 0.f, 0.f, 0.f};

  int rA = w * 16 + lr;
  #pragma unroll
  for (int k0 = 0; k0 < 4; k0++) {
    int slot = k0 * 4 + lg;
    bf16x8 a = *(const bf16x8*)((const char*)A_s + rA * 256 + ((slot ^ (rA & 7)) << 4));
    #pragma unroll
    for (int ct = 0; ct < CT; ct++) {
      int rB = ct * 16 + lr;
      bf16x8 b = *(const bf16x8*)((const char*)B_s + rB * 256 + ((slot ^ (rB & 7)) << 4));
      acc[ct] = __builtin_amdgcn_mfma_f32_16x16x32_bf16(a, b, acc[ct], 0, 0, 0);
    }
  }

  #pragma unroll
  for (int ct = 0; ct < CT; ct++) {
    #pragma unroll
    for (int j = 0; j < 4; j++) {
      int gr = row0 + w * 16 + lg * 4 + j;
      if (gr >= N) continue;
      int col = ct * 16 + lr;
      float v = acc[ct][j];
      if (col < DOUT)                 h[(size_t)gr * DOUT + col] = __float2bfloat16(v);
      else if (col < DOUT + HEADS)    als[(size_t)gr * HEADS + (col - DOUT)] = v;
      else if (col < DOUT + 2*HEADS)  ald[(size_t)gr * HEADS + (col - DOUT - HEADS)] = v;
    }
  }
}

// ---------------- aggregation, H=4 C=32 ----------------
__global__ __launch_bounds__(256) void k_agg4(const __hip_bfloat16* __restrict__ h, const float* __restrict__ als,
    const float* __restrict__ ald, const int* __restrict__ rs, const int* __restrict__ col,
    const float* __restrict__ bias, const float* __restrict__ bng,
    const float* __restrict__ bnb, const float* __restrict__ bnm,
    const float* __restrict__ bnv, __hip_bfloat16* __restrict__ out, int N) {
  __shared__ int svs[4][64];
  __shared__ float alps[4][64][4];
  int lane = threadIdx.x & 63;
  int w = threadIdx.x >> 6;
  int n = blockIdx.x * 4 + w;
  if (n >= N) return;
  int row = rs[n], deg = rs[n + 1] - row;
  float4 ad4 = *(const float4*)(ald + (size_t)n * 4);

  float s0 = 0.f, s1 = 0.f, s2 = 0.f, s3 = 0.f;
  float p0 = 0.f, p1 = 0.f, p2 = 0.f, p3 = 0.f;
  int sv0 = 0;
  for (int base = 0; base < deg; base += 64) {
    int k = base + lane;
    int sv = 0; float q0 = 0.f, q1 = 0.f, q2 = 0.f, q3 = 0.f;
    if (k < deg) {
      sv = col[row + k];
      float4 a4 = *(const float4*)(als + (size_t)sv * 4);
      q0 = __expf(lrelu(a4.x + ad4.x));
      q1 = __expf(lrelu(a4.y + ad4.y));
      q2 = __expf(lrelu(a4.z + ad4.z));
      q3 = __expf(lrelu(a4.w + ad4.w));
    }
    if (base == 0) { sv0 = sv; p0 = q0; p1 = q1; p2 = q2; p3 = q3; }
    s0 += q0; s1 += q1; s2 += q2; s3 += q3;
  }
  #pragma unroll
  for (int off = 32; off; off >>= 1) {
    s0 += __shfl_xor(s0, off); s1 += __shfl_xor(s1, off);
    s2 += __shfl_xor(s2, off); s3 += __shfl_xor(s3, off);
  }
  float i0 = 1.f / (s0 + 1e-16f), i1 = 1.f / (s1 + 1e-16f);
  float i2 = 1.f / (s2 + 1e-16f), i3 = 1.f / (s3 + 1e-16f);

  int hh = lane >> 4;
  float acc0 = 0.f, acc1 = 0.f;
  for (int base = 0; base < deg; base += 64) {
    int cnt = min(64, deg - base);
    int sv; float a0, a1, a2, a3;
    if (base == 0) {
      sv = sv0; a0 = p0 * i0; a1 = p1 * i1; a2 = p2 * i2; a3 = p3 * i3;
    } else {
      int k = base + lane;
      sv = 0; a0 = a1 = a2 = a3 = 0.f;
      if (k < deg) {
        sv = col[row + k];
        float4 a4 = *(const float4*)(als + (size_t)sv * 4);
        a0 = __expf(lrelu(a4.x + ad4.x)) * i0;
        a1 = __expf(lrelu(a4.y + ad4.y)) * i1;
        a2 = __expf(lrelu(a4.z + ad4.z)) * i2;
        a3 = __expf(lrelu(a4.w + ad4.w)) * i3;
      }
    }
    svs[w][lane] = sv;
    *(float4*)&alps[w][lane][0] = make_float4(a0, a1, a2, a3);
    for (int k2 = 0; k2 < cnt; k2 += 4) {
      #pragma unroll
      for (int i = 0; i < 4; i++) {
        int ee = k2 + i;
        int e = min(ee, 63);
        float alpha = (ee < cnt) ? alps[w][e][hh] : 0.f;
        int s_ = svs[w][e];
        unsigned int hv = *((const unsigned int*)(h + (size_t)s_ * 128) + lane);
        float lo = __uint_as_float(hv << 16);
        float hi_ = __uint_as_float(hv & 0xFFFF0000u);
        acc0 = fmaf(alpha, lo, acc0);
        acc1 = fmaf(alpha, hi_, acc1);
      }
    }
  }
  int c0 = 2 * lane;
  float v0 = acc0 + bias[c0];
  float v1 = acc1 + bias[c0 + 1];
  v0 = (v0 - bnm[c0]) * rsqrtf(bnv[c0] + BN_EPS) * bng[c0] + bnb[c0];
  v1 = (v1 - bnm[c0 + 1]) * rsqrtf(bnv[c0 + 1] + BN_EPS) * bng[c0 + 1] + bnb[c0 + 1];
  v0 = v0 > 0.f ? v0 : expm1f(v0);
  v1 = v1 > 0.f ? v1 : expm1f(v1);
  unsigned int packed = ((unsigned int)f2bu(v1) << 16) | f2bu(v0);
  *(unsigned int*)((unsigned short*)out + (size_t)n * 128 + c0) = packed;
}

// ---------------- aggregation, H=1 C=32 ----------------
__global__ __launch_bounds__(256) void k_agg1(const __hip_bfloat16* __restrict__ h, const float* __restrict__ als,
    const float* __restrict__ ald, const int* __restrict__ rs, const int* __restrict__ col,
    const float* __restrict__ bias, const float* __restrict__ bng,
    const float* __restrict__ bnb, const float* __restrict__ bnm,
    const float* __restrict__ bnv, __hip_bfloat16* __restrict__ out, int N) {
  __shared__ int svs[4][64];
  __shared__ float alp[4][64];
  int lane = threadIdx.x & 63;
  int w = threadIdx.x >> 6;
  int n = blockIdx.x * 4 + w;
  if (n >= N) return;
  int row = rs[n], deg = rs[n + 1] - row;
  float ad = ald[n];

  float s = 0.f, p = 0.f;
  int sv0 = 0;
  for (int base = 0; base < deg; base += 64) {
    int k = base + lane;
    int sv = 0; float q = 0.f;
    if (k < deg) {
      sv = col[row + k];
      q = __expf(lrelu(als[sv] + ad));
    }
    if (base == 0) { sv0 = sv; p = q; }
    s += q;
  }
  #pragma unroll
  for (int off = 32; off; off >>= 1) s += __shfl_xor(s, off);
  float inv = 1.f / (s + 1e-16f);

  int c = lane & 31, eh = lane >> 5;
  float acc = 0.f;
  for (int base = 0; base < deg; base += 64) {
    int cnt = min(64, deg - base);
    int sv; float a;
    if (base == 0) { sv = sv0; a = p * inv; }
    else {
      int k = base + lane;
      sv = 0; a = 0.f;
      if (k < deg) { sv = col[row + k]; a = __expf(lrelu(als[sv] + ad)) * inv; }
    }
    svs[w][lane] = sv;
    alp[w][lane] = a;
    for (int k2 = 0; k2 < cnt; k2 += 4) {
      int ee0 = k2 + eh, ee1 = k2 + 2 + eh;
      int e0 = min(ee0, 63), e1 = min(ee1, 63);
      float a0 = (ee0 < cnt) ? alp[w][e0] : 0.f;
      float a1 = (ee1 < cnt) ? alp[w][e1] : 0.f;
      int s0v = svs[w][e0], s1v = svs[w][e1];
      float h0 = b2f(h[(size_t)s0v * 32 + c]);
      float h1 = b2f(h[(size_t)s1v * 32 + c]);
      acc = fmaf(a0, h0, fmaf(a1, h1, acc));
    }
  }
  acc += __shfl_xor(acc, 32);
  if (lane < 32) {
    float v = acc + bias[c];
    v = (v - bnm[c]) * rsqrtf(bnv[c] + BN_EPS) * bng[c] + bnb[c];
    v = v > 0.f ? v : expm1f(v);
    out[(size_t)n * 32 + c] = __float2bfloat16(v);
  }
}

// ---------------- per-graph pooling + MLP head ----------------
__global__ __launch_bounds__(64) void k_pool(const __hip_bfloat16* __restrict__ x3, const int* __restrict__ batch,
    const float* __restrict__ u, const float* __restrict__ l1w,
    const float* __restrict__ l1b, const float* __restrict__ l2w,
    const float* __restrict__ l2b, float* __restrict__ out, int N, int G) {
  int g = blockIdx.x;
  int lane = threadIdx.x;
  int lo = 0, hi = N;
  while (lo < hi) { int mid = (lo + hi) >> 1; if (batch[mid] < g) lo = mid + 1; else hi = mid; }
  int start = lo;
  hi = N;
  while (lo < hi) { int mid = (lo + hi) >> 1; if (batch[mid] < g + 1) lo = mid + 1; else hi = mid; }
  int end = lo;
  int c = lane & 31, half = lane >> 5;
  float sum = 0.f, mx = -1e30f;
  for (int i = start + half; i < end; i += 2) {
    float v = b2f(x3[(size_t)i * 32 + c]);
    sum += v; mx = fmaxf(mx, v);
  }
  sum += __shfl_xor(sum, 32);
  mx = fmaxf(mx, __shfl_xor(mx, 32));
  __shared__ float comb[74];
  if (lane < 32) {
    float cnt = (float)(end - start);
    comb[lane] = sum / cnt;
    comb[32 + lane] = mx;
  }
  if (lane < 10) comb[64 + lane] = u[g * 10 + lane];
  __syncthreads();
  if (lane < 32) {
    float acc = l1b[lane];
    #pragma unroll
    for (int k = 0; k < 74; k++) acc = fmaf(comb[k], l1w[k * 32 + lane], acc);
    acc = fmaxf(acc, 0.f);
    float v = acc * l2w[lane];
    #pragma unroll
    for (int off = 16; off; off >>= 1) v += __shfl_xor(v, off, 32);
    if (lane == 0) out[g] = 1.f / (1.f + __expf(-(v + l2b[0])));
  }
}

extern "C" void kernel_launch(void* const* d_in, const int* in_sizes, int n_in,
                              void* d_out, int out_size, void* d_ws, size_t ws_size,
                              hipStream_t stream) {
  const int* EI    = (const int*)d_in[1];
  const int* BATCH = (const int*)d_in[2];
  float* OUT = (float*)d_out;

  int N = in_sizes[2];
  int E = in_sizes[1] / 2;
  int G = in_sizes[3] / 10;
  int EN = E + N;
  int NB = (N + 127) >> 7;          // buckets of 128 nodes

  char* ws = (char*)d_ws;
  size_t off = 0;
  auto alloc = [&](size_t bytes) {
    void* p = ws + off;
    off = (off + bytes + 255) & ~(size_t)255;
    return p;
  };
  __hip_bfloat16* f_xa = (__hip_bfloat16*)alloc((size_t)N * 128 * 2);
  __hip_bfloat16* f_h  = (__hip_bfloat16*)alloc((size_t)N * 128 * 2);
  float* f_als = (float*)alloc((size_t)N * 4 * 4);
  float* f_ald = (float*)alloc((size_t)N * 4 * 4);
  float* fW0p  = (float*)alloc(576 * 4);
  __hip_bfloat16* fWt1 = (__hip_bfloat16*)alloc(144 * 128 * 2);
  __hip_bfloat16* fWt2 = (__hip_bfloat16*)alloc(48 * 128 * 2);
  int* i_deg  = (int*)alloc((size_t)(N + 1) * 4);
  int* i_rs   = (int*)alloc((size_t)(N + 1) * 4);
  int* i_col  = (int*)alloc((size_t)EN * 4);
  unsigned int* i_pairs = (unsigned int*)alloc((size_t)EN * 4);
  int* i_ghist   = (int*)alloc(512 * 4);
  int* i_bbase   = (int*)alloc(513 * 4);
  int* i_gcursor = (int*)alloc(512 * 4);
  int* i_flag = (int*)alloc(256);

  CvtArgs ca;
  float* fptr[32];
  int maxn = 0, na = 0;
  for (int i = 0; i < 32; i++) {
    if (i == 1 || i == 2) { fptr[i] = nullptr; continue; }
    int n = in_sizes[i];
    fptr[i] = (float*)alloc((size_t)n * 4);
    ca.src[na] = d_in[i];
    ca.dst[na] = fptr[i];
    ca.n[na] = n;
    if (n > maxn) maxn = n;
    na++;
  }

  // dtype detect + convert
  k_detect<<<1, 256, 0, stream>>>((const unsigned short*)d_in[12], in_sizes[12], i_flag);
  dim3 cgrid((maxn + 255) / 256, na);
  k_cvt_all<<<cgrid, 256, 0, stream>>>(ca, i_flag);

  // weight folding
  k_foldW<<<99, 256, 0, stream>>>(fptr[4], fptr[5], fptr[6],
                                  fptr[12], fptr[13], fptr[14],
                                  fptr[20], fptr[21], fptr[22],
                                  fW0p, fWt1, fWt2);

  // bucketed CSR build
  hipMemsetAsync(i_ghist, 0, 512 * 4, stream);
  int ebks = (EN + 4095) / 4096;
  k_binhist<<<ebks, 256, 0, stream>>>(EI, i_ghist, E, EN);
  k_bucketscan<<<1, 512, 0, stream>>>(i_ghist, i_bbase, i_gcursor);
  k_binscatter<<<ebks, 256, 0, stream>>>(EI, i_gcursor, i_pairs, E, EN);
  k_bucketdeg<<<NB, 128, 0, stream>>>(i_pairs, i_bbase, i_deg, N);
  k_scan<<<1, 1024, 0, stream>>>(i_deg, i_rs, N);
  k_scatter2<<<NB, 256, 0, stream>>>(i_pairs, i_bbase, i_rs, i_col, N);

  // layer 0
  k_gemm0<<<(N * 144 + 255) / 256, 256, 0, stream>>>(fptr[0], fW0p, f_h, f_als, f_ald, N);
  k_agg4<<<(N + 3) / 4, 256, 0, stream>>>(f_h, f_als, f_ald, i_rs, i_col, fptr[7], fptr[8], fptr[9], fptr[10], fptr[11], f_xa, N);
  // layer 1 (MFMA)
  k_mm<9, 128, 4><<<(N + 63) / 64, 256, 0, stream>>>(f_xa, fWt1, f_h, f_als, f_ald, N);
  k_agg4<<<(N + 3) / 4, 256, 0, stream>>>(f_h, f_als, f_ald, i_rs, i_col, fptr[15], fptr[16], fptr[17], fptr[18], fptr[19], f_xa, N);
  // layer 2 (MFMA)
  k_mm<3, 32, 1><<<(N + 63) / 64, 256, 0, stream>>>(f_xa, fWt2, f_h, f_als, f_ald, N);
  k_agg1<<<(N + 3) / 4, 256, 0, stream>>>(f_h, f_als, f_ald, i_rs, i_col, fptr[23], fptr[24], fptr[25], fptr[26], fptr[27], f_xa, N);

  // pooling + MLP head
  k_pool<<<G, 64, 0, stream>>>(f_xa, BATCH, fptr[3], fptr[28], fptr[29], fptr[30], fptr[31], OUT, N, G);
}

// Round 9
// 287.157 us; speedup vs baseline: 2.0755x; 1.0243x over previous
//
#include <hip/hip_runtime.h>
#include <hip/hip_bf16.h>
#include <math.h>

#define LRELU_NEG 0.2f
#define BN_EPS 1e-5f
#define CSR_SHIFT 7

typedef __attribute__((ext_vector_type(8))) short bf16x8;
typedef __attribute__((ext_vector_type(4))) float f32x4;

__device__ __forceinline__ float lrelu(float x) { return x > 0.f ? x : LRELU_NEG * x; }
__device__ __forceinline__ float b2f(__hip_bfloat16 v) { return __bfloat162float(v); }
__device__ __forceinline__ unsigned short f2bu(float v) {
  __hip_bfloat16 b = __float2bfloat16(v);
  return *(unsigned short*)&b;
}
__device__ __forceinline__ float blo(unsigned int u) { return __uint_as_float(u << 16); }
__device__ __forceinline__ float bhi(unsigned int u) { return __uint_as_float(u & 0xFFFF0000u); }

// ---------------- dtype detection ----------------
__global__ __launch_bounds__(256) void k_detect(const unsigned short* __restrict__ w, int n,
                                                int* __restrict__ flag) {
  __shared__ int bad_s;
  if (threadIdx.x == 0) bad_s = 0;
  __syncthreads();
  int bad = 0;
  for (int i = 2 * threadIdx.x; i < n; i += 512) {
    unsigned short u = w[i];
    if ((u & 0x7FFF) == 0) continue;
    int ex = (u >> 7) & 0xFF;
    if (ex > 131 || ex < 90) bad++;
  }
  atomicAdd(&bad_s, bad);
  __syncthreads();
  if (threadIdx.x == 0) *flag = (bad_s < 2048) ? 1 : 0;
}

// ---------------- unified input conversion -> f32 in ws ----------------
struct CvtArgs {
  const void* src[30];
  float* dst[30];
  int n[30];
};

__global__ __launch_bounds__(256) void k_cvt_all(CvtArgs a, const int* __restrict__ flag) {
  int ai = blockIdx.y;
  int n = a.n[ai];
  int i = blockIdx.x * 256 + threadIdx.x;
  if (i >= n) return;
  if (*flag) {
    a.dst[ai][i] = b2f(((const __hip_bfloat16*)a.src[ai])[i]);
  } else {
    a.dst[ai][i] = ((const float*)a.src[ai])[i];
  }
}

// ---------------- weight folding ----------------
__global__ __launch_bounds__(256) void k_foldW(const float* __restrict__ W0, const float* __restrict__ as0, const float* __restrict__ ad0,
                                               const float* __restrict__ W1, const float* __restrict__ as1, const float* __restrict__ ad1,
                                               const float* __restrict__ W2, const float* __restrict__ as2, const float* __restrict__ ad2,
                                               float* __restrict__ W0p, __hip_bfloat16* __restrict__ Wt1, __hip_bfloat16* __restrict__ Wt2) {
  int idx = blockIdx.x * 256 + threadIdx.x;
  if (idx < 576) {                  // W0p [4][144]
    int k = idx / 144, c = idx % 144;
    float v = 0.f;
    if (c < 128) v = W0[k * 128 + c];
    else if (c < 136) {
      int hh = (c - 128) & 3; const float* a = (c < 132) ? as0 : ad0;
      float s = 0.f;
      for (int cc = 0; cc < 32; cc++) s += W0[k * 128 + hh * 32 + cc] * a[hh * 32 + cc];
      v = s;
    }
    W0p[k * 144 + c] = v;
    return;
  }
  idx -= 576;
  if (idx < 144 * 128) {            // Wt1 [144][128]
    int c = idx >> 7, k = idx & 127;
    float v = 0.f;
    if (c < 128) v = W1[k * 128 + c];
    else if (c < 136) {
      int hh = (c - 128) & 3; const float* a = (c < 132) ? as1 : ad1;
      float s = 0.f;
      for (int cc = 0; cc < 32; cc++) s += W1[k * 128 + hh * 32 + cc] * a[hh * 32 + cc];
      v = s;
    }
    Wt1[c * 128 + k] = __float2bfloat16(v);
    return;
  }
  idx -= 144 * 128;
  if (idx < 48 * 128) {             // Wt2 [48][128]
    int c = idx >> 7, k = idx & 127;
    float v = 0.f;
    if (c < 32) v = W2[k * 32 + c];
    else if (c == 32) { float s = 0.f; for (int cc = 0; cc < 32; cc++) s += W2[k * 32 + cc] * as2[cc]; v = s; }
    else if (c == 33) { float s = 0.f; for (int cc = 0; cc < 32; cc++) s += W2[k * 32 + cc] * ad2[cc]; v = s; }
    Wt2[c * 128 + k] = __float2bfloat16(v);
  }
}

// ================= bucketed CSR build =================
__global__ __launch_bounds__(256) void k_binhist(const int* __restrict__ ei, int* __restrict__ ghist,
                                                 int E, int EN) {
  __shared__ int hist[512];
  int tid = threadIdx.x;
  hist[tid] = 0; hist[tid + 256] = 0;
  __syncthreads();
  int base = blockIdx.x * 4096;
  for (int i = 0; i < 16; i++) {
    int e = base + i * 256 + tid;
    if (e < EN) {
      int dst = (e < E) ? ei[E + e] : (e - E);
      atomicAdd(&hist[dst >> CSR_SHIFT], 1);
    }
  }
  __syncthreads();
  if (hist[tid]) atomicAdd(&ghist[tid], hist[tid]);
  if (hist[tid + 256]) atomicAdd(&ghist[tid + 256], hist[tid + 256]);
}

__global__ __launch_bounds__(512) void k_bucketscan(const int* __restrict__ ghist,
                                                    int* __restrict__ bbase, int* __restrict__ gcursor) {
  __shared__ int wpre[8];
  int tid = threadIdx.x, lane = tid & 63, wid = tid >> 6;
  int v = ghist[tid];
  int x = v;
  #pragma unroll
  for (int off = 1; off < 64; off <<= 1) {
    int y = __shfl_up(x, off);
    if (lane >= off) x += y;
  }
  if (lane == 63) wpre[wid] = x;
  __syncthreads();
  if (tid == 0) {
    int acc = 0;
    #pragma unroll
    for (int w = 0; w < 8; w++) { int t = wpre[w]; wpre[w] = acc; acc += t; }
  }
  __syncthreads();
  int excl = wpre[wid] + x - v;
  bbase[tid] = excl;
  gcursor[tid] = excl;
  if (tid == 511) bbase[512] = excl + v;
}

__global__ __launch_bounds__(256) void k_binscatter(const int* __restrict__ ei, int* __restrict__ gcursor,
                                                    unsigned int* __restrict__ pairs, int E, int EN) {
  __shared__ int cnt[512];
  __shared__ int base[512];
  int tid = threadIdx.x;
  cnt[tid] = 0; cnt[tid + 256] = 0;
  __syncthreads();
  int eb = blockIdx.x * 4096;
  int srcs[16], dsts[16];
  #pragma unroll
  for (int i = 0; i < 16; i++) {
    int e = eb + i * 256 + tid;
    srcs[i] = -1; dsts[i] = 0;
    if (e < EN) {
      int s, d;
      if (e < E) { s = ei[e]; d = ei[E + e]; } else { s = e - E; d = s; }
      srcs[i] = s; dsts[i] = d;
      atomicAdd(&cnt[d >> CSR_SHIFT], 1);
    }
  }
  __syncthreads();
  for (int b = tid; b < 512; b += 256) {
    int c = cnt[b];
    base[b] = c ? atomicAdd(&gcursor[b], c) : 0;
    cnt[b] = 0;
  }
  __syncthreads();
  #pragma unroll
  for (int i = 0; i < 16; i++) {
    if (srcs[i] >= 0) {
      int b = dsts[i] >> CSR_SHIFT;
      int loc = atomicAdd(&cnt[b], 1);
      pairs[base[b] + loc] = ((unsigned int)srcs[i] << CSR_SHIFT) | (unsigned int)(dsts[i] & 127);
    }
  }
}

__global__ __launch_bounds__(128) void k_bucketdeg(const unsigned int* __restrict__ pairs,
                                                   const int* __restrict__ bbase,
                                                   int* __restrict__ deg, int N) {
  __shared__ int dcount[128];
  int b = blockIdx.x, tid = threadIdx.x;
  dcount[tid] = 0;
  __syncthreads();
  int s = bbase[b], e = bbase[b + 1];
  for (int i = s + tid; i < e; i += 128)
    atomicAdd(&dcount[pairs[i] & 127], 1);
  __syncthreads();
  int node = (b << CSR_SHIFT) + tid;
  if (node < N) deg[node] = dcount[tid];
}

__global__ __launch_bounds__(1024) void k_scan(const int* __restrict__ deg, int* __restrict__ rs, int N) {
  __shared__ int wpre[16];
  __shared__ int running_s;
  int tid = threadIdx.x, lane = tid & 63, wid = tid >> 6;
  if (tid == 0) running_s = 0;
  __syncthreads();
  for (int base = 0; base <= N; base += 1024) {
    int idx = base + tid;
    int v = (idx < N) ? deg[idx] : 0;
    int x = v;
    #pragma unroll
    for (int off = 1; off < 64; off <<= 1) {
      int y = __shfl_up(x, off);
      if (lane >= off) x += y;
    }
    if (lane == 63) wpre[wid] = x;
    __syncthreads();
    if (tid == 0) {
      int acc = running_s;
      #pragma unroll
      for (int w = 0; w < 16; w++) { int t = wpre[w]; wpre[w] = acc; acc += t; }
      running_s = acc;
    }
    __syncthreads();
    int excl = wpre[wid] + x - v;
    if (idx <= N) rs[idx] = excl;
    __syncthreads();
  }
}

__global__ __launch_bounds__(256) void k_scatter2(const unsigned int* __restrict__ pairs,
                                                  const int* __restrict__ bbase, const int* __restrict__ rs,
                                                  int* __restrict__ col, int N) {
  __shared__ int lcur[128];
  int b = blockIdx.x, tid = threadIdx.x;
  if (tid < 128) {
    int node = (b << CSR_SHIFT) + tid;
    lcur[tid] = (node < N) ? rs[node] : 0;
  }
  __syncthreads();
  int s = bbase[b], e = bbase[b + 1];
  for (int i = s + tid; i < e; i += 256) {
    unsigned int p = pairs[i];
    int pos = atomicAdd(&lcur[p & 127], 1);
    col[pos] = (int)(p >> CSR_SHIFT);
  }
}

// ---------------- layer-0 GEMM (K=4), folded logits ----------------
__global__ __launch_bounds__(256) void k_gemm0(const float* __restrict__ x, const float* __restrict__ W0p,
    __hip_bfloat16* __restrict__ h, float* __restrict__ als, float* __restrict__ ald, int N) {
  int t = blockIdx.x * 256 + threadIdx.x;
  int nrow = t / 144, c = t - nrow * 144;
  if (nrow >= N || c >= 136) return;
  float4 xv = *(const float4*)(x + (size_t)nrow * 4);
  float acc = fmaf(xv.x, W0p[c], fmaf(xv.y, W0p[144 + c], fmaf(xv.z, W0p[288 + c], xv.w * W0p[432 + c])));
  if (c < 128)      h[(size_t)nrow * 128 + c] = __float2bfloat16(acc);
  else if (c < 132) als[(size_t)nrow * 4 + (c - 128)] = acc;
  else              ald[(size_t)nrow * 4 + (c - 132)] = acc;
}

// ---------------- MFMA GEMM ----------------
template <int CT, int DOUT, int HEADS>
__global__ __launch_bounds__(256) void k_mm(const __hip_bfloat16* __restrict__ xa,
    const __hip_bfloat16* __restrict__ Wt,
    __hip_bfloat16* __restrict__ h, float* __restrict__ als, float* __restrict__ ald, int N) {
  __shared__ unsigned short A_s[64 * 128];
  __shared__ unsigned short B_s[CT * 16 * 128];
  int tid = threadIdx.x;
  int row0 = blockIdx.x * 64;

  for (int i = tid; i < 1024; i += 256) {
    int r = i >> 4, slot = i & 15;
    int gr = row0 + r;
    float4 v = make_float4(0.f, 0.f, 0.f, 0.f);
    if (gr < N) v = ((const float4*)(xa + (size_t)gr * 128))[slot];
    *(float4*)((char*)A_s + r * 256 + ((slot ^ (r & 7)) << 4)) = v;
  }
  for (int i = tid; i < CT * 256; i += 256) {
    int r = i >> 4, slot = i & 15;
    float4 v = ((const float4*)Wt)[i];
    *(float4*)((char*)B_s + r * 256 + ((slot ^ (r & 7)) << 4)) = v;
  }
  __syncthreads();

  int l = tid & 63, w = tid >> 6;
  int lr = l & 15, lg = l >> 4;
  f32x4 acc[CT];
  #pragma unroll
  for (int ct = 0; ct < CT; ct++) acc[ct] = (f32x4){0.f, 0.f, 0.f, 0.f};

  int rA = w * 16 + lr;
  #pragma unroll
  for (int k0 = 0; k0 < 4; k0++) {
    int slot = k0 * 4 + lg;
    bf16x8 a = *(const bf16x8*)((const char*)A_s + rA * 256 + ((slot ^ (rA & 7)) << 4));
    #pragma unroll
    for (int ct = 0; ct < CT; ct++) {
      int rB = ct * 16 + lr;
      bf16x8 b = *(const bf16x8*)((const char*)B_s + rB * 256 + ((slot ^ (rB & 7)) << 4));
      acc[ct] = __builtin_amdgcn_mfma_f32_16x16x32_bf16(a, b, acc[ct], 0, 0, 0);
    }
  }

  #pragma unroll
  for (int ct = 0; ct < CT; ct++) {
    #pragma unroll
    for (int j = 0; j < 4; j++) {
      int gr = row0 + w * 16 + lg * 4 + j;
      if (gr >= N) continue;
      int col = ct * 16 + lr;
      float v = acc[ct][j];
      if (col < DOUT)                 h[(size_t)gr * DOUT + col] = __float2bfloat16(v);
      else if (col < DOUT + HEADS)    als[(size_t)gr * HEADS + (col - DOUT)] = v;
      else if (col < DOUT + 2*HEADS)  ald[(size_t)gr * HEADS + (col - DOUT - HEADS)] = v;
    }
  }
}

// ---------------- aggregation, H=4 C=32: 2 edges/iter, uint2 loads ----------------
__global__ __launch_bounds__(256) void k_agg4(const __hip_bfloat16* __restrict__ h, const float* __restrict__ als,
    const float* __restrict__ ald, const int* __restrict__ rs, const int* __restrict__ col,
    const float* __restrict__ bias, const float* __restrict__ bng,
    const float* __restrict__ bnb, const float* __restrict__ bnm,
    const float* __restrict__ bnv, __hip_bfloat16* __restrict__ out, int N) {
  __shared__ int svs[4][64];
  __shared__ float alps[4][64][4];
  int lane = threadIdx.x & 63;
  int w = threadIdx.x >> 6;
  int n = blockIdx.x * 4 + w;
  if (n >= N) return;
  int row = rs[n], deg = rs[n + 1] - row;
  float4 ad4 = *(const float4*)(ald + (size_t)n * 4);

  // softmax pass (lane = edge)
  float s0 = 0.f, s1 = 0.f, s2 = 0.f, s3 = 0.f;
  float p0 = 0.f, p1 = 0.f, p2 = 0.f, p3 = 0.f;
  int sv0 = 0;
  for (int base = 0; base < deg; base += 64) {
    int k = base + lane;
    int sv = 0; float q0 = 0.f, q1 = 0.f, q2 = 0.f, q3 = 0.f;
    if (k < deg) {
      sv = col[row + k];
      float4 a4 = *(const float4*)(als + (size_t)sv * 4);
      q0 = __expf(lrelu(a4.x + ad4.x));
      q1 = __expf(lrelu(a4.y + ad4.y));
      q2 = __expf(lrelu(a4.z + ad4.z));
      q3 = __expf(lrelu(a4.w + ad4.w));
    }
    if (base == 0) { sv0 = sv; p0 = q0; p1 = q1; p2 = q2; p3 = q3; }
    s0 += q0; s1 += q1; s2 += q2; s3 += q3;
  }
  #pragma unroll
  for (int off = 32; off; off >>= 1) {
    s0 += __shfl_xor(s0, off); s1 += __shfl_xor(s1, off);
    s2 += __shfl_xor(s2, off); s3 += __shfl_xor(s3, off);
  }
  float i0 = 1.f / (s0 + 1e-16f), i1 = 1.f / (s1 + 1e-16f);
  float i2 = 1.f / (s2 + 1e-16f), i3 = 1.f / (s3 + 1e-16f);

  // gather: half-wave per edge, 4 channels per lane via uint2
  int sub = lane & 31, half = lane >> 5;
  int hh2 = sub >> 3;                      // head of channel group 4*sub
  float acc0 = 0.f, acc1 = 0.f, acc2 = 0.f, acc3 = 0.f;
  for (int base = 0; base < deg; base += 64) {
    int cnt = min(64, deg - base);
    int sv; float a0, a1, a2, a3;
    if (base == 0) {
      sv = sv0; a0 = p0 * i0; a1 = p1 * i1; a2 = p2 * i2; a3 = p3 * i3;
    } else {
      int k = base + lane;
      sv = 0; a0 = a1 = a2 = a3 = 0.f;
      if (k < deg) {
        sv = col[row + k];
        float4 a4 = *(const float4*)(als + (size_t)sv * 4);
        a0 = __expf(lrelu(a4.x + ad4.x)) * i0;
        a1 = __expf(lrelu(a4.y + ad4.y)) * i1;
        a2 = __expf(lrelu(a4.z + ad4.z)) * i2;
        a3 = __expf(lrelu(a4.w + ad4.w)) * i3;
      }
    }
    svs[w][lane] = sv;
    *(float4*)&alps[w][lane][0] = make_float4(a0, a1, a2, a3);
    for (int k2 = 0; k2 < cnt; k2 += 4) {
      #pragma unroll
      for (int i = 0; i < 2; i++) {
        int ee = k2 + 2 * i + half;
        int e = min(ee, 63);
        float alpha = (ee < cnt) ? alps[w][e][hh2] : 0.f;
        int s_ = svs[w][e];
        uint2 hv = *((const uint2*)(h + (size_t)s_ * 128) + sub);
        acc0 = fmaf(alpha, blo(hv.x), acc0);
        acc1 = fmaf(alpha, bhi(hv.x), acc1);
        acc2 = fmaf(alpha, blo(hv.y), acc2);
        acc3 = fmaf(alpha, bhi(hv.y), acc3);
      }
    }
  }
  acc0 += __shfl_xor(acc0, 32);
  acc1 += __shfl_xor(acc1, 32);
  acc2 += __shfl_xor(acc2, 32);
  acc3 += __shfl_xor(acc3, 32);
  if (half == 0) {
    int c0 = 4 * sub;
    float4 bi = *(const float4*)(bias + c0);
    float4 bm = *(const float4*)(bnm + c0);
    float4 bv = *(const float4*)(bnv + c0);
    float4 bg = *(const float4*)(bng + c0);
    float4 bb = *(const float4*)(bnb + c0);
    float v0 = (acc0 + bi.x - bm.x) * rsqrtf(bv.x + BN_EPS) * bg.x + bb.x;
    float v1 = (acc1 + bi.y - bm.y) * rsqrtf(bv.y + BN_EPS) * bg.y + bb.y;
    float v2 = (acc2 + bi.z - bm.z) * rsqrtf(bv.z + BN_EPS) * bg.z + bb.z;
    float v3 = (acc3 + bi.w - bm.w) * rsqrtf(bv.w + BN_EPS) * bg.w + bb.w;
    v0 = v0 > 0.f ? v0 : expm1f(v0);
    v1 = v1 > 0.f ? v1 : expm1f(v1);
    v2 = v2 > 0.f ? v2 : expm1f(v2);
    v3 = v3 > 0.f ? v3 : expm1f(v3);
    uint2 packed;
    packed.x = ((unsigned int)f2bu(v1) << 16) | f2bu(v0);
    packed.y = ((unsigned int)f2bu(v3) << 16) | f2bu(v2);
    *((uint2*)((unsigned short*)out + (size_t)n * 128) + sub) = packed;
  }
}

// ---------------- aggregation, H=1 C=32: 4 edges/iter, uint loads ----------------
__global__ __launch_bounds__(256) void k_agg1(const __hip_bfloat16* __restrict__ h, const float* __restrict__ als,
    const float* __restrict__ ald, const int* __restrict__ rs, const int* __restrict__ col,
    const float* __restrict__ bias, const float* __restrict__ bng,
    const float* __restrict__ bnb, const float* __restrict__ bnm,
    const float* __restrict__ bnv, __hip_bfloat16* __restrict__ out, int N) {
  __shared__ int svs[4][64];
  __shared__ float alp[4][64];
  int lane = threadIdx.x & 63;
  int w = threadIdx.x >> 6;
  int n = blockIdx.x * 4 + w;
  if (n >= N) return;
  int row = rs[n], deg = rs[n + 1] - row;
  float ad = ald[n];

  float s = 0.f, p = 0.f;
  int sv0 = 0;
  for (int base = 0; base < deg; base += 64) {
    int k = base + lane;
    int sv = 0; float q = 0.f;
    if (k < deg) {
      sv = col[row + k];
      q = __expf(lrelu(als[sv] + ad));
    }
    if (base == 0) { sv0 = sv; p = q; }
    s += q;
  }
  #pragma unroll
  for (int off = 32; off; off >>= 1) s += __shfl_xor(s, off);
  float inv = 1.f / (s + 1e-16f);

  // gather: 4 x 16-lane groups, 2 channels per lane via uint
  int sub = lane & 15, g = lane >> 4;
  float acc0 = 0.f, acc1 = 0.f;
  for (int base = 0; base < deg; base += 64) {
    int cnt = min(64, deg - base);
    int sv; float a;
    if (base == 0) { sv = sv0; a = p * inv; }
    else {
      int k = base + lane;
      sv = 0; a = 0.f;
      if (k < deg) { sv = col[row + k]; a = __expf(lrelu(als[sv] + ad)) * inv; }
    }
    svs[w][lane] = sv;
    alp[w][lane] = a;
    for (int k2 = 0; k2 < cnt; k2 += 8) {
      #pragma unroll
      for (int i = 0; i < 2; i++) {
        int ee = k2 + 4 * i + g;
        int e = min(ee, 63);
        float a_ = (ee < cnt) ? alp[w][e] : 0.f;
        int s_ = svs[w][e];
        unsigned int hv = *((const unsigned int*)(h + (size_t)s_ * 32) + sub);
        acc0 = fmaf(a_, blo(hv), acc0);
        acc1 = fmaf(a_, bhi(hv), acc1);
      }
    }
  }
  acc0 += __shfl_xor(acc0, 16); acc0 += __shfl_xor(acc0, 32);
  acc1 += __shfl_xor(acc1, 16); acc1 += __shfl_xor(acc1, 32);
  if (lane < 16) {
    int c0 = 2 * lane;
    float2 bi = *(const float2*)(bias + c0);
    float2 bm = *(const float2*)(bnm + c0);
    float2 bv = *(const float2*)(bnv + c0);
    float2 bg = *(const float2*)(bng + c0);
    float2 bb = *(const float2*)(bnb + c0);
    float v0 = (acc0 + bi.x - bm.x) * rsqrtf(bv.x + BN_EPS) * bg.x + bb.x;
    float v1 = (acc1 + bi.y - bm.y) * rsqrtf(bv.y + BN_EPS) * bg.y + bb.y;
    v0 = v0 > 0.f ? v0 : expm1f(v0);
    v1 = v1 > 0.f ? v1 : expm1f(v1);
    unsigned int packed = ((unsigned int)f2bu(v1) << 16) | f2bu(v0);
    *((unsigned int*)((unsigned short*)out + (size_t)n * 32) + lane) = packed;
  }
}

// ---------------- per-graph pooling + MLP head ----------------
__global__ __launch_bounds__(64) void k_pool(const __hip_bfloat16* __restrict__ x3, const int* __restrict__ batch,
    const float* __restrict__ u, const float* __restrict__ l1w,
    const float* __restrict__ l1b, const float* __restrict__ l2w,
    const float* __restrict__ l2b, float* __restrict__ out, int N, int G) {
  int g = blockIdx.x;
  int lane = threadIdx.x;
  int lo = 0, hi = N;
  while (lo < hi) { int mid = (lo + hi) >> 1; if (batch[mid] < g) lo = mid + 1; else hi = mid; }
  int start = lo;
  hi = N;
  while (lo < hi) { int mid = (lo + hi) >> 1; if (batch[mid] < g + 1) lo = mid + 1; else hi = mid; }
  int end = lo;
  // 4 x 16-lane groups: group q handles nodes start+q, step 4; uint loads (2ch/lane)
  int sub = lane & 15, q = lane >> 4;
  float sum0 = 0.f, sum1 = 0.f, mx0 = -1e30f, mx1 = -1e30f;
  for (int i = start + q; i < end; i += 4) {
    unsigned int hv = *((const unsigned int*)(x3 + (size_t)i * 32) + sub);
    float v0 = blo(hv), v1 = bhi(hv);
    sum0 += v0; sum1 += v1;
    mx0 = fmaxf(mx0, v0); mx1 = fmaxf(mx1, v1);
  }
  sum0 += __shfl_xor(sum0, 16); sum0 += __shfl_xor(sum0, 32);
  sum1 += __shfl_xor(sum1, 16); sum1 += __shfl_xor(sum1, 32);
  mx0 = fmaxf(mx0, __shfl_xor(mx0, 16)); mx0 = fmaxf(mx0, __shfl_xor(mx0, 32));
  mx1 = fmaxf(mx1, __shfl_xor(mx1, 16)); mx1 = fmaxf(mx1, __shfl_xor(mx1, 32));
  __shared__ float comb[74];
  if (lane < 16) {
    float cnt = (float)(end - start);
    comb[2 * lane] = sum0 / cnt;
    comb[2 * lane + 1] = sum1 / cnt;
    comb[32 + 2 * lane] = mx0;
    comb[32 + 2 * lane + 1] = mx1;
  }
  if (lane < 10) comb[64 + lane] = u[g * 10 + lane];
  __syncthreads();
  if (lane < 32) {
    float acc = l1b[lane];
    #pragma unroll
    for (int k = 0; k < 74; k++) acc = fmaf(comb[k], l1w[k * 32 + lane], acc);
    acc = fmaxf(acc, 0.f);
    float v = acc * l2w[lane];
    #pragma unroll
    for (int off = 16; off; off >>= 1) v += __shfl_xor(v, off, 32);
    if (lane == 0) out[g] = 1.f / (1.f + __expf(-(v + l2b[0])));
  }
}

extern "C" void kernel_launch(void* const* d_in, const int* in_sizes, int n_in,
                              void* d_out, int out_size, void* d_ws, size_t ws_size,
                              hipStream_t stream) {
  const int* EI    = (const int*)d_in[1];
  const int* BATCH = (const int*)d_in[2];
  float* OUT = (float*)d_out;

  int N = in_sizes[2];
  int E = in_sizes[1] / 2;
  int G = in_sizes[3] / 10;
  int EN = E + N;
  int NB = (N + 127) >> 7;

  char* ws = (char*)d_ws;
  size_t off = 0;
  auto alloc = [&](size_t bytes) {
    void* p = ws + off;
    off = (off + bytes + 255) & ~(size_t)255;
    return p;
  };
  __hip_bfloat16* f_xa = (__hip_bfloat16*)alloc((size_t)N * 128 * 2);
  __hip_bfloat16* f_h  = (__hip_bfloat16*)alloc((size_t)N * 128 * 2);
  float* f_als = (float*)alloc((size_t)N * 4 * 4);
  float* f_ald = (float*)alloc((size_t)N * 4 * 4);
  float* fW0p  = (float*)alloc(576 * 4);
  __hip_bfloat16* fWt1 = (__hip_bfloat16*)alloc(144 * 128 * 2);
  __hip_bfloat16* fWt2 = (__hip_bfloat16*)alloc(48 * 128 * 2);
  int* i_deg  = (int*)alloc((size_t)(N + 1) * 4);
  int* i_rs   = (int*)alloc((size_t)(N + 1) * 4);
  int* i_col  = (int*)alloc((size_t)EN * 4);
  unsigned int* i_pairs = (unsigned int*)alloc((size_t)EN * 4);
  int* i_ghist   = (int*)alloc(512 * 4);
  int* i_bbase   = (int*)alloc(513 * 4);
  int* i_gcursor = (int*)alloc(512 * 4);
  int* i_flag = (int*)alloc(256);

  CvtArgs ca;
  float* fptr[32];
  int maxn = 0, na = 0;
  for (int i = 0; i < 32; i++) {
    if (i == 1 || i == 2) { fptr[i] = nullptr; continue; }
    int n = in_sizes[i];
    fptr[i] = (float*)alloc((size_t)n * 4);
    ca.src[na] = d_in[i];
    ca.dst[na] = fptr[i];
    ca.n[na] = n;
    if (n > maxn) maxn = n;
    na++;
  }

  // dtype detect + convert
  k_detect<<<1, 256, 0, stream>>>((const unsigned short*)d_in[12], in_sizes[12], i_flag);
  dim3 cgrid((maxn + 255) / 256, na);
  k_cvt_all<<<cgrid, 256, 0, stream>>>(ca, i_flag);

  // weight folding
  k_foldW<<<99, 256, 0, stream>>>(fptr[4], fptr[5], fptr[6],
                                  fptr[12], fptr[13], fptr[14],
                                  fptr[20], fptr[21], fptr[22],
                                  fW0p, fWt1, fWt2);

  // bucketed CSR build
  hipMemsetAsync(i_ghist, 0, 512 * 4, stream);
  int ebks = (EN + 4095) / 4096;
  k_binhist<<<ebks, 256, 0, stream>>>(EI, i_ghist, E, EN);
  k_bucketscan<<<1, 512, 0, stream>>>(i_ghist, i_bbase, i_gcursor);
  k_binscatter<<<ebks, 256, 0, stream>>>(EI, i_gcursor, i_pairs, E, EN);
  k_bucketdeg<<<NB, 128, 0, stream>>>(i_pairs, i_bbase, i_deg, N);
  k_scan<<<1, 1024, 0, stream>>>(i_deg, i_rs, N);
  k_scatter2<<<NB, 256, 0, stream>>>(i_pairs, i_bbase, i_rs, i_col, N);

  // layer 0
  k_gemm0<<<(N * 144 + 255) / 256, 256, 0, stream>>>(fptr[0], fW0p, f_h, f_als, f_ald, N);
  k_agg4<<<(N + 3) / 4, 256, 0, stream>>>(f_h, f_als, f_ald, i_rs, i_col, fptr[7], fptr[8], fptr[9], fptr[10], fptr[11], f_xa, N);
  // layer 1 (MFMA)
  k_mm<9, 128, 4><<<(N + 63) / 64, 256, 0, stream>>>(f_xa, fWt1, f_h, f_als, f_ald, N);
  k_agg4<<<(N + 3) / 4, 256, 0, stream>>>(f_h, f_als, f_ald, i_rs, i_col, fptr[15], fptr[16], fptr[17], fptr[18], fptr[19], f_xa, N);
  // layer 2 (MFMA)
  k_mm<3, 32, 1><<<(N + 63) / 64, 256, 0, stream>>>(f_xa, fWt2, f_h, f_als, f_ald, N);
  k_agg1<<<(N + 3) / 4, 256, 0, stream>>>(f_h, f_als, f_ald, i_rs, i_col, fptr[23], fptr[24], fptr[25], fptr[26], fptr[27], f_xa, N);

  // pooling + MLP head
  k_pool<<<G, 64, 0, stream>>>(f_xa, BATCH, fptr[3], fptr[28], fptr[29], fptr[30], fptr[31], OUT, N, G);
}

// Round 10
// 251.261 us; speedup vs baseline: 2.3720x; 1.1429x over previous
//
#include <hip/hip_runtime.h>
#include <hip/hip_bf16.h>
#include <math.h>

#define LRELU_NEG 0.2f
#define BN_EPS 1e-5f
#define CSR_SHIFT 7

typedef __attribute__((ext_vector_type(8))) short bf16x8;
typedef __attribute__((ext_vector_type(4))) float f32x4;

__device__ __forceinline__ float lrelu(float x) { return x > 0.f ? x : LRELU_NEG * x; }
__device__ __forceinline__ float b2f(__hip_bfloat16 v) { return __bfloat162float(v); }
__device__ __forceinline__ unsigned short f2bu(float v) {
  __hip_bfloat16 b = __float2bfloat16(v);
  return *(unsigned short*)&b;
}
__device__ __forceinline__ float blo(unsigned int u) { return __uint_as_float(u << 16); }
__device__ __forceinline__ float bhi(unsigned int u) { return __uint_as_float(u & 0xFFFF0000u); }
__device__ __forceinline__ float elu_fast(float v) { return v > 0.f ? v : __expf(v) - 1.f; }

// ---------------- dtype detection ----------------
__global__ __launch_bounds__(256) void k_detect(const unsigned short* __restrict__ w, int n,
                                                int* __restrict__ flag) {
  __shared__ int bad_s;
  if (threadIdx.x == 0) bad_s = 0;
  __syncthreads();
  int bad = 0;
  for (int i = 2 * threadIdx.x; i < n; i += 512) {
    unsigned short u = w[i];
    if ((u & 0x7FFF) == 0) continue;
    int ex = (u >> 7) & 0xFF;
    if (ex > 131 || ex < 90) bad++;
  }
  atomicAdd(&bad_s, bad);
  __syncthreads();
  if (threadIdx.x == 0) *flag = (bad_s < 2048) ? 1 : 0;
}

// ---------------- unified input conversion -> f32 in ws ----------------
struct CvtArgs {
  const void* src[30];
  float* dst[30];
  int n[30];
};

__global__ __launch_bounds__(256) void k_cvt_all(CvtArgs a, const int* __restrict__ flag) {
  int ai = blockIdx.y;
  int n = a.n[ai];
  int i = blockIdx.x * 256 + threadIdx.x;
  if (i >= n) return;
  if (*flag) {
    a.dst[ai][i] = b2f(((const __hip_bfloat16*)a.src[ai])[i]);
  } else {
    a.dst[ai][i] = ((const float*)a.src[ai])[i];
  }
}

// ---------------- weight folding ----------------
__global__ __launch_bounds__(256) void k_foldW(const float* __restrict__ W0, const float* __restrict__ as0, const float* __restrict__ ad0,
                                               const float* __restrict__ W1, const float* __restrict__ as1, const float* __restrict__ ad1,
                                               const float* __restrict__ W2, const float* __restrict__ as2, const float* __restrict__ ad2,
                                               float* __restrict__ W0p, __hip_bfloat16* __restrict__ Wt1, __hip_bfloat16* __restrict__ Wt2) {
  int idx = blockIdx.x * 256 + threadIdx.x;
  if (idx < 576) {                  // W0p [4][144]
    int k = idx / 144, c = idx % 144;
    float v = 0.f;
    if (c < 128) v = W0[k * 128 + c];
    else if (c < 136) {
      int hh = (c - 128) & 3; const float* a = (c < 132) ? as0 : ad0;
      float s = 0.f;
      for (int cc = 0; cc < 32; cc++) s += W0[k * 128 + hh * 32 + cc] * a[hh * 32 + cc];
      v = s;
    }
    W0p[k * 144 + c] = v;
    return;
  }
  idx -= 576;
  if (idx < 144 * 128) {            // Wt1 [144][128]
    int c = idx >> 7, k = idx & 127;
    float v = 0.f;
    if (c < 128) v = W1[k * 128 + c];
    else if (c < 136) {
      int hh = (c - 128) & 3; const float* a = (c < 132) ? as1 : ad1;
      float s = 0.f;
      for (int cc = 0; cc < 32; cc++) s += W1[k * 128 + hh * 32 + cc] * a[hh * 32 + cc];
      v = s;
    }
    Wt1[c * 128 + k] = __float2bfloat16(v);
    return;
  }
  idx -= 144 * 128;
  if (idx < 48 * 128) {             // Wt2 [48][128]
    int c = idx >> 7, k = idx & 127;
    float v = 0.f;
    if (c < 32) v = W2[k * 32 + c];
    else if (c == 32) { float s = 0.f; for (int cc = 0; cc < 32; cc++) s += W2[k * 32 + cc] * as2[cc]; v = s; }
    else if (c == 33) { float s = 0.f; for (int cc = 0; cc < 32; cc++) s += W2[k * 32 + cc] * ad2[cc]; v = s; }
    Wt2[c * 128 + k] = __float2bfloat16(v);
  }
}

// ================= bucketed CSR build =================
__global__ __launch_bounds__(256) void k_binhist(const int* __restrict__ ei, int* __restrict__ ghist,
                                                 int E, int EN) {
  __shared__ int hist[512];
  int tid = threadIdx.x;
  hist[tid] = 0; hist[tid + 256] = 0;
  __syncthreads();
  int base = blockIdx.x * 4096;
  for (int i = 0; i < 16; i++) {
    int e = base + i * 256 + tid;
    if (e < EN) {
      int dst = (e < E) ? ei[E + e] : (e - E);
      atomicAdd(&hist[dst >> CSR_SHIFT], 1);
    }
  }
  __syncthreads();
  if (hist[tid]) atomicAdd(&ghist[tid], hist[tid]);
  if (hist[tid + 256]) atomicAdd(&ghist[tid + 256], hist[tid + 256]);
}

__global__ __launch_bounds__(512) void k_bucketscan(const int* __restrict__ ghist,
                                                    int* __restrict__ bbase, int* __restrict__ gcursor) {
  __shared__ int wpre[8];
  int tid = threadIdx.x, lane = tid & 63, wid = tid >> 6;
  int v = ghist[tid];
  int x = v;
  #pragma unroll
  for (int off = 1; off < 64; off <<= 1) {
    int y = __shfl_up(x, off);
    if (lane >= off) x += y;
  }
  if (lane == 63) wpre[wid] = x;
  __syncthreads();
  if (tid == 0) {
    int acc = 0;
    #pragma unroll
    for (int w = 0; w < 8; w++) { int t = wpre[w]; wpre[w] = acc; acc += t; }
  }
  __syncthreads();
  int excl = wpre[wid] + x - v;
  bbase[tid] = excl;
  gcursor[tid] = excl;
  if (tid == 511) bbase[512] = excl + v;
}

__global__ __launch_bounds__(256) void k_binscatter(const int* __restrict__ ei, int* __restrict__ gcursor,
                                                    unsigned int* __restrict__ pairs, int E, int EN) {
  __shared__ int cnt[512];
  __shared__ int base[512];
  int tid = threadIdx.x;
  cnt[tid] = 0; cnt[tid + 256] = 0;
  __syncthreads();
  int eb = blockIdx.x * 4096;
  int srcs[16], dsts[16];
  #pragma unroll
  for (int i = 0; i < 16; i++) {
    int e = eb + i * 256 + tid;
    srcs[i] = -1; dsts[i] = 0;
    if (e < EN) {
      int s, d;
      if (e < E) { s = ei[e]; d = ei[E + e]; } else { s = e - E; d = s; }
      srcs[i] = s; dsts[i] = d;
      atomicAdd(&cnt[d >> CSR_SHIFT], 1);
    }
  }
  __syncthreads();
  for (int b = tid; b < 512; b += 256) {
    int c = cnt[b];
    base[b] = c ? atomicAdd(&gcursor[b], c) : 0;
    cnt[b] = 0;
  }
  __syncthreads();
  #pragma unroll
  for (int i = 0; i < 16; i++) {
    if (srcs[i] >= 0) {
      int b = dsts[i] >> CSR_SHIFT;
      int loc = atomicAdd(&cnt[b], 1);
      pairs[base[b] + loc] = ((unsigned int)srcs[i] << CSR_SHIFT) | (unsigned int)(dsts[i] & 127);
    }
  }
}

__global__ __launch_bounds__(128) void k_bucketdeg(const unsigned int* __restrict__ pairs,
                                                   const int* __restrict__ bbase,
                                                   int* __restrict__ deg, int N) {
  __shared__ int dcount[128];
  int b = blockIdx.x, tid = threadIdx.x;
  dcount[tid] = 0;
  __syncthreads();
  int s = bbase[b], e = bbase[b + 1];
  for (int i = s + tid; i < e; i += 128)
    atomicAdd(&dcount[pairs[i] & 127], 1);
  __syncthreads();
  int node = (b << CSR_SHIFT) + tid;
  if (node < N) deg[node] = dcount[tid];
}

__global__ __launch_bounds__(1024) void k_scan(const int* __restrict__ deg, int* __restrict__ rs, int N) {
  __shared__ int wpre[16];
  __shared__ int running_s;
  int tid = threadIdx.x, lane = tid & 63, wid = tid >> 6;
  if (tid == 0) running_s = 0;
  __syncthreads();
  for (int base = 0; base <= N; base += 1024) {
    int idx = base + tid;
    int v = (idx < N) ? deg[idx] : 0;
    int x = v;
    #pragma unroll
    for (int off = 1; off < 64; off <<= 1) {
      int y = __shfl_up(x, off);
      if (lane >= off) x += y;
    }
    if (lane == 63) wpre[wid] = x;
    __syncthreads();
    if (tid == 0) {
      int acc = running_s;
      #pragma unroll
      for (int w = 0; w < 16; w++) { int t = wpre[w]; wpre[w] = acc; acc += t; }
      running_s = acc;
    }
    __syncthreads();
    int excl = wpre[wid] + x - v;
    if (idx <= N) rs[idx] = excl;
    __syncthreads();
  }
}

__global__ __launch_bounds__(256) void k_scatter2(const unsigned int* __restrict__ pairs,
                                                  const int* __restrict__ bbase, const int* __restrict__ rs,
                                                  int* __restrict__ col, int N) {
  __shared__ int lcur[128];
  int b = blockIdx.x, tid = threadIdx.x;
  if (tid < 128) {
    int node = (b << CSR_SHIFT) + tid;
    lcur[tid] = (node < N) ? rs[node] : 0;
  }
  __syncthreads();
  int s = bbase[b], e = bbase[b + 1];
  for (int i = s + tid; i < e; i += 256) {
    unsigned int p = pairs[i];
    int pos = atomicAdd(&lcur[p & 127], 1);
    col[pos] = (int)(p >> CSR_SHIFT);
  }
}

// ---------------- layer-0 GEMM (K=4), folded logits ----------------
__global__ __launch_bounds__(256) void k_gemm0(const float* __restrict__ x, const float* __restrict__ W0p,
    __hip_bfloat16* __restrict__ h, float* __restrict__ als, float* __restrict__ ald, int N) {
  int t = blockIdx.x * 256 + threadIdx.x;
  int nrow = t / 144, c = t - nrow * 144;
  if (nrow >= N || c >= 136) return;
  float4 xv = *(const float4*)(x + (size_t)nrow * 4);
  float acc = fmaf(xv.x, W0p[c], fmaf(xv.y, W0p[144 + c], fmaf(xv.z, W0p[288 + c], xv.w * W0p[432 + c])));
  if (c < 128)      h[(size_t)nrow * 128 + c] = __float2bfloat16(acc);
  else if (c < 132) als[(size_t)nrow * 4 + (c - 128)] = acc;
  else              ald[(size_t)nrow * 4 + (c - 132)] = acc;
}

// ---------------- MFMA GEMM ----------------
template <int CT, int DOUT, int HEADS>
__global__ __launch_bounds__(256) void k_mm(const __hip_bfloat16* __restrict__ xa,
    const __hip_bfloat16* __restrict__ Wt,
    __hip_bfloat16* __restrict__ h, float* __restrict__ als, float* __restrict__ ald, int N) {
  __shared__ unsigned short A_s[64 * 128];
  __shared__ unsigned short B_s[CT * 16 * 128];
  int tid = threadIdx.x;
  int row0 = blockIdx.x * 64;

  for (int i = tid; i < 1024; i += 256) {
    int r = i >> 4, slot = i & 15;
    int gr = row0 + r;
    float4 v = make_float4(0.f, 0.f, 0.f, 0.f);
    if (gr < N) v = ((const float4*)(xa + (size_t)gr * 128))[slot];
    *(float4*)((char*)A_s + r * 256 + ((slot ^ (r & 7)) << 4)) = v;
  }
  for (int i = tid; i < CT * 256; i += 256) {
    int r = i >> 4, slot = i & 15;
    float4 v = ((const float4*)Wt)[i];
    *(float4*)((char*)B_s + r * 256 + ((slot ^ (r & 7)) << 4)) = v;
  }
  __syncthreads();

  int l = tid & 63, w = tid >> 6;
  int lr = l & 15, lg = l >> 4;
  f32x4 acc[CT];
  #pragma unroll
  for (int ct = 0; ct < CT; ct++) acc[ct] = (f32x4){0.f, 0.f, 0.f, 0.f};

  int rA = w * 16 + lr;
  #pragma unroll
  for (int k0 = 0; k0 < 4; k0++) {
    int slot = k0 * 4 + lg;
    bf16x8 a = *(const bf16x8*)((const char*)A_s + rA * 256 + ((slot ^ (rA & 7)) << 4));
    #pragma unroll
    for (int ct = 0; ct < CT; ct++) {
      int rB = ct * 16 + lr;
      bf16x8 b = *(const bf16x8*)((const char*)B_s + rB * 256 + ((slot ^ (rB & 7)) << 4));
      acc[ct] = __builtin_amdgcn_mfma_f32_16x16x32_bf16(a, b, acc[ct], 0, 0, 0);
    }
  }

  #pragma unroll
  for (int ct = 0; ct < CT; ct++) {
    #pragma unroll
    for (int j = 0; j < 4; j++) {
      int gr = row0 + w * 16 + lg * 4 + j;
      if (gr >= N) continue;
      int col = ct * 16 + lr;
      float v = acc[ct][j];
      if (col < DOUT)                 h[(size_t)gr * DOUT + col] = __float2bfloat16(v);
      else if (col < DOUT + HEADS)    als[(size_t)gr * HEADS + (col - DOUT)] = v;
      else if (col < DOUT + 2*HEADS)  ald[(size_t)gr * HEADS + (col - DOUT - HEADS)] = v;
    }
  }
}

// ---------------- aggregation, H=4 C=32: 32-lane group per node, single pass ----------------
__global__ __launch_bounds__(256) void k_agg4(const __hip_bfloat16* __restrict__ h, const float* __restrict__ als,
    const float* __restrict__ ald, const int* __restrict__ rs, const int* __restrict__ col,
    const float* __restrict__ bias, const float* __restrict__ bng,
    const float* __restrict__ bnb, const float* __restrict__ bnm,
    const float* __restrict__ bnv, __hip_bfloat16* __restrict__ out, int N) {
  __shared__ int svs[8][32];
  __shared__ float ps[8][32][4];
  int tid = threadIdx.x;
  int sub = tid & 31, gi = tid >> 5;
  int n = blockIdx.x * 8 + gi;
  if (n >= N) return;
  int row = rs[n], deg = rs[n + 1] - row;
  float4 ad4 = *(const float4*)(ald + (size_t)n * 4);
  int hh2 = sub >> 3;                 // head of channel group 4*sub
  float acc0 = 0.f, acc1 = 0.f, acc2 = 0.f, acc3 = 0.f;
  float s0 = 0.f, s1 = 0.f, s2 = 0.f, s3 = 0.f;

  for (int base = 0; base < deg; base += 32) {
    int k = base + sub;
    int sv = 0; float q0 = 0.f, q1 = 0.f, q2 = 0.f, q3 = 0.f;
    if (k < deg) {
      sv = col[row + k];
      float4 a4 = *(const float4*)(als + (size_t)sv * 4);
      q0 = __expf(lrelu(a4.x + ad4.x));
      q1 = __expf(lrelu(a4.y + ad4.y));
      q2 = __expf(lrelu(a4.z + ad4.z));
      q3 = __expf(lrelu(a4.w + ad4.w));
    }
    svs[gi][sub] = sv;
    *(float4*)&ps[gi][sub][0] = make_float4(q0, q1, q2, q3);
    s0 += q0; s1 += q1; s2 += q2; s3 += q3;
    int cnt = min(32, deg - base);
    // wave-synchronous LDS: group-private, same wave, program order
    int e = 0;
    for (; e + 1 < cnt; e += 2) {
      float pa = ps[gi][e][hh2];     int sa = svs[gi][e];
      float pb = ps[gi][e + 1][hh2]; int sb = svs[gi][e + 1];
      uint2 ha = *((const uint2*)(h + (size_t)sa * 128) + sub);
      uint2 hb = *((const uint2*)(h + (size_t)sb * 128) + sub);
      acc0 = fmaf(pa, blo(ha.x), acc0); acc1 = fmaf(pa, bhi(ha.x), acc1);
      acc2 = fmaf(pa, blo(ha.y), acc2); acc3 = fmaf(pa, bhi(ha.y), acc3);
      acc0 = fmaf(pb, blo(hb.x), acc0); acc1 = fmaf(pb, bhi(hb.x), acc1);
      acc2 = fmaf(pb, blo(hb.y), acc2); acc3 = fmaf(pb, bhi(hb.y), acc3);
    }
    if (e < cnt) {
      float pa = ps[gi][e][hh2]; int sa = svs[gi][e];
      uint2 ha = *((const uint2*)(h + (size_t)sa * 128) + sub);
      acc0 = fmaf(pa, blo(ha.x), acc0); acc1 = fmaf(pa, bhi(ha.x), acc1);
      acc2 = fmaf(pa, blo(ha.y), acc2); acc3 = fmaf(pa, bhi(ha.y), acc3);
    }
  }
  #pragma unroll
  for (int off = 1; off < 32; off <<= 1) {
    s0 += __shfl_xor(s0, off); s1 += __shfl_xor(s1, off);
    s2 += __shfl_xor(s2, off); s3 += __shfl_xor(s3, off);
  }
  float ssel = hh2 == 0 ? s0 : hh2 == 1 ? s1 : hh2 == 2 ? s2 : s3;
  float inv = 1.f / (ssel + 1e-16f);
  acc0 *= inv; acc1 *= inv; acc2 *= inv; acc3 *= inv;

  int c0 = 4 * sub;
  float4 bi = *(const float4*)(bias + c0);
  float4 bm = *(const float4*)(bnm + c0);
  float4 bv = *(const float4*)(bnv + c0);
  float4 bg = *(const float4*)(bng + c0);
  float4 bb = *(const float4*)(bnb + c0);
  float v0 = (acc0 + bi.x - bm.x) * rsqrtf(bv.x + BN_EPS) * bg.x + bb.x;
  float v1 = (acc1 + bi.y - bm.y) * rsqrtf(bv.y + BN_EPS) * bg.y + bb.y;
  float v2 = (acc2 + bi.z - bm.z) * rsqrtf(bv.z + BN_EPS) * bg.z + bb.z;
  float v3 = (acc3 + bi.w - bm.w) * rsqrtf(bv.w + BN_EPS) * bg.w + bb.w;
  v0 = elu_fast(v0); v1 = elu_fast(v1); v2 = elu_fast(v2); v3 = elu_fast(v3);
  uint2 packed;
  packed.x = ((unsigned int)f2bu(v1) << 16) | f2bu(v0);
  packed.y = ((unsigned int)f2bu(v3) << 16) | f2bu(v2);
  *((uint2*)((unsigned short*)out + (size_t)n * 128) + sub) = packed;
}

// ---------------- aggregation, H=1 C=32: 16-lane group per node, single pass ----------------
__global__ __launch_bounds__(256) void k_agg1(const __hip_bfloat16* __restrict__ h, const float* __restrict__ als,
    const float* __restrict__ ald, const int* __restrict__ rs, const int* __restrict__ col,
    const float* __restrict__ bias, const float* __restrict__ bng,
    const float* __restrict__ bnb, const float* __restrict__ bnm,
    const float* __restrict__ bnv, __hip_bfloat16* __restrict__ out, int N) {
  __shared__ int svs[16][16];
  __shared__ float ps[16][16];
  int tid = threadIdx.x;
  int sub = tid & 15, gi = tid >> 4;
  int n = blockIdx.x * 16 + gi;
  if (n >= N) return;
  int row = rs[n], deg = rs[n + 1] - row;
  float ad = ald[n];
  float acc0 = 0.f, acc1 = 0.f, s = 0.f;

  for (int base = 0; base < deg; base += 16) {
    int k = base + sub;
    int sv = 0; float q = 0.f;
    if (k < deg) {
      sv = col[row + k];
      q = __expf(lrelu(als[sv] + ad));
    }
    svs[gi][sub] = sv;
    ps[gi][sub] = q;
    s += q;
    int cnt = min(16, deg - base);
    int e = 0;
    for (; e + 1 < cnt; e += 2) {
      float pa = ps[gi][e];     int sa = svs[gi][e];
      float pb = ps[gi][e + 1]; int sb = svs[gi][e + 1];
      unsigned int ha = *((const unsigned int*)(h + (size_t)sa * 32) + sub);
      unsigned int hb = *((const unsigned int*)(h + (size_t)sb * 32) + sub);
      acc0 = fmaf(pa, blo(ha), acc0); acc1 = fmaf(pa, bhi(ha), acc1);
      acc0 = fmaf(pb, blo(hb), acc0); acc1 = fmaf(pb, bhi(hb), acc1);
    }
    if (e < cnt) {
      float pa = ps[gi][e]; int sa = svs[gi][e];
      unsigned int ha = *((const unsigned int*)(h + (size_t)sa * 32) + sub);
      acc0 = fmaf(pa, blo(ha), acc0); acc1 = fmaf(pa, bhi(ha), acc1);
    }
  }
  #pragma unroll
  for (int off = 1; off < 16; off <<= 1) s += __shfl_xor(s, off);
  float inv = 1.f / (s + 1e-16f);
  acc0 *= inv; acc1 *= inv;

  int c0 = 2 * sub;
  float2 bi = *(const float2*)(bias + c0);
  float2 bm = *(const float2*)(bnm + c0);
  float2 bv = *(const float2*)(bnv + c0);
  float2 bg = *(const float2*)(bng + c0);
  float2 bb = *(const float2*)(bnb + c0);
  float v0 = (acc0 + bi.x - bm.x) * rsqrtf(bv.x + BN_EPS) * bg.x + bb.x;
  float v1 = (acc1 + bi.y - bm.y) * rsqrtf(bv.y + BN_EPS) * bg.y + bb.y;
  v0 = elu_fast(v0);
  v1 = elu_fast(v1);
  unsigned int packed = ((unsigned int)f2bu(v1) << 16) | f2bu(v0);
  *((unsigned int*)((unsigned short*)out + (size_t)n * 32) + sub) = packed;
}

// ---------------- per-graph pooling + MLP head ----------------
__global__ __launch_bounds__(64) void k_pool(const __hip_bfloat16* __restrict__ x3, const int* __restrict__ batch,
    const float* __restrict__ u, const float* __restrict__ l1w,
    const float* __restrict__ l1b, const float* __restrict__ l2w,
    const float* __restrict__ l2b, float* __restrict__ out, int N, int G) {
  int g = blockIdx.x;
  int lane = threadIdx.x;
  int lo = 0, hi = N;
  while (lo < hi) { int mid = (lo + hi) >> 1; if (batch[mid] < g) lo = mid + 1; else hi = mid; }
  int start = lo;
  hi = N;
  while (lo < hi) { int mid = (lo + hi) >> 1; if (batch[mid] < g + 1) lo = mid + 1; else hi = mid; }
  int end = lo;
  int sub = lane & 15, q = lane >> 4;
  float sum0 = 0.f, sum1 = 0.f, mx0 = -1e30f, mx1 = -1e30f;
  for (int i = start + q; i < end; i += 4) {
    unsigned int hv = *((const unsigned int*)(x3 + (size_t)i * 32) + sub);
    float v0 = blo(hv), v1 = bhi(hv);
    sum0 += v0; sum1 += v1;
    mx0 = fmaxf(mx0, v0); mx1 = fmaxf(mx1, v1);
  }
  sum0 += __shfl_xor(sum0, 16); sum0 += __shfl_xor(sum0, 32);
  sum1 += __shfl_xor(sum1, 16); sum1 += __shfl_xor(sum1, 32);
  mx0 = fmaxf(mx0, __shfl_xor(mx0, 16)); mx0 = fmaxf(mx0, __shfl_xor(mx0, 32));
  mx1 = fmaxf(mx1, __shfl_xor(mx1, 16)); mx1 = fmaxf(mx1, __shfl_xor(mx1, 32));
  __shared__ float comb[74];
  if (lane < 16) {
    float cnt = (float)(end - start);
    comb[2 * lane] = sum0 / cnt;
    comb[2 * lane + 1] = sum1 / cnt;
    comb[32 + 2 * lane] = mx0;
    comb[32 + 2 * lane + 1] = mx1;
  }
  if (lane < 10) comb[64 + lane] = u[g * 10 + lane];
  __syncthreads();
  if (lane < 32) {
    float acc = l1b[lane];
    #pragma unroll
    for (int k = 0; k < 74; k++) acc = fmaf(comb[k], l1w[k * 32 + lane], acc);
    acc = fmaxf(acc, 0.f);
    float v = acc * l2w[lane];
    #pragma unroll
    for (int off = 16; off; off >>= 1) v += __shfl_xor(v, off, 32);
    if (lane == 0) out[g] = 1.f / (1.f + __expf(-(v + l2b[0])));
  }
}

extern "C" void kernel_launch(void* const* d_in, const int* in_sizes, int n_in,
                              void* d_out, int out_size, void* d_ws, size_t ws_size,
                              hipStream_t stream) {
  const int* EI    = (const int*)d_in[1];
  const int* BATCH = (const int*)d_in[2];
  float* OUT = (float*)d_out;

  int N = in_sizes[2];
  int E = in_sizes[1] / 2;
  int G = in_sizes[3] / 10;
  int EN = E + N;
  int NB = (N + 127) >> 7;

  char* ws = (char*)d_ws;
  size_t off = 0;
  auto alloc = [&](size_t bytes) {
    void* p = ws + off;
    off = (off + bytes + 255) & ~(size_t)255;
    return p;
  };
  __hip_bfloat16* f_xa = (__hip_bfloat16*)alloc((size_t)N * 128 * 2);
  __hip_bfloat16* f_h  = (__hip_bfloat16*)alloc((size_t)N * 128 * 2);
  float* f_als = (float*)alloc((size_t)N * 4 * 4);
  float* f_ald = (float*)alloc((size_t)N * 4 * 4);
  float* fW0p  = (float*)alloc(576 * 4);
  __hip_bfloat16* fWt1 = (__hip_bfloat16*)alloc(144 * 128 * 2);
  __hip_bfloat16* fWt2 = (__hip_bfloat16*)alloc(48 * 128 * 2);
  int* i_deg  = (int*)alloc((size_t)(N + 1) * 4);
  int* i_rs   = (int*)alloc((size_t)(N + 1) * 4);
  int* i_col  = (int*)alloc((size_t)EN * 4);
  unsigned int* i_pairs = (unsigned int*)alloc((size_t)EN * 4);
  int* i_ghist   = (int*)alloc(512 * 4);
  int* i_bbase   = (int*)alloc(513 * 4);
  int* i_gcursor = (int*)alloc(512 * 4);
  int* i_flag = (int*)alloc(256);

  CvtArgs ca;
  float* fptr[32];
  int maxn = 0, na = 0;
  for (int i = 0; i < 32; i++) {
    if (i == 1 || i == 2) { fptr[i] = nullptr; continue; }
    int n = in_sizes[i];
    fptr[i] = (float*)alloc((size_t)n * 4);
    ca.src[na] = d_in[i];
    ca.dst[na] = fptr[i];
    ca.n[na] = n;
    if (n > maxn) maxn = n;
    na++;
  }

  // dtype detect + convert
  k_detect<<<1, 256, 0, stream>>>((const unsigned short*)d_in[12], in_sizes[12], i_flag);
  dim3 cgrid((maxn + 255) / 256, na);
  k_cvt_all<<<cgrid, 256, 0, stream>>>(ca, i_flag);

  // weight folding
  k_foldW<<<99, 256, 0, stream>>>(fptr[4], fptr[5], fptr[6],
                                  fptr[12], fptr[13], fptr[14],
                                  fptr[20], fptr[21], fptr[22],
                                  fW0p, fWt1, fWt2);

  // bucketed CSR build
  hipMemsetAsync(i_ghist, 0, 512 * 4, stream);
  int ebks = (EN + 4095) / 4096;
  k_binhist<<<ebks, 256, 0, stream>>>(EI, i_ghist, E, EN);
  k_bucketscan<<<1, 512, 0, stream>>>(i_ghist, i_bbase, i_gcursor);
  k_binscatter<<<ebks, 256, 0, stream>>>(EI, i_gcursor, i_pairs, E, EN);
  k_bucketdeg<<<NB, 128, 0, stream>>>(i_pairs, i_bbase, i_deg, N);
  k_scan<<<1, 1024, 0, stream>>>(i_deg, i_rs, N);
  k_scatter2<<<NB, 256, 0, stream>>>(i_pairs, i_bbase, i_rs, i_col, N);

  // layer 0
  k_gemm0<<<(N * 144 + 255) / 256, 256, 0, stream>>>(fptr[0], fW0p, f_h, f_als, f_ald, N);
  k_agg4<<<(N + 7) / 8, 256, 0, stream>>>(f_h, f_als, f_ald, i_rs, i_col, fptr[7], fptr[8], fptr[9], fptr[10], fptr[11], f_xa, N);
  // layer 1 (MFMA)
  k_mm<9, 128, 4><<<(N + 63) / 64, 256, 0, stream>>>(f_xa, fWt1, f_h, f_als, f_ald, N);
  k_agg4<<<(N + 7) / 8, 256, 0, stream>>>(f_h, f_als, f_ald, i_rs, i_col, fptr[15], fptr[16], fptr[17], fptr[18], fptr[19], f_xa, N);
  // layer 2 (MFMA)
  k_mm<3, 32, 1><<<(N + 63) / 64, 256, 0, stream>>>(f_xa, fWt2, f_h, f_als, f_ald, N);
  k_agg1<<<(N + 15) / 16, 256, 0, stream>>>(f_h, f_als, f_ald, i_rs, i_col, fptr[23], fptr[24], fptr[25], fptr[26], fptr[27], f_xa, N);

  // pooling + MLP head
  k_pool<<<G, 64, 0, stream>>>(f_xa, BATCH, fptr[3], fptr[28], fptr[29], fptr[30], fptr[31], OUT, N, G);
}

// Round 11
// 211.698 us; speedup vs baseline: 2.8153x; 1.1869x over previous
//
#include <hip/hip_runtime.h>
#include <hip/hip_bf16.h>
#include <math.h>

#define LRELU_NEG 0.2f
#define BN_EPS 1e-5f
#define CSR_SHIFT 7

typedef __attribute__((ext_vector_type(8))) short bf16x8;
typedef __attribute__((ext_vector_type(4))) float f32x4;

__device__ __forceinline__ float lrelu(float x) { return x > 0.f ? x : LRELU_NEG * x; }
__device__ __forceinline__ float b2f(__hip_bfloat16 v) { return __bfloat162float(v); }
__device__ __forceinline__ unsigned short f2bu(float v) {
  __hip_bfloat16 b = __float2bfloat16(v);
  return *(unsigned short*)&b;
}
__device__ __forceinline__ float blo(unsigned int u) { return __uint_as_float(u << 16); }
__device__ __forceinline__ float bhi(unsigned int u) { return __uint_as_float(u & 0xFFFF0000u); }
__device__ __forceinline__ float elu_fast(float v) { return v > 0.f ? v : __expf(v) - 1.f; }

// ---------------- dtype detection ----------------
__global__ __launch_bounds__(256) void k_detect(const unsigned short* __restrict__ w, int n,
                                                int* __restrict__ flag) {
  __shared__ int bad_s;
  if (threadIdx.x == 0) bad_s = 0;
  __syncthreads();
  int bad = 0;
  for (int i = 2 * threadIdx.x; i < n; i += 512) {
    unsigned short u = w[i];
    if ((u & 0x7FFF) == 0) continue;
    int ex = (u >> 7) & 0xFF;
    if (ex > 131 || ex < 90) bad++;
  }
  atomicAdd(&bad_s, bad);
  __syncthreads();
  if (threadIdx.x == 0) *flag = (bad_s < 2048) ? 1 : 0;
}

// ---------------- unified input conversion -> f32 in ws ----------------
struct CvtArgs {
  const void* src[30];
  float* dst[30];
  int n[30];
};

__global__ __launch_bounds__(256) void k_cvt_all(CvtArgs a, const int* __restrict__ flag) {
  int ai = blockIdx.y;
  int n = a.n[ai];
  int i = blockIdx.x * 256 + threadIdx.x;
  if (i >= n) return;
  if (*flag) {
    a.dst[ai][i] = b2f(((const __hip_bfloat16*)a.src[ai])[i]);
  } else {
    a.dst[ai][i] = ((const float*)a.src[ai])[i];
  }
}

// ---------------- weight folding ----------------
__global__ __launch_bounds__(256) void k_foldW(const float* __restrict__ W0, const float* __restrict__ as0, const float* __restrict__ ad0,
                                               const float* __restrict__ W1, const float* __restrict__ as1, const float* __restrict__ ad1,
                                               const float* __restrict__ W2, const float* __restrict__ as2, const float* __restrict__ ad2,
                                               float* __restrict__ W0p, __hip_bfloat16* __restrict__ Wt1, __hip_bfloat16* __restrict__ Wt2) {
  int idx = blockIdx.x * 256 + threadIdx.x;
  if (idx < 576) {                  // W0p [4][144]
    int k = idx / 144, c = idx % 144;
    float v = 0.f;
    if (c < 128) v = W0[k * 128 + c];
    else if (c < 136) {
      int hh = (c - 128) & 3; const float* a = (c < 132) ? as0 : ad0;
      float s = 0.f;
      for (int cc = 0; cc < 32; cc++) s += W0[k * 128 + hh * 32 + cc] * a[hh * 32 + cc];
      v = s;
    }
    W0p[k * 144 + c] = v;
    return;
  }
  idx -= 576;
  if (idx < 144 * 128) {            // Wt1 [144][128]
    int c = idx >> 7, k = idx & 127;
    float v = 0.f;
    if (c < 128) v = W1[k * 128 + c];
    else if (c < 136) {
      int hh = (c - 128) & 3; const float* a = (c < 132) ? as1 : ad1;
      float s = 0.f;
      for (int cc = 0; cc < 32; cc++) s += W1[k * 128 + hh * 32 + cc] * a[hh * 32 + cc];
      v = s;
    }
    Wt1[c * 128 + k] = __float2bfloat16(v);
    return;
  }
  idx -= 144 * 128;
  if (idx < 48 * 128) {             // Wt2 [48][128]
    int c = idx >> 7, k = idx & 127;
    float v = 0.f;
    if (c < 32) v = W2[k * 32 + c];
    else if (c == 32) { float s = 0.f; for (int cc = 0; cc < 32; cc++) s += W2[k * 32 + cc] * as2[cc]; v = s; }
    else if (c == 33) { float s = 0.f; for (int cc = 0; cc < 32; cc++) s += W2[k * 32 + cc] * ad2[cc]; v = s; }
    Wt2[c * 128 + k] = __float2bfloat16(v);
  }
}

// ================= bucketed CSR build =================
__global__ __launch_bounds__(256) void k_binhist(const int* __restrict__ ei, int* __restrict__ ghist,
                                                 int E, int EN) {
  __shared__ int hist[512];
  int tid = threadIdx.x;
  hist[tid] = 0; hist[tid + 256] = 0;
  __syncthreads();
  int base = blockIdx.x * 4096;
  for (int i = 0; i < 16; i++) {
    int e = base + i * 256 + tid;
    if (e < EN) {
      int dst = (e < E) ? ei[E + e] : (e - E);
      atomicAdd(&hist[dst >> CSR_SHIFT], 1);
    }
  }
  __syncthreads();
  if (hist[tid]) atomicAdd(&ghist[tid], hist[tid]);
  if (hist[tid + 256]) atomicAdd(&ghist[tid + 256], hist[tid + 256]);
}

__global__ __launch_bounds__(512) void k_bucketscan(const int* __restrict__ ghist,
                                                    int* __restrict__ bbase, int* __restrict__ gcursor) {
  __shared__ int wpre[8];
  int tid = threadIdx.x, lane = tid & 63, wid = tid >> 6;
  int v = ghist[tid];
  int x = v;
  #pragma unroll
  for (int off = 1; off < 64; off <<= 1) {
    int y = __shfl_up(x, off);
    if (lane >= off) x += y;
  }
  if (lane == 63) wpre[wid] = x;
  __syncthreads();
  if (tid == 0) {
    int acc = 0;
    #pragma unroll
    for (int w = 0; w < 8; w++) { int t = wpre[w]; wpre[w] = acc; acc += t; }
  }
  __syncthreads();
  int excl = wpre[wid] + x - v;
  bbase[tid] = excl;
  gcursor[tid] = excl;
  if (tid == 511) bbase[512] = excl + v;
}

__global__ __launch_bounds__(256) void k_binscatter(const int* __restrict__ ei, int* __restrict__ gcursor,
                                                    unsigned int* __restrict__ pairs, int E, int EN) {
  __shared__ int cnt[512];
  __shared__ int base[512];
  int tid = threadIdx.x;
  cnt[tid] = 0; cnt[tid + 256] = 0;
  __syncthreads();
  int eb = blockIdx.x * 4096;
  int srcs[16], dsts[16];
  #pragma unroll
  for (int i = 0; i < 16; i++) {
    int e = eb + i * 256 + tid;
    srcs[i] = -1; dsts[i] = 0;
    if (e < EN) {
      int s, d;
      if (e < E) { s = ei[e]; d = ei[E + e]; } else { s = e - E; d = s; }
      srcs[i] = s; dsts[i] = d;
      atomicAdd(&cnt[d >> CSR_SHIFT], 1);
    }
  }
  __syncthreads();
  for (int b = tid; b < 512; b += 256) {
    int c = cnt[b];
    base[b] = c ? atomicAdd(&gcursor[b], c) : 0;
    cnt[b] = 0;
  }
  __syncthreads();
  #pragma unroll
  for (int i = 0; i < 16; i++) {
    if (srcs[i] >= 0) {
      int b = dsts[i] >> CSR_SHIFT;
      int loc = atomicAdd(&cnt[b], 1);
      pairs[base[b] + loc] = ((unsigned int)srcs[i] << CSR_SHIFT) | (unsigned int)(dsts[i] & 127);
    }
  }
}

// per-bucket degree histogram + in-block 128-scan -> rs directly (replaces global scan)
__global__ __launch_bounds__(128) void k_bucketrs(const unsigned int* __restrict__ pairs,
                                                  const int* __restrict__ bbase,
                                                  int* __restrict__ rs, int N, int EN) {
  __shared__ int dcount[128];
  __shared__ int wsum;
  int b = blockIdx.x, tid = threadIdx.x;
  dcount[tid] = 0;
  __syncthreads();
  int s = bbase[b], e = bbase[b + 1];
  for (int i = s + tid; i < e; i += 128)
    atomicAdd(&dcount[pairs[i] & 127], 1);
  __syncthreads();
  int v = dcount[tid];
  int lane = tid & 63, wid = tid >> 6;
  int x = v;
  #pragma unroll
  for (int off = 1; off < 64; off <<= 1) {
    int y = __shfl_up(x, off);
    if (lane >= off) x += y;
  }
  if (wid == 0 && lane == 63) wsum = x;
  __syncthreads();
  int excl = x - v + (wid ? wsum : 0);
  int node = (b << CSR_SHIFT) + tid;
  if (node < N) rs[node] = s + excl;
  if (b == 0 && tid == 0) rs[N] = EN;
}

__global__ __launch_bounds__(256) void k_scatter2(const unsigned int* __restrict__ pairs,
                                                  const int* __restrict__ bbase, const int* __restrict__ rs,
                                                  int* __restrict__ col, int N) {
  __shared__ int lcur[128];
  int b = blockIdx.x, tid = threadIdx.x;
  if (tid < 128) {
    int node = (b << CSR_SHIFT) + tid;
    lcur[tid] = (node < N) ? rs[node] : 0;
  }
  __syncthreads();
  int s = bbase[b], e = bbase[b + 1];
  for (int i = s + tid; i < e; i += 256) {
    unsigned int p = pairs[i];
    int pos = atomicAdd(&lcur[p & 127], 1);
    col[pos] = (int)(p >> CSR_SHIFT);
  }
}

// ---------------- layer-0 GEMM (K=4), folded logits ----------------
__global__ __launch_bounds__(256) void k_gemm0(const float* __restrict__ x, const float* __restrict__ W0p,
    __hip_bfloat16* __restrict__ h, float* __restrict__ als, float* __restrict__ ald, int N) {
  int t = blockIdx.x * 256 + threadIdx.x;
  int nrow = t / 144, c = t - nrow * 144;
  if (nrow >= N || c >= 136) return;
  float4 xv = *(const float4*)(x + (size_t)nrow * 4);
  float acc = fmaf(xv.x, W0p[c], fmaf(xv.y, W0p[144 + c], fmaf(xv.z, W0p[288 + c], xv.w * W0p[432 + c])));
  if (c < 128)      h[(size_t)nrow * 128 + c] = __float2bfloat16(acc);
  else if (c < 132) als[(size_t)nrow * 4 + (c - 128)] = acc;
  else              ald[(size_t)nrow * 4 + (c - 132)] = acc;
}

// ---------------- MFMA GEMM ----------------
template <int CT, int DOUT, int HEADS>
__global__ __launch_bounds__(256) void k_mm(const __hip_bfloat16* __restrict__ xa,
    const __hip_bfloat16* __restrict__ Wt,
    __hip_bfloat16* __restrict__ h, float* __restrict__ als, float* __restrict__ ald, int N) {
  __shared__ unsigned short A_s[64 * 128];
  __shared__ unsigned short B_s[CT * 16 * 128];
  int tid = threadIdx.x;
  int row0 = blockIdx.x * 64;

  for (int i = tid; i < 1024; i += 256) {
    int r = i >> 4, slot = i & 15;
    int gr = row0 + r;
    float4 v = make_float4(0.f, 0.f, 0.f, 0.f);
    if (gr < N) v = ((const float4*)(xa + (size_t)gr * 128))[slot];
    *(float4*)((char*)A_s + r * 256 + ((slot ^ (r & 7)) << 4)) = v;
  }
  for (int i = tid; i < CT * 256; i += 256) {
    int r = i >> 4, slot = i & 15;
    float4 v = ((const float4*)Wt)[i];
    *(float4*)((char*)B_s + r * 256 + ((slot ^ (r & 7)) << 4)) = v;
  }
  __syncthreads();

  int l = tid & 63, w = tid >> 6;
  int lr = l & 15, lg = l >> 4;
  f32x4 acc[CT];
  #pragma unroll
  for (int ct = 0; ct < CT; ct++) acc[ct] = (f32x4){0.f, 0.f, 0.f, 0.f};

  int rA = w * 16 + lr;
  #pragma unroll
  for (int k0 = 0; k0 < 4; k0++) {
    int slot = k0 * 4 + lg;
    bf16x8 a = *(const bf16x8*)((const char*)A_s + rA * 256 + ((slot ^ (rA & 7)) << 4));
    #pragma unroll
    for (int ct = 0; ct < CT; ct++) {
      int rB = ct * 16 + lr;
      bf16x8 b = *(const bf16x8*)((const char*)B_s + rB * 256 + ((slot ^ (rB & 7)) << 4));
      acc[ct] = __builtin_amdgcn_mfma_f32_16x16x32_bf16(a, b, acc[ct], 0, 0, 0);
    }
  }

  #pragma unroll
  for (int ct = 0; ct < CT; ct++) {
    #pragma unroll
    for (int j = 0; j < 4; j++) {
      int gr = row0 + w * 16 + lg * 4 + j;
      if (gr >= N) continue;
      int col = ct * 16 + lr;
      float v = acc[ct][j];
      if (col < DOUT)                 h[(size_t)gr * DOUT + col] = __float2bfloat16(v);
      else if (col < DOUT + HEADS)    als[(size_t)gr * HEADS + (col - DOUT)] = v;
      else if (col < DOUT + 2*HEADS)  ald[(size_t)gr * HEADS + (col - DOUT - HEADS)] = v;
    }
  }
}

// ---------------- aggregation, H=4 C=32: 32-lane group per node, single pass ----------------
__global__ __launch_bounds__(256) void k_agg4(const __hip_bfloat16* __restrict__ h, const float* __restrict__ als,
    const float* __restrict__ ald, const int* __restrict__ rs, const int* __restrict__ col,
    const float* __restrict__ bias, const float* __restrict__ bng,
    const float* __restrict__ bnb, const float* __restrict__ bnm,
    const float* __restrict__ bnv, __hip_bfloat16* __restrict__ out, int N) {
  __shared__ int svs[8][32];
  __shared__ float ps[8][32][4];
  int tid = threadIdx.x;
  int sub = tid & 31, gi = tid >> 5;
  int n = blockIdx.x * 8 + gi;
  if (n >= N) return;
  int row = rs[n], deg = rs[n + 1] - row;
  float4 ad4 = *(const float4*)(ald + (size_t)n * 4);
  int hh2 = sub >> 3;
  float acc0 = 0.f, acc1 = 0.f, acc2 = 0.f, acc3 = 0.f;
  float s0 = 0.f, s1 = 0.f, s2 = 0.f, s3 = 0.f;

  for (int base = 0; base < deg; base += 32) {
    int k = base + sub;
    int sv = 0; float q0 = 0.f, q1 = 0.f, q2 = 0.f, q3 = 0.f;
    if (k < deg) {
      sv = col[row + k];
      float4 a4 = *(const float4*)(als + (size_t)sv * 4);
      q0 = __expf(lrelu(a4.x + ad4.x));
      q1 = __expf(lrelu(a4.y + ad4.y));
      q2 = __expf(lrelu(a4.z + ad4.z));
      q3 = __expf(lrelu(a4.w + ad4.w));
    }
    svs[gi][sub] = sv;
    *(float4*)&ps[gi][sub][0] = make_float4(q0, q1, q2, q3);
    s0 += q0; s1 += q1; s2 += q2; s3 += q3;
    int cnt = min(32, deg - base);
    int e = 0;
    for (; e + 1 < cnt; e += 2) {
      float pa = ps[gi][e][hh2];     int sa = svs[gi][e];
      float pb = ps[gi][e + 1][hh2]; int sb = svs[gi][e + 1];
      uint2 ha = *((const uint2*)(h + (size_t)sa * 128) + sub);
      uint2 hb = *((const uint2*)(h + (size_t)sb * 128) + sub);
      acc0 = fmaf(pa, blo(ha.x), acc0); acc1 = fmaf(pa, bhi(ha.x), acc1);
      acc2 = fmaf(pa, blo(ha.y), acc2); acc3 = fmaf(pa, bhi(ha.y), acc3);
      acc0 = fmaf(pb, blo(hb.x), acc0); acc1 = fmaf(pb, bhi(hb.x), acc1);
      acc2 = fmaf(pb, blo(hb.y), acc2); acc3 = fmaf(pb, bhi(hb.y), acc3);
    }
    if (e < cnt) {
      float pa = ps[gi][e][hh2]; int sa = svs[gi][e];
      uint2 ha = *((const uint2*)(h + (size_t)sa * 128) + sub);
      acc0 = fmaf(pa, blo(ha.x), acc0); acc1 = fmaf(pa, bhi(ha.x), acc1);
      acc2 = fmaf(pa, blo(ha.y), acc2); acc3 = fmaf(pa, bhi(ha.y), acc3);
    }
  }
  #pragma unroll
  for (int off = 1; off < 32; off <<= 1) {
    s0 += __shfl_xor(s0, off); s1 += __shfl_xor(s1, off);
    s2 += __shfl_xor(s2, off); s3 += __shfl_xor(s3, off);
  }
  float ssel = hh2 == 0 ? s0 : hh2 == 1 ? s1 : hh2 == 2 ? s2 : s3;
  float inv = 1.f / (ssel + 1e-16f);
  acc0 *= inv; acc1 *= inv; acc2 *= inv; acc3 *= inv;

  int c0 = 4 * sub;
  float4 bi = *(const float4*)(bias + c0);
  float4 bm = *(const float4*)(bnm + c0);
  float4 bv = *(const float4*)(bnv + c0);
  float4 bg = *(const float4*)(bng + c0);
  float4 bb = *(const float4*)(bnb + c0);
  float v0 = (acc0 + bi.x - bm.x) * rsqrtf(bv.x + BN_EPS) * bg.x + bb.x;
  float v1 = (acc1 + bi.y - bm.y) * rsqrtf(bv.y + BN_EPS) * bg.y + bb.y;
  float v2 = (acc2 + bi.z - bm.z) * rsqrtf(bv.z + BN_EPS) * bg.z + bb.z;
  float v3 = (acc3 + bi.w - bm.w) * rsqrtf(bv.w + BN_EPS) * bg.w + bb.w;
  v0 = elu_fast(v0); v1 = elu_fast(v1); v2 = elu_fast(v2); v3 = elu_fast(v3);
  uint2 packed;
  packed.x = ((unsigned int)f2bu(v1) << 16) | f2bu(v0);
  packed.y = ((unsigned int)f2bu(v3) << 16) | f2bu(v2);
  *((uint2*)((unsigned short*)out + (size_t)n * 128) + sub) = packed;
}

// ---------------- aggregation, H=1 C=32: 16-lane group per node, single pass ----------------
__global__ __launch_bounds__(256) void k_agg1(const __hip_bfloat16* __restrict__ h, const float* __restrict__ als,
    const float* __restrict__ ald, const int* __restrict__ rs, const int* __restrict__ col,
    const float* __restrict__ bias, const float* __restrict__ bng,
    const float* __restrict__ bnb, const float* __restrict__ bnm,
    const float* __restrict__ bnv, __hip_bfloat16* __restrict__ out, int N) {
  __shared__ int svs[16][16];
  __shared__ float ps[16][16];
  int tid = threadIdx.x;
  int sub = tid & 15, gi = tid >> 4;
  int n = blockIdx.x * 16 + gi;
  if (n >= N) return;
  int row = rs[n], deg = rs[n + 1] - row;
  float ad = ald[n];
  float acc0 = 0.f, acc1 = 0.f, s = 0.f;

  for (int base = 0; base < deg; base += 16) {
    int k = base + sub;
    int sv = 0; float q = 0.f;
    if (k < deg) {
      sv = col[row + k];
      q = __expf(lrelu(als[sv] + ad));
    }
    svs[gi][sub] = sv;
    ps[gi][sub] = q;
    s += q;
    int cnt = min(16, deg - base);
    int e = 0;
    for (; e + 1 < cnt; e += 2) {
      float pa = ps[gi][e];     int sa = svs[gi][e];
      float pb = ps[gi][e + 1]; int sb = svs[gi][e + 1];
      unsigned int ha = *((const unsigned int*)(h + (size_t)sa * 32) + sub);
      unsigned int hb = *((const unsigned int*)(h + (size_t)sb * 32) + sub);
      acc0 = fmaf(pa, blo(ha), acc0); acc1 = fmaf(pa, bhi(ha), acc1);
      acc0 = fmaf(pb, blo(hb), acc0); acc1 = fmaf(pb, bhi(hb), acc1);
    }
    if (e < cnt) {
      float pa = ps[gi][e]; int sa = svs[gi][e];
      unsigned int ha = *((const unsigned int*)(h + (size_t)sa * 32) + sub);
      acc0 = fmaf(pa, blo(ha), acc0); acc1 = fmaf(pa, bhi(ha), acc1);
    }
  }
  #pragma unroll
  for (int off = 1; off < 16; off <<= 1) s += __shfl_xor(s, off);
  float inv = 1.f / (s + 1e-16f);
  acc0 *= inv; acc1 *= inv;

  int c0 = 2 * sub;
  float2 bi = *(const float2*)(bias + c0);
  float2 bm = *(const float2*)(bnm + c0);
  float2 bv = *(const float2*)(bnv + c0);
  float2 bg = *(const float2*)(bng + c0);
  float2 bb = *(const float2*)(bnb + c0);
  float v0 = (acc0 + bi.x - bm.x) * rsqrtf(bv.x + BN_EPS) * bg.x + bb.x;
  float v1 = (acc1 + bi.y - bm.y) * rsqrtf(bv.y + BN_EPS) * bg.y + bb.y;
  v0 = elu_fast(v0);
  v1 = elu_fast(v1);
  unsigned int packed = ((unsigned int)f2bu(v1) << 16) | f2bu(v0);
  *((unsigned int*)((unsigned short*)out + (size_t)n * 32) + sub) = packed;
}

// ---------------- per-graph pooling + MLP head ----------------
__global__ __launch_bounds__(64) void k_pool(const __hip_bfloat16* __restrict__ x3, const int* __restrict__ batch,
    const float* __restrict__ u, const float* __restrict__ l1w,
    const float* __restrict__ l1b, const float* __restrict__ l2w,
    const float* __restrict__ l2b, float* __restrict__ out, int N, int G) {
  int g = blockIdx.x;
  int lane = threadIdx.x;
  int lo = 0, hi = N;
  while (lo < hi) { int mid = (lo + hi) >> 1; if (batch[mid] < g) lo = mid + 1; else hi = mid; }
  int start = lo;
  hi = N;
  while (lo < hi) { int mid = (lo + hi) >> 1; if (batch[mid] < g + 1) lo = mid + 1; else hi = mid; }
  int end = lo;
  int sub = lane & 15, q = lane >> 4;
  float sum0 = 0.f, sum1 = 0.f, mx0 = -1e30f, mx1 = -1e30f;
  for (int i = start + q; i < end; i += 4) {
    unsigned int hv = *((const unsigned int*)(x3 + (size_t)i * 32) + sub);
    float v0 = blo(hv), v1 = bhi(hv);
    sum0 += v0; sum1 += v1;
    mx0 = fmaxf(mx0, v0); mx1 = fmaxf(mx1, v1);
  }
  sum0 += __shfl_xor(sum0, 16); sum0 += __shfl_xor(sum0, 32);
  sum1 += __shfl_xor(sum1, 16); sum1 += __shfl_xor(sum1, 32);
  mx0 = fmaxf(mx0, __shfl_xor(mx0, 16)); mx0 = fmaxf(mx0, __shfl_xor(mx0, 32));
  mx1 = fmaxf(mx1, __shfl_xor(mx1, 16)); mx1 = fmaxf(mx1, __shfl_xor(mx1, 32));
  __shared__ float comb[74];
  if (lane < 16) {
    float cnt = (float)(end - start);
    comb[2 * lane] = sum0 / cnt;
    comb[2 * lane + 1] = sum1 / cnt;
    comb[32 + 2 * lane] = mx0;
    comb[32 + 2 * lane + 1] = mx1;
  }
  if (lane < 10) comb[64 + lane] = u[g * 10 + lane];
  __syncthreads();
  if (lane < 32) {
    float acc = l1b[lane];
    #pragma unroll
    for (int k = 0; k < 74; k++) acc = fmaf(comb[k], l1w[k * 32 + lane], acc);
    acc = fmaxf(acc, 0.f);
    float v = acc * l2w[lane];
    #pragma unroll
    for (int off = 16; off; off >>= 1) v += __shfl_xor(v, off, 32);
    if (lane == 0) out[g] = 1.f / (1.f + __expf(-(v + l2b[0])));
  }
}

extern "C" void kernel_launch(void* const* d_in, const int* in_sizes, int n_in,
                              void* d_out, int out_size, void* d_ws, size_t ws_size,
                              hipStream_t stream) {
  const int* EI    = (const int*)d_in[1];
  const int* BATCH = (const int*)d_in[2];
  float* OUT = (float*)d_out;

  int N = in_sizes[2];
  int E = in_sizes[1] / 2;
  int G = in_sizes[3] / 10;
  int EN = E + N;
  int NB = (N + 127) >> 7;

  char* ws = (char*)d_ws;
  size_t off = 0;
  auto alloc = [&](size_t bytes) {
    void* p = ws + off;
    off = (off + bytes + 255) & ~(size_t)255;
    return p;
  };
  __hip_bfloat16* f_xa = (__hip_bfloat16*)alloc((size_t)N * 128 * 2);
  __hip_bfloat16* f_h  = (__hip_bfloat16*)alloc((size_t)N * 128 * 2);
  float* f_als = (float*)alloc((size_t)N * 4 * 4);
  float* f_ald = (float*)alloc((size_t)N * 4 * 4);
  float* fW0p  = (float*)alloc(576 * 4);
  __hip_bfloat16* fWt1 = (__hip_bfloat16*)alloc(144 * 128 * 2);
  __hip_bfloat16* fWt2 = (__hip_bfloat16*)alloc(48 * 128 * 2);
  int* i_rs   = (int*)alloc((size_t)(N + 1) * 4);
  int* i_col  = (int*)alloc((size_t)EN * 4);
  unsigned int* i_pairs = (unsigned int*)alloc((size_t)EN * 4);
  int* i_ghist   = (int*)alloc(512 * 4);
  int* i_bbase   = (int*)alloc(513 * 4);
  int* i_gcursor = (int*)alloc(512 * 4);
  int* i_flag = (int*)alloc(256);

  CvtArgs ca;
  float* fptr[32];
  int maxn = 0, na = 0;
  for (int i = 0; i < 32; i++) {
    if (i == 1 || i == 2) { fptr[i] = nullptr; continue; }
    int n = in_sizes[i];
    fptr[i] = (float*)alloc((size_t)n * 4);
    ca.src[na] = d_in[i];
    ca.dst[na] = fptr[i];
    ca.n[na] = n;
    if (n > maxn) maxn = n;
    na++;
  }

  // dtype detect + convert
  k_detect<<<1, 256, 0, stream>>>((const unsigned short*)d_in[12], in_sizes[12], i_flag);
  dim3 cgrid((maxn + 255) / 256, na);
  k_cvt_all<<<cgrid, 256, 0, stream>>>(ca, i_flag);

  // weight folding
  k_foldW<<<99, 256, 0, stream>>>(fptr[4], fptr[5], fptr[6],
                                  fptr[12], fptr[13], fptr[14],
                                  fptr[20], fptr[21], fptr[22],
                                  fW0p, fWt1, fWt2);

  // bucketed CSR build (no global scan: rs from per-bucket 128-wide scan)
  hipMemsetAsync(i_ghist, 0, 512 * 4, stream);
  int ebks = (EN + 4095) / 4096;
  k_binhist<<<ebks, 256, 0, stream>>>(EI, i_ghist, E, EN);
  k_bucketscan<<<1, 512, 0, stream>>>(i_ghist, i_bbase, i_gcursor);
  k_binscatter<<<ebks, 256, 0, stream>>>(EI, i_gcursor, i_pairs, E, EN);
  k_bucketrs<<<NB, 128, 0, stream>>>(i_pairs, i_bbase, i_rs, N, EN);
  k_scatter2<<<NB, 256, 0, stream>>>(i_pairs, i_bbase, i_rs, i_col, N);

  // layer 0
  k_gemm0<<<(N * 144 + 255) / 256, 256, 0, stream>>>(fptr[0], fW0p, f_h, f_als, f_ald, N);
  k_agg4<<<(N + 7) / 8, 256, 0, stream>>>(f_h, f_als, f_ald, i_rs, i_col, fptr[7], fptr[8], fptr[9], fptr[10], fptr[11], f_xa, N);
  // layer 1 (MFMA)
  k_mm<9, 128, 4><<<(N + 63) / 64, 256, 0, stream>>>(f_xa, fWt1, f_h, f_als, f_ald, N);
  k_agg4<<<(N + 7) / 8, 256, 0, stream>>>(f_h, f_als, f_ald, i_rs, i_col, fptr[15], fptr[16], fptr[17], fptr[18], fptr[19], f_xa, N);
  // layer 2 (MFMA)
  k_mm<3, 32, 1><<<(N + 63) / 64, 256, 0, stream>>>(f_xa, fWt2, f_h, f_als, f_ald, N);
  k_agg1<<<(N + 15) / 16, 256, 0, stream>>>(f_h, f_als, f_ald, i_rs, i_col, fptr[23], fptr[24], fptr[25], fptr[26], fptr[27], f_xa, N);

  // pooling + MLP head
  k_pool<<<G, 64, 0, stream>>>(f_xa, BATCH, fptr[3], fptr[28], fptr[29], fptr[30], fptr[31], OUT, N, G);
}

// Round 12
// 192.471 us; speedup vs baseline: 3.0965x; 1.0999x over previous
//
#include <hip/hip_runtime.h>
#include <hip/hip_bf16.h>
#include <math.h>

#define LRELU_NEG 0.2f
#define BN_EPS 1e-5f
#define CSR_SHIFT 7

typedef __attribute__((ext_vector_type(8))) short bf16x8;
typedef __attribute__((ext_vector_type(4))) float f32x4;

__device__ __forceinline__ float lrelu(float x) { return x > 0.f ? x : LRELU_NEG * x; }
__device__ __forceinline__ float b2f(__hip_bfloat16 v) { return __bfloat162float(v); }
__device__ __forceinline__ unsigned short f2bu(float v) {
  __hip_bfloat16 b = __float2bfloat16(v);
  return *(unsigned short*)&b;
}
__device__ __forceinline__ float blo(unsigned int u) { return __uint_as_float(u << 16); }
__device__ __forceinline__ float bhi(unsigned int u) { return __uint_as_float(u & 0xFFFF0000u); }
__device__ __forceinline__ float elu_fast(float v) { return v > 0.f ? v : __expf(v) - 1.f; }

// ---------------- dtype detection (+ ghist zeroing) ----------------
__global__ __launch_bounds__(256) void k_detect(const unsigned short* __restrict__ w, int n,
                                                int* __restrict__ flag, int* __restrict__ ghist) {
  __shared__ int bad_s;
  int tid = threadIdx.x;
  ghist[tid] = 0; ghist[tid + 256] = 0;
  if (tid == 0) bad_s = 0;
  __syncthreads();
  int bad = 0;
  for (int i = 2 * tid; i < n; i += 512) {
    unsigned short u = w[i];
    if ((u & 0x7FFF) == 0) continue;
    int ex = (u >> 7) & 0xFF;
    if (ex > 131 || ex < 90) bad++;
  }
  atomicAdd(&bad_s, bad);
  __syncthreads();
  if (tid == 0) *flag = (bad_s < 2048) ? 1 : 0;
}

// ---------------- unified input conversion -> f32 in ws ----------------
struct CvtArgs {
  const void* src[30];
  float* dst[30];
  int n[30];
};

__global__ __launch_bounds__(256) void k_cvt_all(CvtArgs a, const int* __restrict__ flag) {
  int ai = blockIdx.y;
  int n = a.n[ai];
  int i = blockIdx.x * 256 + threadIdx.x;
  if (i >= n) return;
  if (*flag) {
    a.dst[ai][i] = b2f(((const __hip_bfloat16*)a.src[ai])[i]);
  } else {
    a.dst[ai][i] = ((const float*)a.src[ai])[i];
  }
}

// ---------------- weight folding ----------------
__global__ __launch_bounds__(256) void k_foldW(const float* __restrict__ W0, const float* __restrict__ as0, const float* __restrict__ ad0,
                                               const float* __restrict__ W1, const float* __restrict__ as1, const float* __restrict__ ad1,
                                               const float* __restrict__ W2, const float* __restrict__ as2, const float* __restrict__ ad2,
                                               float* __restrict__ W0p, __hip_bfloat16* __restrict__ Wt1, __hip_bfloat16* __restrict__ Wt2) {
  int idx = blockIdx.x * 256 + threadIdx.x;
  if (idx < 576) {                  // W0p [4][144]
    int k = idx / 144, c = idx % 144;
    float v = 0.f;
    if (c < 128) v = W0[k * 128 + c];
    else if (c < 136) {
      int hh = (c - 128) & 3; const float* a = (c < 132) ? as0 : ad0;
      float s = 0.f;
      for (int cc = 0; cc < 32; cc++) s += W0[k * 128 + hh * 32 + cc] * a[hh * 32 + cc];
      v = s;
    }
    W0p[k * 144 + c] = v;
    return;
  }
  idx -= 576;
  if (idx < 144 * 128) {            // Wt1 [144][128]
    int c = idx >> 7, k = idx & 127;
    float v = 0.f;
    if (c < 128) v = W1[k * 128 + c];
    else if (c < 136) {
      int hh = (c - 128) & 3; const float* a = (c < 132) ? as1 : ad1;
      float s = 0.f;
      for (int cc = 0; cc < 32; cc++) s += W1[k * 128 + hh * 32 + cc] * a[hh * 32 + cc];
      v = s;
    }
    Wt1[c * 128 + k] = __float2bfloat16(v);
    return;
  }
  idx -= 144 * 128;
  if (idx < 48 * 128) {             // Wt2 [48][128]
    int c = idx >> 7, k = idx & 127;
    float v = 0.f;
    if (c < 32) v = W2[k * 32 + c];
    else if (c == 32) { float s = 0.f; for (int cc = 0; cc < 32; cc++) s += W2[k * 32 + cc] * as2[cc]; v = s; }
    else if (c == 33) { float s = 0.f; for (int cc = 0; cc < 32; cc++) s += W2[k * 32 + cc] * ad2[cc]; v = s; }
    Wt2[c * 128 + k] = __float2bfloat16(v);
  }
}

// ================= bucketed CSR build =================
__global__ __launch_bounds__(256) void k_binhist(const int* __restrict__ ei, int* __restrict__ ghist,
                                                 int E, int EN) {
  __shared__ int hist[512];
  int tid = threadIdx.x;
  hist[tid] = 0; hist[tid + 256] = 0;
  __syncthreads();
  int base = blockIdx.x * 4096;
  for (int i = 0; i < 16; i++) {
    int e = base + i * 256 + tid;
    if (e < EN) {
      int dst = (e < E) ? ei[E + e] : (e - E);
      atomicAdd(&hist[dst >> CSR_SHIFT], 1);
    }
  }
  __syncthreads();
  if (hist[tid]) atomicAdd(&ghist[tid], hist[tid]);
  if (hist[tid + 256]) atomicAdd(&ghist[tid + 256], hist[tid + 256]);
}

__global__ __launch_bounds__(512) void k_bucketscan(const int* __restrict__ ghist,
                                                    int* __restrict__ bbase, int* __restrict__ gcursor) {
  __shared__ int wpre[8];
  int tid = threadIdx.x, lane = tid & 63, wid = tid >> 6;
  int v = ghist[tid];
  int x = v;
  #pragma unroll
  for (int off = 1; off < 64; off <<= 1) {
    int y = __shfl_up(x, off);
    if (lane >= off) x += y;
  }
  if (lane == 63) wpre[wid] = x;
  __syncthreads();
  if (tid == 0) {
    int acc = 0;
    #pragma unroll
    for (int w = 0; w < 8; w++) { int t = wpre[w]; wpre[w] = acc; acc += t; }
  }
  __syncthreads();
  int excl = wpre[wid] + x - v;
  bbase[tid] = excl;
  gcursor[tid] = excl;
  if (tid == 511) bbase[512] = excl + v;
}

__global__ __launch_bounds__(256) void k_binscatter(const int* __restrict__ ei, int* __restrict__ gcursor,
                                                    unsigned int* __restrict__ pairs, int E, int EN) {
  __shared__ int cnt[512];
  __shared__ int base[512];
  int tid = threadIdx.x;
  cnt[tid] = 0; cnt[tid + 256] = 0;
  __syncthreads();
  int eb = blockIdx.x * 4096;
  int srcs[16], dsts[16];
  #pragma unroll
  for (int i = 0; i < 16; i++) {
    int e = eb + i * 256 + tid;
    srcs[i] = -1; dsts[i] = 0;
    if (e < EN) {
      int s, d;
      if (e < E) { s = ei[e]; d = ei[E + e]; } else { s = e - E; d = s; }
      srcs[i] = s; dsts[i] = d;
      atomicAdd(&cnt[d >> CSR_SHIFT], 1);
    }
  }
  __syncthreads();
  for (int b = tid; b < 512; b += 256) {
    int c = cnt[b];
    base[b] = c ? atomicAdd(&gcursor[b], c) : 0;
    cnt[b] = 0;
  }
  __syncthreads();
  #pragma unroll
  for (int i = 0; i < 16; i++) {
    if (srcs[i] >= 0) {
      int b = dsts[i] >> CSR_SHIFT;
      int loc = atomicAdd(&cnt[b], 1);
      pairs[base[b] + loc] = ((unsigned int)srcs[i] << CSR_SHIFT) | (unsigned int)(dsts[i] & 127);
    }
  }
}

// merged: per-bucket degree histogram + 128-scan -> rs, then scatter col (one kernel)
__global__ __launch_bounds__(256) void k_csrfin(const unsigned int* __restrict__ pairs,
                                                const int* __restrict__ bbase,
                                                int* __restrict__ rs, int* __restrict__ col,
                                                int N, int EN) {
  __shared__ int dcount[128];
  __shared__ int wsum;
  __shared__ int lcur[128];
  int b = blockIdx.x, tid = threadIdx.x;
  if (tid < 128) dcount[tid] = 0;
  __syncthreads();
  int s = bbase[b], e = bbase[b + 1];
  for (int i = s + tid; i < e; i += 256)
    atomicAdd(&dcount[pairs[i] & 127], 1);
  __syncthreads();
  int x = 0, v = 0, wid = 0;
  if (tid < 128) {
    v = dcount[tid];
    int lane = tid & 63; wid = tid >> 6;
    x = v;
    #pragma unroll
    for (int off = 1; off < 64; off <<= 1) {
      int y = __shfl_up(x, off);
      if (lane >= off) x += y;
    }
    if (wid == 0 && lane == 63) wsum = x;
  }
  __syncthreads();
  if (tid < 128) {
    int excl = x - v + (wid ? wsum : 0);
    int r = s + excl;
    int node = (b << CSR_SHIFT) + tid;
    if (node < N) rs[node] = r;
    lcur[tid] = r;
  }
  if (b == 0 && tid == 0) rs[N] = EN;
  __syncthreads();
  for (int i = s + tid; i < e; i += 256) {
    unsigned int p = pairs[i];
    int pos = atomicAdd(&lcur[p & 127], 1);
    col[pos] = (int)(p >> CSR_SHIFT);
  }
}

// ---------------- layer-0 GEMM (K=4), folded logits, 4 outputs/thread ----------------
__global__ __launch_bounds__(256) void k_gemm0(const float* __restrict__ x, const float* __restrict__ W0p,
    __hip_bfloat16* __restrict__ h, float* __restrict__ als, float* __restrict__ ald, int N) {
  int t = blockIdx.x * 256 + threadIdx.x;
  int nrow = t / 36, cg = t - nrow * 36;
  if (nrow >= N) return;
  float4 xv = *(const float4*)(x + (size_t)nrow * 4);
  int c0 = cg * 4;
  float o[4];
  #pragma unroll
  for (int j = 0; j < 4; j++) {
    int c = c0 + j;
    o[j] = fmaf(xv.x, W0p[c], fmaf(xv.y, W0p[144 + c], fmaf(xv.z, W0p[288 + c], xv.w * W0p[432 + c])));
  }
  if (c0 < 128) {
    uint2 pk;
    pk.x = ((unsigned int)f2bu(o[1]) << 16) | f2bu(o[0]);
    pk.y = ((unsigned int)f2bu(o[3]) << 16) | f2bu(o[2]);
    *((uint2*)((unsigned short*)h + (size_t)nrow * 128) + cg) = pk;
  } else if (c0 == 128) {
    *(float4*)(als + (size_t)nrow * 4) = make_float4(o[0], o[1], o[2], o[3]);
  } else {   // c0 == 132
    *(float4*)(ald + (size_t)nrow * 4) = make_float4(o[0], o[1], o[2], o[3]);
  }
}

// ---------------- MFMA GEMM ----------------
template <int CT, int DOUT, int HEADS>
__global__ __launch_bounds__(256) void k_mm(const __hip_bfloat16* __restrict__ xa,
    const __hip_bfloat16* __restrict__ Wt,
    __hip_bfloat16* __restrict__ h, float* __restrict__ als, float* __restrict__ ald, int N) {
  __shared__ unsigned short A_s[64 * 128];
  __shared__ unsigned short B_s[CT * 16 * 128];
  int tid = threadIdx.x;
  int row0 = blockIdx.x * 64;

  for (int i = tid; i < 1024; i += 256) {
    int r = i >> 4, slot = i & 15;
    int gr = row0 + r;
    float4 v = make_float4(0.f, 0.f, 0.f, 0.f);
    if (gr < N) v = ((const float4*)(xa + (size_t)gr * 128))[slot];
    *(float4*)((char*)A_s + r * 256 + ((slot ^ (r & 7)) << 4)) = v;
  }
  for (int i = tid; i < CT * 256; i += 256) {
    int r = i >> 4, slot = i & 15;
    float4 v = ((const float4*)Wt)[i];
    *(float4*)((char*)B_s + r * 256 + ((slot ^ (r & 7)) << 4)) = v;
  }
  __syncthreads();

  int l = tid & 63, w = tid >> 6;
  int lr = l & 15, lg = l >> 4;
  f32x4 acc[CT];
  #pragma unroll
  for (int ct = 0; ct < CT; ct++) acc[ct] = (f32x4){0.f, 0.f, 0.f, 0.f};

  int rA = w * 16 + lr;
  #pragma unroll
  for (int k0 = 0; k0 < 4; k0++) {
    int slot = k0 * 4 + lg;
    bf16x8 a = *(const bf16x8*)((const char*)A_s + rA * 256 + ((slot ^ (rA & 7)) << 4));
    #pragma unroll
    for (int ct = 0; ct < CT; ct++) {
      int rB = ct * 16 + lr;
      bf16x8 b = *(const bf16x8*)((const char*)B_s + rB * 256 + ((slot ^ (rB & 7)) << 4));
      acc[ct] = __builtin_amdgcn_mfma_f32_16x16x32_bf16(a, b, acc[ct], 0, 0, 0);
    }
  }

  #pragma unroll
  for (int ct = 0; ct < CT; ct++) {
    #pragma unroll
    for (int j = 0; j < 4; j++) {
      int gr = row0 + w * 16 + lg * 4 + j;
      if (gr >= N) continue;
      int col = ct * 16 + lr;
      float v = acc[ct][j];
      if (col < DOUT)                 h[(size_t)gr * DOUT + col] = __float2bfloat16(v);
      else if (col < DOUT + HEADS)    als[(size_t)gr * HEADS + (col - DOUT)] = v;
      else if (col < DOUT + 2*HEADS)  ald[(size_t)gr * HEADS + (col - DOUT - HEADS)] = v;
    }
  }
}

// ---------------- aggregation, H=4 C=32: 32-lane group per node, unroll-4 gather ----------------
__global__ __launch_bounds__(256) void k_agg4(const __hip_bfloat16* __restrict__ h, const float* __restrict__ als,
    const float* __restrict__ ald, const int* __restrict__ rs, const int* __restrict__ col,
    const float* __restrict__ bias, const float* __restrict__ bng,
    const float* __restrict__ bnb, const float* __restrict__ bnm,
    const float* __restrict__ bnv, __hip_bfloat16* __restrict__ out, int N) {
  __shared__ int svs[8][32];
  __shared__ float ps[8][32][4];
  int tid = threadIdx.x;
  int sub = tid & 31, gi = tid >> 5;
  int n = blockIdx.x * 8 + gi;
  if (n >= N) return;
  int row = rs[n], deg = rs[n + 1] - row;
  float4 ad4 = *(const float4*)(ald + (size_t)n * 4);
  int hh2 = sub >> 3;
  float acc0 = 0.f, acc1 = 0.f, acc2 = 0.f, acc3 = 0.f;
  float s0 = 0.f, s1 = 0.f, s2 = 0.f, s3 = 0.f;

  for (int base = 0; base < deg; base += 32) {
    int k = base + sub;
    int sv = 0; float q0 = 0.f, q1 = 0.f, q2 = 0.f, q3 = 0.f;
    if (k < deg) {
      sv = col[row + k];
      float4 a4 = *(const float4*)(als + (size_t)sv * 4);
      q0 = __expf(lrelu(a4.x + ad4.x));
      q1 = __expf(lrelu(a4.y + ad4.y));
      q2 = __expf(lrelu(a4.z + ad4.z));
      q3 = __expf(lrelu(a4.w + ad4.w));
    }
    svs[gi][sub] = sv;
    *(float4*)&ps[gi][sub][0] = make_float4(q0, q1, q2, q3);
    s0 += q0; s1 += q1; s2 += q2; s3 += q3;
    int cnt = min(32, deg - base);
    int e = 0;
    for (; e + 3 < cnt; e += 4) {
      float pA = ps[gi][e][hh2];     int sA = svs[gi][e];
      float pB = ps[gi][e + 1][hh2]; int sB = svs[gi][e + 1];
      float pC = ps[gi][e + 2][hh2]; int sC = svs[gi][e + 2];
      float pD = ps[gi][e + 3][hh2]; int sD = svs[gi][e + 3];
      uint2 hA = *((const uint2*)(h + (size_t)sA * 128) + sub);
      uint2 hB = *((const uint2*)(h + (size_t)sB * 128) + sub);
      uint2 hC = *((const uint2*)(h + (size_t)sC * 128) + sub);
      uint2 hD = *((const uint2*)(h + (size_t)sD * 128) + sub);
      acc0 = fmaf(pA, blo(hA.x), acc0); acc1 = fmaf(pA, bhi(hA.x), acc1);
      acc2 = fmaf(pA, blo(hA.y), acc2); acc3 = fmaf(pA, bhi(hA.y), acc3);
      acc0 = fmaf(pB, blo(hB.x), acc0); acc1 = fmaf(pB, bhi(hB.x), acc1);
      acc2 = fmaf(pB, blo(hB.y), acc2); acc3 = fmaf(pB, bhi(hB.y), acc3);
      acc0 = fmaf(pC, blo(hC.x), acc0); acc1 = fmaf(pC, bhi(hC.x), acc1);
      acc2 = fmaf(pC, blo(hC.y), acc2); acc3 = fmaf(pC, bhi(hC.y), acc3);
      acc0 = fmaf(pD, blo(hD.x), acc0); acc1 = fmaf(pD, bhi(hD.x), acc1);
      acc2 = fmaf(pD, blo(hD.y), acc2); acc3 = fmaf(pD, bhi(hD.y), acc3);
    }
    for (; e < cnt; e++) {
      float pA = ps[gi][e][hh2]; int sA = svs[gi][e];
      uint2 hA = *((const uint2*)(h + (size_t)sA * 128) + sub);
      acc0 = fmaf(pA, blo(hA.x), acc0); acc1 = fmaf(pA, bhi(hA.x), acc1);
      acc2 = fmaf(pA, blo(hA.y), acc2); acc3 = fmaf(pA, bhi(hA.y), acc3);
    }
  }
  #pragma unroll
  for (int off = 1; off < 32; off <<= 1) {
    s0 += __shfl_xor(s0, off); s1 += __shfl_xor(s1, off);
    s2 += __shfl_xor(s2, off); s3 += __shfl_xor(s3, off);
  }
  float ssel = hh2 == 0 ? s0 : hh2 == 1 ? s1 : hh2 == 2 ? s2 : s3;
  float inv = 1.f / (ssel + 1e-16f);
  acc0 *= inv; acc1 *= inv; acc2 *= inv; acc3 *= inv;

  int c0 = 4 * sub;
  float4 bi = *(const float4*)(bias + c0);
  float4 bm = *(const float4*)(bnm + c0);
  float4 bv = *(const float4*)(bnv + c0);
  float4 bg = *(const float4*)(bng + c0);
  float4 bb = *(const float4*)(bnb + c0);
  float v0 = (acc0 + bi.x - bm.x) * rsqrtf(bv.x + BN_EPS) * bg.x + bb.x;
  float v1 = (acc1 + bi.y - bm.y) * rsqrtf(bv.y + BN_EPS) * bg.y + bb.y;
  float v2 = (acc2 + bi.z - bm.z) * rsqrtf(bv.z + BN_EPS) * bg.z + bb.z;
  float v3 = (acc3 + bi.w - bm.w) * rsqrtf(bv.w + BN_EPS) * bg.w + bb.w;
  v0 = elu_fast(v0); v1 = elu_fast(v1); v2 = elu_fast(v2); v3 = elu_fast(v3);
  uint2 packed;
  packed.x = ((unsigned int)f2bu(v1) << 16) | f2bu(v0);
  packed.y = ((unsigned int)f2bu(v3) << 16) | f2bu(v2);
  *((uint2*)((unsigned short*)out + (size_t)n * 128) + sub) = packed;
}

// ---------------- aggregation, H=1 C=32: 16-lane group per node, unroll-4 gather ----------------
__global__ __launch_bounds__(256) void k_agg1(const __hip_bfloat16* __restrict__ h, const float* __restrict__ als,
    const float* __restrict__ ald, const int* __restrict__ rs, const int* __restrict__ col,
    const float* __restrict__ bias, const float* __restrict__ bng,
    const float* __restrict__ bnb, const float* __restrict__ bnm,
    const float* __restrict__ bnv, __hip_bfloat16* __restrict__ out, int N) {
  __shared__ int svs[16][16];
  __shared__ float ps[16][16];
  int tid = threadIdx.x;
  int sub = tid & 15, gi = tid >> 4;
  int n = blockIdx.x * 16 + gi;
  if (n >= N) return;
  int row = rs[n], deg = rs[n + 1] - row;
  float ad = ald[n];
  float acc0 = 0.f, acc1 = 0.f, s = 0.f;

  for (int base = 0; base < deg; base += 16) {
    int k = base + sub;
    int sv = 0; float q = 0.f;
    if (k < deg) {
      sv = col[row + k];
      q = __expf(lrelu(als[sv] + ad));
    }
    svs[gi][sub] = sv;
    ps[gi][sub] = q;
    s += q;
    int cnt = min(16, deg - base);
    int e = 0;
    for (; e + 3 < cnt; e += 4) {
      float pA = ps[gi][e];     int sA = svs[gi][e];
      float pB = ps[gi][e + 1]; int sB = svs[gi][e + 1];
      float pC = ps[gi][e + 2]; int sC = svs[gi][e + 2];
      float pD = ps[gi][e + 3]; int sD = svs[gi][e + 3];
      unsigned int hA = *((const unsigned int*)(h + (size_t)sA * 32) + sub);
      unsigned int hB = *((const unsigned int*)(h + (size_t)sB * 32) + sub);
      unsigned int hC = *((const unsigned int*)(h + (size_t)sC * 32) + sub);
      unsigned int hD = *((const unsigned int*)(h + (size_t)sD * 32) + sub);
      acc0 = fmaf(pA, blo(hA), acc0); acc1 = fmaf(pA, bhi(hA), acc1);
      acc0 = fmaf(pB, blo(hB), acc0); acc1 = fmaf(pB, bhi(hB), acc1);
      acc0 = fmaf(pC, blo(hC), acc0); acc1 = fmaf(pC, bhi(hC), acc1);
      acc0 = fmaf(pD, blo(hD), acc0); acc1 = fmaf(pD, bhi(hD), acc1);
    }
    for (; e < cnt; e++) {
      float pA = ps[gi][e]; int sA = svs[gi][e];
      unsigned int hA = *((const unsigned int*)(h + (size_t)sA * 32) + sub);
      acc0 = fmaf(pA, blo(hA), acc0); acc1 = fmaf(pA, bhi(hA), acc1);
    }
  }
  #pragma unroll
  for (int off = 1; off < 16; off <<= 1) s += __shfl_xor(s, off);
  float inv = 1.f / (s + 1e-16f);
  acc0 *= inv; acc1 *= inv;

  int c0 = 2 * sub;
  float2 bi = *(const float2*)(bias + c0);
  float2 bm = *(const float2*)(bnm + c0);
  float2 bv = *(const float2*)(bnv + c0);
  float2 bg = *(const float2*)(bng + c0);
  float2 bb = *(const float2*)(bnb + c0);
  float v0 = (acc0 + bi.x - bm.x) * rsqrtf(bv.x + BN_EPS) * bg.x + bb.x;
  float v1 = (acc1 + bi.y - bm.y) * rsqrtf(bv.y + BN_EPS) * bg.y + bb.y;
  v0 = elu_fast(v0);
  v1 = elu_fast(v1);
  unsigned int packed = ((unsigned int)f2bu(v1) << 16) | f2bu(v0);
  *((unsigned int*)((unsigned short*)out + (size_t)n * 32) + sub) = packed;
}

// ---------------- per-graph pooling + MLP head ----------------
__global__ __launch_bounds__(64) void k_pool(const __hip_bfloat16* __restrict__ x3, const int* __restrict__ batch,
    const float* __restrict__ u, const float* __restrict__ l1w,
    const float* __restrict__ l1b, const float* __restrict__ l2w,
    const float* __restrict__ l2b, float* __restrict__ out, int N, int G) {
  int g = blockIdx.x;
  int lane = threadIdx.x;
  int lo = 0, hi = N;
  while (lo < hi) { int mid = (lo + hi) >> 1; if (batch[mid] < g) lo = mid + 1; else hi = mid; }
  int start = lo;
  hi = N;
  while (lo < hi) { int mid = (lo + hi) >> 1; if (batch[mid] < g + 1) lo = mid + 1; else hi = mid; }
  int end = lo;
  int sub = lane & 15, q = lane >> 4;
  float sum0 = 0.f, sum1 = 0.f, mx0 = -1e30f, mx1 = -1e30f;
  for (int i = start + q; i < end; i += 4) {
    unsigned int hv = *((const unsigned int*)(x3 + (size_t)i * 32) + sub);
    float v0 = blo(hv), v1 = bhi(hv);
    sum0 += v0; sum1 += v1;
    mx0 = fmaxf(mx0, v0); mx1 = fmaxf(mx1, v1);
  }
  sum0 += __shfl_xor(sum0, 16); sum0 += __shfl_xor(sum0, 32);
  sum1 += __shfl_xor(sum1, 16); sum1 += __shfl_xor(sum1, 32);
  mx0 = fmaxf(mx0, __shfl_xor(mx0, 16)); mx0 = fmaxf(mx0, __shfl_xor(mx0, 32));
  mx1 = fmaxf(mx1, __shfl_xor(mx1, 16)); mx1 = fmaxf(mx1, __shfl_xor(mx1, 32));
  __shared__ float comb[74];
  if (lane < 16) {
    float cnt = (float)(end - start);
    comb[2 * lane] = sum0 / cnt;
    comb[2 * lane + 1] = sum1 / cnt;
    comb[32 + 2 * lane] = mx0;
    comb[32 + 2 * lane + 1] = mx1;
  }
  if (lane < 10) comb[64 + lane] = u[g * 10 + lane];
  __syncthreads();
  if (lane < 32) {
    float acc = l1b[lane];
    #pragma unroll
    for (int k = 0; k < 74; k++) acc = fmaf(comb[k], l1w[k * 32 + lane], acc);
    acc = fmaxf(acc, 0.f);
    float v = acc * l2w[lane];
    #pragma unroll
    for (int off = 16; off; off >>= 1) v += __shfl_xor(v, off, 32);
    if (lane == 0) out[g] = 1.f / (1.f + __expf(-(v + l2b[0])));
  }
}

extern "C" void kernel_launch(void* const* d_in, const int* in_sizes, int n_in,
                              void* d_out, int out_size, void* d_ws, size_t ws_size,
                              hipStream_t stream) {
  const int* EI    = (const int*)d_in[1];
  const int* BATCH = (const int*)d_in[2];
  float* OUT = (float*)d_out;

  int N = in_sizes[2];
  int E = in_sizes[1] / 2;
  int G = in_sizes[3] / 10;
  int EN = E + N;
  int NB = (N + 127) >> 7;

  char* ws = (char*)d_ws;
  size_t off = 0;
  auto alloc = [&](size_t bytes) {
    void* p = ws + off;
    off = (off + bytes + 255) & ~(size_t)255;
    return p;
  };
  __hip_bfloat16* f_xa = (__hip_bfloat16*)alloc((size_t)N * 128 * 2);
  __hip_bfloat16* f_h  = (__hip_bfloat16*)alloc((size_t)N * 128 * 2);
  float* f_als = (float*)alloc((size_t)N * 4 * 4);
  float* f_ald = (float*)alloc((size_t)N * 4 * 4);
  float* fW0p  = (float*)alloc(576 * 4);
  __hip_bfloat16* fWt1 = (__hip_bfloat16*)alloc(144 * 128 * 2);
  __hip_bfloat16* fWt2 = (__hip_bfloat16*)alloc(48 * 128 * 2);
  int* i_rs   = (int*)alloc((size_t)(N + 1) * 4);
  int* i_col  = (int*)alloc((size_t)EN * 4);
  unsigned int* i_pairs = (unsigned int*)alloc((size_t)EN * 4);
  int* i_ghist   = (int*)alloc(512 * 4);
  int* i_bbase   = (int*)alloc(513 * 4);
  int* i_gcursor = (int*)alloc(512 * 4);
  int* i_flag = (int*)alloc(256);

  CvtArgs ca;
  float* fptr[32];
  int maxn = 0, na = 0;
  for (int i = 0; i < 32; i++) {
    if (i == 1 || i == 2) { fptr[i] = nullptr; continue; }
    int n = in_sizes[i];
    fptr[i] = (float*)alloc((size_t)n * 4);
    ca.src[na] = d_in[i];
    ca.dst[na] = fptr[i];
    ca.n[na] = n;
    if (n > maxn) maxn = n;
    na++;
  }

  // dtype detect (+ ghist zero) + convert
  k_detect<<<1, 256, 0, stream>>>((const unsigned short*)d_in[12], in_sizes[12], i_flag, i_ghist);
  dim3 cgrid((maxn + 255) / 256, na);
  k_cvt_all<<<cgrid, 256, 0, stream>>>(ca, i_flag);

  // weight folding
  k_foldW<<<99, 256, 0, stream>>>(fptr[4], fptr[5], fptr[6],
                                  fptr[12], fptr[13], fptr[14],
                                  fptr[20], fptr[21], fptr[22],
                                  fW0p, fWt1, fWt2);

  // bucketed CSR build
  int ebks = (EN + 4095) / 4096;
  k_binhist<<<ebks, 256, 0, stream>>>(EI, i_ghist, E, EN);
  k_bucketscan<<<1, 512, 0, stream>>>(i_ghist, i_bbase, i_gcursor);
  k_binscatter<<<ebks, 256, 0, stream>>>(EI, i_gcursor, i_pairs, E, EN);
  k_csrfin<<<NB, 256, 0, stream>>>(i_pairs, i_bbase, i_rs, i_col, N, EN);

  // layer 0
  k_gemm0<<<(N * 36 + 255) / 256, 256, 0, stream>>>(fptr[0], fW0p, f_h, f_als, f_ald, N);
  k_agg4<<<(N + 7) / 8, 256, 0, stream>>>(f_h, f_als, f_ald, i_rs, i_col, fptr[7], fptr[8], fptr[9], fptr[10], fptr[11], f_xa, N);
  // layer 1 (MFMA)
  k_mm<9, 128, 4><<<(N + 63) / 64, 256, 0, stream>>>(f_xa, fWt1, f_h, f_als, f_ald, N);
  k_agg4<<<(N + 7) / 8, 256, 0, stream>>>(f_h, f_als, f_ald, i_rs, i_col, fptr[15], fptr[16], fptr[17], fptr[18], fptr[19], f_xa, N);
  // layer 2 (MFMA)
  k_mm<3, 32, 1><<<(N + 63) / 64, 256, 0, stream>>>(f_xa, fWt2, f_h, f_als, f_ald, N);
  k_agg1<<<(N + 15) / 16, 256, 0, stream>>>(f_h, f_als, f_ald, i_rs, i_col, fptr[23], fptr[24], fptr[25], fptr[26], fptr[27], f_xa, N);

  // pooling + MLP head
  k_pool<<<G, 64, 0, stream>>>(f_xa, BATCH, fptr[3], fptr[28], fptr[29], fptr[30], fptr[31], OUT, N, G);
}